// Round 2
// baseline (829.033 us; speedup 1.0000x reference)
//
#include <hip/hip_runtime.h>
#include <stdint.h>

#define N_NODES 50000
#define N_EDGES 800000
#define IN_F    100
#define HID     256
#define NCLS    47

__device__ __forceinline__ uint32_t rotl32(uint32_t v, uint32_t r) {
    return (v << r) | (v >> (32u - r));
}

// JAX threefry2x32, key = jax.random.key(42) -> (0, 42), PARTITIONABLE mode
// (default since jax 0.4.30): per flat index i, counter pair = (hi32(i)=0, i),
// output bits = x0 ^ x1. bernoulli(0.5) keeps iff MSB(bits)==0.
__device__ __forceinline__ uint32_t jax_bits(uint32_t i) {
    const uint32_t ks0 = 0u, ks1 = 42u, ks2 = 0x1BD11BDAu ^ 42u;
    uint32_t x0 = 0u + ks0;   // counts_hi = 0
    uint32_t x1 = i + ks1;    // counts_lo = i
    // 5 groups of 4 rounds, key injection after each group
    x0 += x1; x1 = rotl32(x1, 13); x1 ^= x0;
    x0 += x1; x1 = rotl32(x1, 15); x1 ^= x0;
    x0 += x1; x1 = rotl32(x1, 26); x1 ^= x0;
    x0 += x1; x1 = rotl32(x1,  6); x1 ^= x0;
    x0 += ks1; x1 += ks2 + 1u;
    x0 += x1; x1 = rotl32(x1, 17); x1 ^= x0;
    x0 += x1; x1 = rotl32(x1, 29); x1 ^= x0;
    x0 += x1; x1 = rotl32(x1, 16); x1 ^= x0;
    x0 += x1; x1 = rotl32(x1, 24); x1 ^= x0;
    x0 += ks2; x1 += ks0 + 2u;
    x0 += x1; x1 = rotl32(x1, 13); x1 ^= x0;
    x0 += x1; x1 = rotl32(x1, 15); x1 ^= x0;
    x0 += x1; x1 = rotl32(x1, 26); x1 ^= x0;
    x0 += x1; x1 = rotl32(x1,  6); x1 ^= x0;
    x0 += ks0; x1 += ks1 + 3u;
    x0 += x1; x1 = rotl32(x1, 17); x1 ^= x0;
    x0 += x1; x1 = rotl32(x1, 29); x1 ^= x0;
    x0 += x1; x1 = rotl32(x1, 16); x1 ^= x0;
    x0 += x1; x1 = rotl32(x1, 24); x1 ^= x0;
    x0 += ks1; x1 += ks2 + 4u;
    x0 += x1; x1 = rotl32(x1, 13); x1 ^= x0;
    x0 += x1; x1 = rotl32(x1, 15); x1 ^= x0;
    x0 += x1; x1 = rotl32(x1, 26); x1 ^= x0;
    x0 += x1; x1 = rotl32(x1,  6); x1 ^= x0;
    x0 += ks2; x1 += ks0 + 5u;
    return x0 ^ x1;
}

// ---------------- edge scatter, layer 1 (aggregate x in 100-dim) -------------
__global__ __launch_bounds__(256) void scatter1(
    const int* __restrict__ src, const int* __restrict__ dst,
    const float* __restrict__ x, float* __restrict__ deg, float* __restrict__ accx)
{
    int gid = blockIdx.x * 256 + threadIdx.x;
    int e = gid >> 7;          // 128 threads per edge
    int j = gid & 127;
    if (e >= N_EDGES) return;
    int d = dst[e];
    if (j < IN_F) {
        int s = src[e];
        atomicAdd(&accx[d * IN_F + j], x[s * IN_F + j]);
    } else if (j == IN_F) {
        atomicAdd(&deg[d], 1.0f);
    }
}

__global__ __launch_bounds__(256) void finalize_deg(float* __restrict__ deg)
{
    int i = blockIdx.x * 256 + threadIdx.x;
    if (i < N_NODES) deg[i] = 1.0f / fmaxf(deg[i], 1.0f);  // becomes invdeg
}

// ---------------- fused layer-1 GEMM + bias + ReLU + dropout -----------------
// [50000 x 200] (x || mean_neigh) @ [200 x 256], 32 rows per block, 1 col/thread
__global__ __launch_bounds__(256) void gemm1_fused(
    const float* __restrict__ x, const float* __restrict__ accx,
    const float* __restrict__ invdeg,
    const float* __restrict__ Wself, const float* __restrict__ Wneigh,
    const float* __restrict__ b1, float* __restrict__ h1d)
{
    __shared__ float xs[32][2 * IN_F];   // 32 rows x (x:100 | mean:100) = 25.6 KB
    __shared__ float invd[32];
    const int row0 = blockIdx.x * 32;
    const int tid  = threadIdx.x;

    if (tid < 32) {
        int g = row0 + tid;
        invd[tid] = (g < N_NODES) ? invdeg[g] : 0.f;
    }
    __syncthreads();

    for (int idx = tid; idx < 32 * IN_F; idx += 256) {
        int r = idx / IN_F, k = idx % IN_F;
        int g = row0 + r;
        float xv = 0.f, av = 0.f;
        if (g < N_NODES) {
            xv = x[g * IN_F + k];
            av = accx[g * IN_F + k] * invd[r];
        }
        xs[r][k]        = xv;
        xs[r][IN_F + k] = av;
    }
    __syncthreads();

    const int j = tid;   // output column 0..255
    float acc[32];
#pragma unroll
    for (int r = 0; r < 32; ++r) acc[r] = 0.f;

    for (int k = 0; k < IN_F; k += 4) {
        float w0 = Wself[(k + 0) * HID + j];
        float w1 = Wself[(k + 1) * HID + j];
        float w2 = Wself[(k + 2) * HID + j];
        float w3 = Wself[(k + 3) * HID + j];
#pragma unroll
        for (int r = 0; r < 32; ++r) {
            const float4 xv = *reinterpret_cast<const float4*>(&xs[r][k]);
            acc[r] = fmaf(xv.x, w0, acc[r]);
            acc[r] = fmaf(xv.y, w1, acc[r]);
            acc[r] = fmaf(xv.z, w2, acc[r]);
            acc[r] = fmaf(xv.w, w3, acc[r]);
        }
    }
    for (int k = 0; k < IN_F; k += 4) {
        float w0 = Wneigh[(k + 0) * HID + j];
        float w1 = Wneigh[(k + 1) * HID + j];
        float w2 = Wneigh[(k + 2) * HID + j];
        float w3 = Wneigh[(k + 3) * HID + j];
#pragma unroll
        for (int r = 0; r < 32; ++r) {
            const float4 xv = *reinterpret_cast<const float4*>(&xs[r][IN_F + k]);
            acc[r] = fmaf(xv.x, w0, acc[r]);
            acc[r] = fmaf(xv.y, w1, acc[r]);
            acc[r] = fmaf(xv.z, w2, acc[r]);
            acc[r] = fmaf(xv.w, w3, acc[r]);
        }
    }

    const float bj = b1[j];
#pragma unroll
    for (int r = 0; r < 32; ++r) {
        int g = row0 + r;
        if (g >= N_NODES) continue;
        float v = fmaxf(acc[r] + bj, 0.f);                 // bias + ReLU
        uint32_t bits = jax_bits((uint32_t)(g * HID + j)); // dropout mask
        v = (bits & 0x80000000u) ? 0.f : v * 2.0f;         // /(1-p), p=0.5
        h1d[g * HID + j] = v;
    }
}

// ---------------- build padded combined layer-2 weight [256 x 96] ------------
// cols 0..46 = W_self2, col 47 = 0, cols 48..94 = W_neigh2, col 95 = 0
__global__ __launch_bounds__(256) void build_wcat(
    const float* __restrict__ Ws2, const float* __restrict__ Wn2,
    float* __restrict__ Wcat)
{
    int gid = blockIdx.x * 256 + threadIdx.x;
    if (gid >= HID * 96) return;
    int k = gid / 96, j = gid % 96;
    float v = 0.f;
    if (j < NCLS)                 v = Ws2[k * NCLS + j];
    else if (j >= 48 && j < 95)   v = Wn2[k * NCLS + (j - 48)];
    Wcat[gid] = v;
}

// ---------------- layer-2 GEMM: s -> d_out (with b2), z2 -> ws ---------------
// 64 rows/block, 192 threads: j = tid%96 (col), rg = tid/96 (row half)
__global__ __launch_bounds__(192) void gemm2(
    const float* __restrict__ h1d, const float* __restrict__ Wcat,
    const float* __restrict__ b2, float* __restrict__ out, float* __restrict__ z2)
{
    __shared__ float hs[64][HID];   // 64 KiB
    const int row0 = blockIdx.x * 64;
    const int tid  = threadIdx.x;

    for (int idx = tid; idx < 64 * (HID / 4); idx += 192) {
        int r = idx >> 6, k4 = idx & 63;
        int g = row0 + r;
        float4 v = make_float4(0.f, 0.f, 0.f, 0.f);
        if (g < N_NODES)
            v = reinterpret_cast<const float4*>(h1d)[g * (HID / 4) + k4];
        *reinterpret_cast<float4*>(&hs[r][k4 * 4]) = v;
    }
    __syncthreads();

    const int j  = tid % 96;
    const int rg = tid / 96;   // 0 or 1
    float acc[32];
#pragma unroll
    for (int r = 0; r < 32; ++r) acc[r] = 0.f;

    for (int k = 0; k < HID; k += 4) {
        float w0 = Wcat[(k + 0) * 96 + j];
        float w1 = Wcat[(k + 1) * 96 + j];
        float w2 = Wcat[(k + 2) * 96 + j];
        float w3 = Wcat[(k + 3) * 96 + j];
#pragma unroll
        for (int r = 0; r < 32; ++r) {
            const float4 hv = *reinterpret_cast<const float4*>(&hs[rg * 32 + r][k]);
            acc[r] = fmaf(hv.x, w0, acc[r]);
            acc[r] = fmaf(hv.y, w1, acc[r]);
            acc[r] = fmaf(hv.z, w2, acc[r]);
            acc[r] = fmaf(hv.w, w3, acc[r]);
        }
    }

#pragma unroll
    for (int r = 0; r < 32; ++r) {
        int g = row0 + rg * 32 + r;
        if (g >= N_NODES) continue;
        if (j < NCLS)                 out[g * NCLS + j] = acc[r] + b2[j];
        else if (j >= 48 && j < 95)   z2[g * NCLS + (j - 48)] = acc[r];
    }
}

// ---------------- edge scatter, layer 2 (aggregate z2 in 47-dim) -------------
__global__ __launch_bounds__(256) void scatter2(
    const int* __restrict__ src, const int* __restrict__ dst,
    const float* __restrict__ z2, const float* __restrict__ invdeg,
    float* __restrict__ out)
{
    int gid = blockIdx.x * 256 + threadIdx.x;
    int e = gid >> 6;          // 64 threads per edge
    int j = gid & 63;
    if (e >= N_EDGES || j >= NCLS) return;
    int d = dst[e], s = src[e];
    atomicAdd(&out[d * NCLS + j], z2[s * NCLS + j] * invdeg[d]);
}

extern "C" void kernel_launch(void* const* d_in, const int* in_sizes, int n_in,
                              void* d_out, int out_size, void* d_ws, size_t ws_size,
                              hipStream_t stream)
{
    const float* x   = (const float*)d_in[0];
    const int*   src = (const int*)  d_in[1];
    const int*   dst = (const int*)  d_in[2];
    const float* Ws1 = (const float*)d_in[3];
    const float* Wn1 = (const float*)d_in[4];
    const float* b1  = (const float*)d_in[5];
    const float* Ws2 = (const float*)d_in[6];
    const float* Wn2 = (const float*)d_in[7];
    const float* b2  = (const float*)d_in[8];
    float* out = (float*)d_out;

    float* ws   = (float*)d_ws;
    float* deg  = ws;                    //    50,000 floats (becomes invdeg)
    float* accx = ws + 50000;            // 5,000,000
    float* h1d  = ws + 5050000;          // 12,800,000
    float* z2   = ws + 17850000;         // 2,350,000
    float* wcat = ws + 20200000;         //    24,576   (~81 MB total)

    // zero deg + accx (contiguous)
    hipMemsetAsync(deg, 0, (size_t)5050000 * sizeof(float), stream);

    scatter1<<<(N_EDGES * 128) / 256, 256, 0, stream>>>(src, dst, x, deg, accx);
    finalize_deg<<<(N_NODES + 255) / 256, 256, 0, stream>>>(deg);
    build_wcat<<<(HID * 96 + 255) / 256, 256, 0, stream>>>(Ws2, Wn2, wcat);
    gemm1_fused<<<(N_NODES + 31) / 32, 256, 0, stream>>>(x, accx, deg, Ws1, Wn1, b1, h1d);
    gemm2<<<(N_NODES + 63) / 64, 192, 0, stream>>>(h1d, wcat, b2, out, z2);
    scatter2<<<(N_EDGES * 64) / 256, 256, 0, stream>>>(src, dst, z2, deg, out);
}

// Round 3
// 630.277 us; speedup vs baseline: 1.3153x; 1.3153x over previous
//
#include <hip/hip_runtime.h>
#include <stdint.h>

#define N_NODES 50000
#define N_EDGES 800000
#define IN_F    100
#define HID     256
#define NCLS    47

__device__ __forceinline__ uint32_t rotl32(uint32_t v, uint32_t r) {
    return (v << r) | (v >> (32u - r));
}

// JAX threefry2x32, key=(0,42), partitionable mode: counter=(0,i), bits=x0^x1.
// bernoulli(0.5) keeps iff MSB==0.  (verified passing in round 2)
__device__ __forceinline__ uint32_t jax_bits(uint32_t i) {
    const uint32_t ks0 = 0u, ks1 = 42u, ks2 = 0x1BD11BDAu ^ 42u;
    uint32_t x0 = 0u + ks0;
    uint32_t x1 = i + ks1;
    x0 += x1; x1 = rotl32(x1, 13); x1 ^= x0;
    x0 += x1; x1 = rotl32(x1, 15); x1 ^= x0;
    x0 += x1; x1 = rotl32(x1, 26); x1 ^= x0;
    x0 += x1; x1 = rotl32(x1,  6); x1 ^= x0;
    x0 += ks1; x1 += ks2 + 1u;
    x0 += x1; x1 = rotl32(x1, 17); x1 ^= x0;
    x0 += x1; x1 = rotl32(x1, 29); x1 ^= x0;
    x0 += x1; x1 = rotl32(x1, 16); x1 ^= x0;
    x0 += x1; x1 = rotl32(x1, 24); x1 ^= x0;
    x0 += ks2; x1 += ks0 + 2u;
    x0 += x1; x1 = rotl32(x1, 13); x1 ^= x0;
    x0 += x1; x1 = rotl32(x1, 15); x1 ^= x0;
    x0 += x1; x1 = rotl32(x1, 26); x1 ^= x0;
    x0 += x1; x1 = rotl32(x1,  6); x1 ^= x0;
    x0 += ks0; x1 += ks1 + 3u;
    x0 += x1; x1 = rotl32(x1, 17); x1 ^= x0;
    x0 += x1; x1 = rotl32(x1, 29); x1 ^= x0;
    x0 += x1; x1 = rotl32(x1, 16); x1 ^= x0;
    x0 += x1; x1 = rotl32(x1, 24); x1 ^= x0;
    x0 += ks1; x1 += ks2 + 4u;
    x0 += x1; x1 = rotl32(x1, 13); x1 ^= x0;
    x0 += x1; x1 = rotl32(x1, 15); x1 ^= x0;
    x0 += x1; x1 = rotl32(x1, 26); x1 ^= x0;
    x0 += x1; x1 = rotl32(x1,  6); x1 ^= x0;
    x0 += ks2; x1 += ks0 + 5u;
    return x0 ^ x1;
}

// ======================= CSR build (dst -> srcs) =============================
__global__ __launch_bounds__(256) void count_deg(
    const int* __restrict__ dst, int* __restrict__ deg)
{
    int e = blockIdx.x * 256 + threadIdx.x;
    if (e < N_EDGES) atomicAdd(&deg[dst[e]], 1);
}

// single-block exclusive scan over 50000 degrees -> row_ptr, cursor, invdeg
__global__ __launch_bounds__(1024) void scan_deg(
    const int* __restrict__ deg, int* __restrict__ row_ptr,
    int* __restrict__ cursor, float* __restrict__ invdeg)
{
    __shared__ int sums[1024];
    const int tid = threadIdx.x;
    const int base = tid * 49;   // 1024*49 = 50176 >= 50000
    int s = 0;
    for (int k = 0; k < 49; ++k) {
        int idx = base + k;
        if (idx < N_NODES) s += deg[idx];
    }
    sums[tid] = s;
    __syncthreads();
    for (int off = 1; off < 1024; off <<= 1) {
        int v = 0;
        if (tid >= off) v = sums[tid - off];
        __syncthreads();
        if (tid >= off) sums[tid] += v;
        __syncthreads();
    }
    int run = (tid > 0) ? sums[tid - 1] : 0;
    for (int k = 0; k < 49; ++k) {
        int idx = base + k;
        if (idx < N_NODES) {
            int d = deg[idx];
            row_ptr[idx] = run;
            cursor[idx]  = run;
            invdeg[idx]  = 1.0f / fmaxf((float)d, 1.0f);
            run += d;
        }
    }
    if (tid == 1023) row_ptr[N_NODES] = sums[1023];
}

__global__ __launch_bounds__(256) void fill_csr(
    const int* __restrict__ src, const int* __restrict__ dst,
    int* __restrict__ cursor, int* __restrict__ csr_src)
{
    int e = blockIdx.x * 256 + threadIdx.x;
    if (e >= N_EDGES) return;
    int pos = atomicAdd(&cursor[dst[e]], 1);
    csr_src[pos] = src[e];
}

// ================ pull aggregation, layer 1 (sum x over in-edges) ============
// 128 threads per node (lanes 0..99 active), 2 nodes per 256-thread block
__global__ __launch_bounds__(256) void agg1(
    const int* __restrict__ row_ptr, const int* __restrict__ csr_src,
    const float* __restrict__ x, float* __restrict__ accx)
{
    int node = blockIdx.x * 2 + (threadIdx.x >> 7);
    int j = threadIdx.x & 127;
    if (node >= N_NODES || j >= IN_F) return;
    int beg = row_ptr[node], end = row_ptr[node + 1];
    float s = 0.f;
    int e = beg;
    for (; e + 1 < end; e += 2) {          // unroll x2 to overlap gathers
        int s0 = csr_src[e], s1 = csr_src[e + 1];
        float v0 = x[s0 * IN_F + j];
        float v1 = x[s1 * IN_F + j];
        s += v0 + v1;
    }
    if (e < end) s += x[csr_src[e] * IN_F + j];
    accx[node * IN_F + j] = s;
}

// ---------------- fused layer-1 GEMM + bias + ReLU + dropout -----------------
__global__ __launch_bounds__(256) void gemm1_fused(
    const float* __restrict__ x, const float* __restrict__ accx,
    const float* __restrict__ invdeg,
    const float* __restrict__ Wself, const float* __restrict__ Wneigh,
    const float* __restrict__ b1, float* __restrict__ h1d)
{
    __shared__ float xs[32][2 * IN_F];
    __shared__ float invd[32];
    const int row0 = blockIdx.x * 32;
    const int tid  = threadIdx.x;

    if (tid < 32) {
        int g = row0 + tid;
        invd[tid] = (g < N_NODES) ? invdeg[g] : 0.f;
    }
    __syncthreads();

    for (int idx = tid; idx < 32 * IN_F; idx += 256) {
        int r = idx / IN_F, k = idx % IN_F;
        int g = row0 + r;
        float xv = 0.f, av = 0.f;
        if (g < N_NODES) {
            xv = x[g * IN_F + k];
            av = accx[g * IN_F + k] * invd[r];
        }
        xs[r][k]        = xv;
        xs[r][IN_F + k] = av;
    }
    __syncthreads();

    const int j = tid;
    float acc[32];
#pragma unroll
    for (int r = 0; r < 32; ++r) acc[r] = 0.f;

    for (int k = 0; k < IN_F; k += 4) {
        float w0 = Wself[(k + 0) * HID + j];
        float w1 = Wself[(k + 1) * HID + j];
        float w2 = Wself[(k + 2) * HID + j];
        float w3 = Wself[(k + 3) * HID + j];
#pragma unroll
        for (int r = 0; r < 32; ++r) {
            const float4 xv = *reinterpret_cast<const float4*>(&xs[r][k]);
            acc[r] = fmaf(xv.x, w0, acc[r]);
            acc[r] = fmaf(xv.y, w1, acc[r]);
            acc[r] = fmaf(xv.z, w2, acc[r]);
            acc[r] = fmaf(xv.w, w3, acc[r]);
        }
    }
    for (int k = 0; k < IN_F; k += 4) {
        float w0 = Wneigh[(k + 0) * HID + j];
        float w1 = Wneigh[(k + 1) * HID + j];
        float w2 = Wneigh[(k + 2) * HID + j];
        float w3 = Wneigh[(k + 3) * HID + j];
#pragma unroll
        for (int r = 0; r < 32; ++r) {
            const float4 xv = *reinterpret_cast<const float4*>(&xs[r][IN_F + k]);
            acc[r] = fmaf(xv.x, w0, acc[r]);
            acc[r] = fmaf(xv.y, w1, acc[r]);
            acc[r] = fmaf(xv.z, w2, acc[r]);
            acc[r] = fmaf(xv.w, w3, acc[r]);
        }
    }

    const float bj = b1[j];
#pragma unroll
    for (int r = 0; r < 32; ++r) {
        int g = row0 + r;
        if (g >= N_NODES) continue;
        float v = fmaxf(acc[r] + bj, 0.f);
        uint32_t bits = jax_bits((uint32_t)(g * HID + j));
        v = (bits & 0x80000000u) ? 0.f : v * 2.0f;
        h1d[g * HID + j] = v;
    }
}

// ---------------- build padded combined layer-2 weight [256 x 96] ------------
__global__ __launch_bounds__(256) void build_wcat(
    const float* __restrict__ Ws2, const float* __restrict__ Wn2,
    float* __restrict__ Wcat)
{
    int gid = blockIdx.x * 256 + threadIdx.x;
    if (gid >= HID * 96) return;
    int k = gid / 96, j = gid % 96;
    float v = 0.f;
    if (j < NCLS)                 v = Ws2[k * NCLS + j];
    else if (j >= 48 && j < 95)   v = Wn2[k * NCLS + (j - 48)];
    Wcat[gid] = v;
}

// ---------------- layer-2 GEMM: self -> d_out (with b2), z2 -> ws ------------
__global__ __launch_bounds__(192) void gemm2(
    const float* __restrict__ h1d, const float* __restrict__ Wcat,
    const float* __restrict__ b2, float* __restrict__ out, float* __restrict__ z2)
{
    __shared__ float hs[64][HID];
    const int row0 = blockIdx.x * 64;
    const int tid  = threadIdx.x;

    for (int idx = tid; idx < 64 * (HID / 4); idx += 192) {
        int r = idx >> 6, k4 = idx & 63;
        int g = row0 + r;
        float4 v = make_float4(0.f, 0.f, 0.f, 0.f);
        if (g < N_NODES)
            v = reinterpret_cast<const float4*>(h1d)[g * (HID / 4) + k4];
        *reinterpret_cast<float4*>(&hs[r][k4 * 4]) = v;
    }
    __syncthreads();

    const int j  = tid % 96;
    const int rg = tid / 96;
    float acc[32];
#pragma unroll
    for (int r = 0; r < 32; ++r) acc[r] = 0.f;

    for (int k = 0; k < HID; k += 4) {
        float w0 = Wcat[(k + 0) * 96 + j];
        float w1 = Wcat[(k + 1) * 96 + j];
        float w2 = Wcat[(k + 2) * 96 + j];
        float w3 = Wcat[(k + 3) * 96 + j];
#pragma unroll
        for (int r = 0; r < 32; ++r) {
            const float4 hv = *reinterpret_cast<const float4*>(&hs[rg * 32 + r][k]);
            acc[r] = fmaf(hv.x, w0, acc[r]);
            acc[r] = fmaf(hv.y, w1, acc[r]);
            acc[r] = fmaf(hv.z, w2, acc[r]);
            acc[r] = fmaf(hv.w, w3, acc[r]);
        }
    }

#pragma unroll
    for (int r = 0; r < 32; ++r) {
        int g = row0 + rg * 32 + r;
        if (g >= N_NODES) continue;
        if (j < NCLS)                 out[g * NCLS + j] = acc[r] + b2[j];
        else if (j >= 48 && j < 95)   z2[g * NCLS + (j - 48)] = acc[r];
    }
}

// ============ pull aggregation, layer 2 (sum z2, fuse mean + add) ============
// 64 threads per node (lanes 0..46 active), 4 nodes per 256-thread block
__global__ __launch_bounds__(256) void agg2(
    const int* __restrict__ row_ptr, const int* __restrict__ csr_src,
    const float* __restrict__ z2, const float* __restrict__ invdeg,
    float* __restrict__ out)
{
    int node = blockIdx.x * 4 + (threadIdx.x >> 6);
    int j = threadIdx.x & 63;
    if (node >= N_NODES || j >= NCLS) return;
    int beg = row_ptr[node], end = row_ptr[node + 1];
    float s = 0.f;
    int e = beg;
    for (; e + 1 < end; e += 2) {
        int s0 = csr_src[e], s1 = csr_src[e + 1];
        float v0 = z2[s0 * NCLS + j];
        float v1 = z2[s1 * NCLS + j];
        s += v0 + v1;
    }
    if (e < end) s += z2[csr_src[e] * NCLS + j];
    out[node * NCLS + j] += s * invdeg[node];
}

extern "C" void kernel_launch(void* const* d_in, const int* in_sizes, int n_in,
                              void* d_out, int out_size, void* d_ws, size_t ws_size,
                              hipStream_t stream)
{
    const float* x   = (const float*)d_in[0];
    const int*   src = (const int*)  d_in[1];
    const int*   dst = (const int*)  d_in[2];
    const float* Ws1 = (const float*)d_in[3];
    const float* Wn1 = (const float*)d_in[4];
    const float* b1  = (const float*)d_in[5];
    const float* Ws2 = (const float*)d_in[6];
    const float* Wn2 = (const float*)d_in[7];
    const float* b2  = (const float*)d_in[8];
    float* out = (float*)d_out;

    // ---- workspace layout ----
    // int region (first 1,000,000 "float slots" = 4 MB):
    int*   wsi     = (int*)d_ws;
    int*   deg     = wsi;               //  50,000
    int*   row_ptr = wsi + 50000;       //  50,001
    int*   cursor  = wsi + 100008;      //  50,000
    int*   csr_src = wsi + 150016;      // 800,000   (ends at 950,016)
    // float region:
    float* wsf    = (float*)d_ws;
    float* invdeg = wsf + 1000000;      //     50,000
    float* accx   = wsf + 1050000;      //  5,000,000
    float* z2     = accx;               //  aliases accx (dead after gemm1)
    float* h1d    = wsf + 6050000;      // 12,800,000
    float* wcat   = wsf + 18850000;     //     24,576  (total ~75.5 MB)

    hipMemsetAsync(deg, 0, (size_t)50000 * sizeof(int), stream);

    count_deg<<<(N_EDGES + 255) / 256, 256, 0, stream>>>(dst, deg);
    scan_deg <<<1, 1024, 0, stream>>>(deg, row_ptr, cursor, invdeg);
    fill_csr <<<(N_EDGES + 255) / 256, 256, 0, stream>>>(src, dst, cursor, csr_src);

    agg1<<<(N_NODES + 1) / 2, 256, 0, stream>>>(row_ptr, csr_src, x, accx);
    build_wcat<<<(HID * 96 + 255) / 256, 256, 0, stream>>>(Ws2, Wn2, wcat);
    gemm1_fused<<<(N_NODES + 31) / 32, 256, 0, stream>>>(x, accx, invdeg, Ws1, Wn1, b1, h1d);
    gemm2<<<(N_NODES + 63) / 64, 192, 0, stream>>>(h1d, wcat, b2, out, z2);
    agg2<<<(N_NODES + 3) / 4, 256, 0, stream>>>(row_ptr, csr_src, z2, invdeg, out);
}

// Round 4
// 566.164 us; speedup vs baseline: 1.4643x; 1.1132x over previous
//
#include <hip/hip_runtime.h>
#include <stdint.h>

#define N_NODES 50000
#define N_EDGES 800000
#define IN_F    100
#define HID     256
#define NCLS    47

__device__ __forceinline__ uint32_t rotl32(uint32_t v, uint32_t r) {
    return (v << r) | (v >> (32u - r));
}

// JAX threefry2x32, key=(0,42), partitionable mode: counter=(0,i), bits=x0^x1.
// bernoulli(0.5) keeps iff MSB==0.  (verified passing in round 2)
__device__ __forceinline__ uint32_t jax_bits(uint32_t i) {
    const uint32_t ks0 = 0u, ks1 = 42u, ks2 = 0x1BD11BDAu ^ 42u;
    uint32_t x0 = 0u + ks0;
    uint32_t x1 = i + ks1;
    x0 += x1; x1 = rotl32(x1, 13); x1 ^= x0;
    x0 += x1; x1 = rotl32(x1, 15); x1 ^= x0;
    x0 += x1; x1 = rotl32(x1, 26); x1 ^= x0;
    x0 += x1; x1 = rotl32(x1,  6); x1 ^= x0;
    x0 += ks1; x1 += ks2 + 1u;
    x0 += x1; x1 = rotl32(x1, 17); x1 ^= x0;
    x0 += x1; x1 = rotl32(x1, 29); x1 ^= x0;
    x0 += x1; x1 = rotl32(x1, 16); x1 ^= x0;
    x0 += x1; x1 = rotl32(x1, 24); x1 ^= x0;
    x0 += ks2; x1 += ks0 + 2u;
    x0 += x1; x1 = rotl32(x1, 13); x1 ^= x0;
    x0 += x1; x1 = rotl32(x1, 15); x1 ^= x0;
    x0 += x1; x1 = rotl32(x1, 26); x1 ^= x0;
    x0 += x1; x1 = rotl32(x1,  6); x1 ^= x0;
    x0 += ks0; x1 += ks1 + 3u;
    x0 += x1; x1 = rotl32(x1, 17); x1 ^= x0;
    x0 += x1; x1 = rotl32(x1, 29); x1 ^= x0;
    x0 += x1; x1 = rotl32(x1, 16); x1 ^= x0;
    x0 += x1; x1 = rotl32(x1, 24); x1 ^= x0;
    x0 += ks1; x1 += ks2 + 4u;
    x0 += x1; x1 = rotl32(x1, 13); x1 ^= x0;
    x0 += x1; x1 = rotl32(x1, 15); x1 ^= x0;
    x0 += x1; x1 = rotl32(x1, 26); x1 ^= x0;
    x0 += x1; x1 = rotl32(x1,  6); x1 ^= x0;
    x0 += ks2; x1 += ks0 + 5u;
    return x0 ^ x1;
}

// ======================= CSR build (dst -> srcs) =============================
__global__ __launch_bounds__(256) void count_deg(
    const int* __restrict__ dst, int* __restrict__ deg)
{
    int e = blockIdx.x * 256 + threadIdx.x;
    if (e < N_EDGES) atomicAdd(&deg[dst[e]], 1);
}

__global__ __launch_bounds__(1024) void scan_deg(
    const int* __restrict__ deg, int* __restrict__ row_ptr,
    int* __restrict__ cursor, float* __restrict__ invdeg)
{
    __shared__ int sums[1024];
    const int tid = threadIdx.x;
    const int base = tid * 49;   // 1024*49 = 50176 >= 50000
    int s = 0;
    for (int k = 0; k < 49; ++k) {
        int idx = base + k;
        if (idx < N_NODES) s += deg[idx];
    }
    sums[tid] = s;
    __syncthreads();
    for (int off = 1; off < 1024; off <<= 1) {
        int v = 0;
        if (tid >= off) v = sums[tid - off];
        __syncthreads();
        if (tid >= off) sums[tid] += v;
        __syncthreads();
    }
    int run = (tid > 0) ? sums[tid - 1] : 0;
    for (int k = 0; k < 49; ++k) {
        int idx = base + k;
        if (idx < N_NODES) {
            int d = deg[idx];
            row_ptr[idx] = run;
            cursor[idx]  = run;
            invdeg[idx]  = 1.0f / fmaxf((float)d, 1.0f);
            run += d;
        }
    }
    if (tid == 1023) row_ptr[N_NODES] = sums[1023];
}

__global__ __launch_bounds__(256) void fill_csr(
    const int* __restrict__ src, const int* __restrict__ dst,
    int* __restrict__ cursor, int* __restrict__ csr_src)
{
    int e = blockIdx.x * 256 + threadIdx.x;
    if (e >= N_EDGES) return;
    int pos = atomicAdd(&cursor[dst[e]], 1);
    csr_src[pos] = src[e];
}

// ======== pull aggregation, layer 1 (MEAN of x over in-edges, fused) ========
__global__ __launch_bounds__(256) void agg1(
    const int* __restrict__ row_ptr, const int* __restrict__ csr_src,
    const float* __restrict__ x, const float* __restrict__ invdeg,
    float* __restrict__ accm)
{
    int node = blockIdx.x * 2 + (threadIdx.x >> 7);
    int j = threadIdx.x & 127;
    if (node >= N_NODES || j >= IN_F) return;
    int beg = row_ptr[node], end = row_ptr[node + 1];
    float s = 0.f;
    int e = beg;
    for (; e + 1 < end; e += 2) {
        int s0 = csr_src[e], s1 = csr_src[e + 1];
        float v0 = x[s0 * IN_F + j];
        float v1 = x[s1 * IN_F + j];
        s += v0 + v1;
    }
    if (e < end) s += x[csr_src[e] * IN_F + j];
    accm[node * IN_F + j] = s * invdeg[node];
}

// ---------------- fused layer-1 GEMM + bias + ReLU + dropout -----------------
// 64 rows x 256 cols per block; 256 threads; thread = 16 rows x 4 cols
__global__ __launch_bounds__(256) void gemm1_fused(
    const float* __restrict__ x, const float* __restrict__ accm,
    const float* __restrict__ Wself, const float* __restrict__ Wneigh,
    const float* __restrict__ b1, float* __restrict__ h1d)
{
    __shared__ float xs[64][2 * IN_F];   // 51.2 KB: [.][0..99]=x, [.][100..199]=mean
    const int row0 = blockIdx.x * 64;
    const int tid  = threadIdx.x;
    const int nrow = min(64, N_NODES - row0);

    // stage x rows (fully coalesced: contiguous region)
    {
        const float4* xg = (const float4*)(x + (size_t)row0 * IN_F);
        const float4* mg = (const float4*)(accm + (size_t)row0 * IN_F);
        for (int idx = tid; idx < 64 * (IN_F / 4); idx += 256) {
            int r = idx / (IN_F / 4), c4 = idx % (IN_F / 4);
            float4 xv = make_float4(0.f,0.f,0.f,0.f), mv = xv;
            if (r < nrow) { xv = xg[idx]; mv = mg[idx]; }
            *reinterpret_cast<float4*>(&xs[r][c4 * 4])        = xv;
            *reinterpret_cast<float4*>(&xs[r][IN_F + c4 * 4]) = mv;
        }
    }
    __syncthreads();

    const int jb = tid & 63;          // column base (+c*64)
    const int r0 = (tid >> 6) * 16;   // row group: 4 groups x 16 rows

    float acc[16][4];
#pragma unroll
    for (int r = 0; r < 16; ++r)
#pragma unroll
        for (int c = 0; c < 4; ++c) acc[r][c] = 0.f;

#define K_BLOCK(W, KOFF)                                                    \
    for (int ks = 0; ks < IN_F / 4; ++ks) {                                 \
        const int k = ks * 4;                                               \
        float w[4][4];                                                      \
        _Pragma("unroll")                                                   \
        for (int kk = 0; kk < 4; ++kk)                                      \
            _Pragma("unroll")                                               \
            for (int c = 0; c < 4; ++c)                                     \
                w[kk][c] = W[(k + kk) * HID + jb + c * 64];                 \
        _Pragma("unroll")                                                   \
        for (int rr = 0; rr < 16; ++rr) {                                   \
            const float4 xv = *reinterpret_cast<const float4*>(             \
                &xs[r0 + rr][KOFF + k]);                                    \
            _Pragma("unroll")                                               \
            for (int c = 0; c < 4; ++c) {                                   \
                acc[rr][c] = fmaf(xv.x, w[0][c], acc[rr][c]);               \
                acc[rr][c] = fmaf(xv.y, w[1][c], acc[rr][c]);               \
                acc[rr][c] = fmaf(xv.z, w[2][c], acc[rr][c]);               \
                acc[rr][c] = fmaf(xv.w, w[3][c], acc[rr][c]);               \
            }                                                               \
        }                                                                   \
    }

    K_BLOCK(Wself, 0)
    K_BLOCK(Wneigh, IN_F)
#undef K_BLOCK

    float bj[4];
#pragma unroll
    for (int c = 0; c < 4; ++c) bj[c] = b1[jb + c * 64];

#pragma unroll
    for (int rr = 0; rr < 16; ++rr) {
        int g = row0 + r0 + rr;
        if (g - row0 >= nrow) continue;
#pragma unroll
        for (int c = 0; c < 4; ++c) {
            int j = jb + c * 64;
            float v = fmaxf(acc[rr][c] + bj[c], 0.f);
            uint32_t bits = jax_bits((uint32_t)(g * HID + j));
            v = (bits & 0x80000000u) ? 0.f : v * 2.0f;
            h1d[(size_t)g * HID + j] = v;
        }
    }
}

// ------------- build padded combined layer-2 weight [256 x 128] --------------
// cols 0..46 = W_self2, cols 48..94 = W_neigh2, rest 0
__global__ __launch_bounds__(256) void build_wcat(
    const float* __restrict__ Ws2, const float* __restrict__ Wn2,
    float* __restrict__ Wcat)
{
    int gid = blockIdx.x * 256 + threadIdx.x;
    if (gid >= HID * 128) return;
    int k = gid >> 7, j = gid & 127;
    float v = 0.f;
    if (j < NCLS)                 v = Ws2[k * NCLS + j];
    else if (j >= 48 && j < 95)   v = Wn2[k * NCLS + (j - 48)];
    Wcat[gid] = v;
}

// ------------- layer-2 GEMM: self -> d_out (with b2), z2 -> ws ---------------
// 64 rows per block; 256 threads; thread = 16 rows x 2 cols (jb, jb+64)
__global__ __launch_bounds__(256) void gemm2(
    const float* __restrict__ h1d, const float* __restrict__ Wcat,
    const float* __restrict__ b2, float* __restrict__ out, float* __restrict__ z2)
{
    __shared__ float hs[64][HID];   // 64 KiB
    const int row0 = blockIdx.x * 64;
    const int tid  = threadIdx.x;
    const int nrow = min(64, N_NODES - row0);

    {
        const float4* hg = (const float4*)(h1d + (size_t)row0 * HID);
        for (int idx = tid; idx < 64 * (HID / 4); idx += 256) {
            int r = idx / (HID / 4);
            float4 v = make_float4(0.f,0.f,0.f,0.f);
            if (r < nrow) v = hg[idx];
            reinterpret_cast<float4*>(hs)[idx] = v;
        }
    }
    __syncthreads();

    const int jb = tid & 63;
    const int r0 = (tid >> 6) * 16;

    float acc[16][2];
#pragma unroll
    for (int r = 0; r < 16; ++r) { acc[r][0] = 0.f; acc[r][1] = 0.f; }

    for (int ks = 0; ks < HID / 4; ++ks) {
        const int k = ks * 4;
        float w[4][2];
#pragma unroll
        for (int kk = 0; kk < 4; ++kk) {
            w[kk][0] = Wcat[(k + kk) * 128 + jb];
            w[kk][1] = Wcat[(k + kk) * 128 + jb + 64];
        }
#pragma unroll
        for (int rr = 0; rr < 16; ++rr) {
            const float4 hv = *reinterpret_cast<const float4*>(&hs[r0 + rr][k]);
#pragma unroll
            for (int c = 0; c < 2; ++c) {
                acc[rr][c] = fmaf(hv.x, w[0][c], acc[rr][c]);
                acc[rr][c] = fmaf(hv.y, w[1][c], acc[rr][c]);
                acc[rr][c] = fmaf(hv.z, w[2][c], acc[rr][c]);
                acc[rr][c] = fmaf(hv.w, w[3][c], acc[rr][c]);
            }
        }
    }

#pragma unroll
    for (int rr = 0; rr < 16; ++rr) {
        int g = row0 + r0 + rr;
        if (g - row0 >= nrow) continue;
#pragma unroll
        for (int c = 0; c < 2; ++c) {
            int j = jb + c * 64;
            if (j < NCLS)               out[(size_t)g * NCLS + j] = acc[rr][c] + b2[j];
            else if (j >= 48 && j < 95) z2[(size_t)g * NCLS + (j - 48)] = acc[rr][c];
        }
    }
}

// ============ pull aggregation, layer 2 (sum z2, fuse mean + add) ============
__global__ __launch_bounds__(256) void agg2(
    const int* __restrict__ row_ptr, const int* __restrict__ csr_src,
    const float* __restrict__ z2, const float* __restrict__ invdeg,
    float* __restrict__ out)
{
    int node = blockIdx.x * 4 + (threadIdx.x >> 6);
    int j = threadIdx.x & 63;
    if (node >= N_NODES || j >= NCLS) return;
    int beg = row_ptr[node], end = row_ptr[node + 1];
    float s = 0.f;
    int e = beg;
    for (; e + 1 < end; e += 2) {
        int s0 = csr_src[e], s1 = csr_src[e + 1];
        float v0 = z2[s0 * NCLS + j];
        float v1 = z2[s1 * NCLS + j];
        s += v0 + v1;
    }
    if (e < end) s += z2[csr_src[e] * NCLS + j];
    out[node * NCLS + j] += s * invdeg[node];
}

extern "C" void kernel_launch(void* const* d_in, const int* in_sizes, int n_in,
                              void* d_out, int out_size, void* d_ws, size_t ws_size,
                              hipStream_t stream)
{
    const float* x   = (const float*)d_in[0];
    const int*   src = (const int*)  d_in[1];
    const int*   dst = (const int*)  d_in[2];
    const float* Ws1 = (const float*)d_in[3];
    const float* Wn1 = (const float*)d_in[4];
    const float* b1  = (const float*)d_in[5];
    const float* Ws2 = (const float*)d_in[6];
    const float* Wn2 = (const float*)d_in[7];
    const float* b2  = (const float*)d_in[8];
    float* out = (float*)d_out;

    // ---- workspace layout ----
    int*   wsi     = (int*)d_ws;
    int*   deg     = wsi;               //  50,000
    int*   row_ptr = wsi + 50000;       //  50,001
    int*   cursor  = wsi + 100008;      //  50,000
    int*   csr_src = wsi + 150016;      // 800,000
    float* wsf    = (float*)d_ws;
    float* invdeg = wsf + 1000000;      //     50,000
    float* accm   = wsf + 1050000;      //  5,000,000 (mean-aggregated x)
    float* z2     = accm;               //  aliases accm (dead after gemm1)
    float* h1d    = wsf + 6050000;      // 12,800,000
    float* wcat   = wsf + 18850000;     //     32,768  (total ~75.5 MB)

    hipMemsetAsync(deg, 0, (size_t)50000 * sizeof(int), stream);

    count_deg<<<(N_EDGES + 255) / 256, 256, 0, stream>>>(dst, deg);
    scan_deg <<<1, 1024, 0, stream>>>(deg, row_ptr, cursor, invdeg);
    fill_csr <<<(N_EDGES + 255) / 256, 256, 0, stream>>>(src, dst, cursor, csr_src);

    agg1<<<(N_NODES + 1) / 2, 256, 0, stream>>>(row_ptr, csr_src, x, invdeg, accm);
    build_wcat<<<(HID * 128 + 255) / 256, 256, 0, stream>>>(Ws2, Wn2, wcat);
    gemm1_fused<<<(N_NODES + 63) / 64, 256, 0, stream>>>(x, accm, Ws1, Wn1, b1, h1d);
    gemm2<<<(N_NODES + 63) / 64, 256, 0, stream>>>(h1d, wcat, b2, out, z2);
    agg2<<<(N_NODES + 3) / 4, 256, 0, stream>>>(row_ptr, csr_src, z2, invdeg, out);
}

// Round 5
// 436.029 us; speedup vs baseline: 1.9013x; 1.2985x over previous
//
#include <hip/hip_runtime.h>
#include <stdint.h>

#define N_NODES 50000
#define N_EDGES 800000
#define IN_F    100
#define HID     256
#define NCLS    47
#define SCAN_NB ((N_NODES + 255) / 256)   // 196 blocks

__device__ __forceinline__ uint32_t rotl32(uint32_t v, uint32_t r) {
    return (v << r) | (v >> (32u - r));
}

// JAX threefry2x32, key=(0,42), partitionable mode: counter=(0,i), bits=x0^x1.
// bernoulli(0.5) keeps iff MSB==0.  (verified passing in round 2)
__device__ __forceinline__ uint32_t jax_bits(uint32_t i) {
    const uint32_t ks0 = 0u, ks1 = 42u, ks2 = 0x1BD11BDAu ^ 42u;
    uint32_t x0 = 0u + ks0;
    uint32_t x1 = i + ks1;
    x0 += x1; x1 = rotl32(x1, 13); x1 ^= x0;
    x0 += x1; x1 = rotl32(x1, 15); x1 ^= x0;
    x0 += x1; x1 = rotl32(x1, 26); x1 ^= x0;
    x0 += x1; x1 = rotl32(x1,  6); x1 ^= x0;
    x0 += ks1; x1 += ks2 + 1u;
    x0 += x1; x1 = rotl32(x1, 17); x1 ^= x0;
    x0 += x1; x1 = rotl32(x1, 29); x1 ^= x0;
    x0 += x1; x1 = rotl32(x1, 16); x1 ^= x0;
    x0 += x1; x1 = rotl32(x1, 24); x1 ^= x0;
    x0 += ks2; x1 += ks0 + 2u;
    x0 += x1; x1 = rotl32(x1, 13); x1 ^= x0;
    x0 += x1; x1 = rotl32(x1, 15); x1 ^= x0;
    x0 += x1; x1 = rotl32(x1, 26); x1 ^= x0;
    x0 += x1; x1 = rotl32(x1,  6); x1 ^= x0;
    x0 += ks0; x1 += ks1 + 3u;
    x0 += x1; x1 = rotl32(x1, 17); x1 ^= x0;
    x0 += x1; x1 = rotl32(x1, 29); x1 ^= x0;
    x0 += x1; x1 = rotl32(x1, 16); x1 ^= x0;
    x0 += x1; x1 = rotl32(x1, 24); x1 ^= x0;
    x0 += ks1; x1 += ks2 + 4u;
    x0 += x1; x1 = rotl32(x1, 13); x1 ^= x0;
    x0 += x1; x1 = rotl32(x1, 15); x1 ^= x0;
    x0 += x1; x1 = rotl32(x1, 26); x1 ^= x0;
    x0 += x1; x1 = rotl32(x1,  6); x1 ^= x0;
    x0 += ks2; x1 += ks0 + 5u;
    return x0 ^ x1;
}

// ======================= CSR build (dst -> srcs) =============================
__global__ __launch_bounds__(256) void count_deg(
    const int* __restrict__ dst, int* __restrict__ deg)
{
    int e = blockIdx.x * 256 + threadIdx.x;
    if (e < N_EDGES) atomicAdd(&deg[dst[e]], 1);
}

// phase A: per-block degree sums
__global__ __launch_bounds__(256) void scan_phaseA(
    const int* __restrict__ deg, int* __restrict__ bsum)
{
    __shared__ int red[256];
    int i = blockIdx.x * 256 + threadIdx.x;
    int v = (i < N_NODES) ? deg[i] : 0;
    red[threadIdx.x] = v;
    __syncthreads();
    for (int off = 128; off > 0; off >>= 1) {
        if (threadIdx.x < off) red[threadIdx.x] += red[threadIdx.x + off];
        __syncthreads();
    }
    if (threadIdx.x == 0) bsum[blockIdx.x] = red[0];
}

// phase B: exclusive scan of the SCAN_NB block sums (single small block)
__global__ __launch_bounds__(256) void scan_phaseB(
    const int* __restrict__ bsum, int* __restrict__ boff)
{
    __shared__ int s[256];
    int tid = threadIdx.x;
    int v = (tid < SCAN_NB) ? bsum[tid] : 0;
    s[tid] = v;
    __syncthreads();
    for (int off = 1; off < 256; off <<= 1) {
        int t = (tid >= off) ? s[tid - off] : 0;
        __syncthreads();
        s[tid] += t;
        __syncthreads();
    }
    if (tid < SCAN_NB) boff[tid] = s[tid] - v;   // exclusive
}

// phase C: in-block scan + block offset -> row_ptr / cursor / invdeg
__global__ __launch_bounds__(256) void scan_phaseC(
    const int* __restrict__ deg, const int* __restrict__ boff,
    int* __restrict__ row_ptr, int* __restrict__ cursor,
    float* __restrict__ invdeg)
{
    __shared__ int s[256];
    int tid = threadIdx.x;
    int i = blockIdx.x * 256 + tid;
    int d = (i < N_NODES) ? deg[i] : 0;
    s[tid] = d;
    __syncthreads();
    for (int off = 1; off < 256; off <<= 1) {
        int t = (tid >= off) ? s[tid - off] : 0;
        __syncthreads();
        s[tid] += t;
        __syncthreads();
    }
    int excl = boff[blockIdx.x] + s[tid] - d;
    if (i < N_NODES) {
        row_ptr[i] = excl;
        cursor[i]  = excl;
        invdeg[i]  = 1.0f / fmaxf((float)d, 1.0f);
        if (i == N_NODES - 1) row_ptr[N_NODES] = excl + d;
    }
}

__global__ __launch_bounds__(256) void fill_csr(
    const int* __restrict__ src, const int* __restrict__ dst,
    int* __restrict__ cursor, int* __restrict__ csr_src)
{
    int e = blockIdx.x * 256 + threadIdx.x;
    if (e >= N_EDGES) return;
    int pos = atomicAdd(&cursor[dst[e]], 1);
    csr_src[pos] = src[e];
}

// ======== pull aggregation, layer 1 (MEAN of x over in-edges, fused) ========
__global__ __launch_bounds__(256) void agg1(
    const int* __restrict__ row_ptr, const int* __restrict__ csr_src,
    const float* __restrict__ x, const float* __restrict__ invdeg,
    float* __restrict__ accm)
{
    int node = blockIdx.x * 2 + (threadIdx.x >> 7);
    int j = threadIdx.x & 127;
    if (node >= N_NODES || j >= IN_F) return;
    int beg = row_ptr[node], end = row_ptr[node + 1];
    float s = 0.f;
    int e = beg;
    for (; e + 1 < end; e += 2) {
        int s0 = csr_src[e], s1 = csr_src[e + 1];
        float v0 = x[s0 * IN_F + j];
        float v1 = x[s1 * IN_F + j];
        s += v0 + v1;
    }
    if (e < end) s += x[csr_src[e] * IN_F + j];
    accm[node * IN_F + j] = s * invdeg[node];
}

// ---------------- fused layer-1 GEMM + bias + ReLU + dropout -----------------
// 64 rows x 256 cols per block; 256 threads; thread = 16 rows x 4 cols
__global__ __launch_bounds__(256) void gemm1_fused(
    const float* __restrict__ x, const float* __restrict__ accm,
    const float* __restrict__ Wself, const float* __restrict__ Wneigh,
    const float* __restrict__ b1, float* __restrict__ h1d)
{
    __shared__ float xs[64][2 * IN_F];   // 51.2 KB
    const int row0 = blockIdx.x * 64;
    const int tid  = threadIdx.x;
    const int nrow = min(64, N_NODES - row0);

    {
        const float4* xg = (const float4*)(x + (size_t)row0 * IN_F);
        const float4* mg = (const float4*)(accm + (size_t)row0 * IN_F);
        for (int idx = tid; idx < 64 * (IN_F / 4); idx += 256) {
            int r = idx / (IN_F / 4), c4 = idx % (IN_F / 4);
            float4 xv = make_float4(0.f,0.f,0.f,0.f), mv = xv;
            if (r < nrow) { xv = xg[idx]; mv = mg[idx]; }
            *reinterpret_cast<float4*>(&xs[r][c4 * 4])        = xv;
            *reinterpret_cast<float4*>(&xs[r][IN_F + c4 * 4]) = mv;
        }
    }
    __syncthreads();

    const int jb = tid & 63;
    const int r0 = (tid >> 6) * 16;

    float acc[16][4];
#pragma unroll
    for (int r = 0; r < 16; ++r)
#pragma unroll
        for (int c = 0; c < 4; ++c) acc[r][c] = 0.f;

#define K_BLOCK(W, KOFF)                                                    \
    for (int ks = 0; ks < IN_F / 4; ++ks) {                                 \
        const int k = ks * 4;                                               \
        float w[4][4];                                                      \
        _Pragma("unroll")                                                   \
        for (int kk = 0; kk < 4; ++kk)                                      \
            _Pragma("unroll")                                               \
            for (int c = 0; c < 4; ++c)                                     \
                w[kk][c] = W[(k + kk) * HID + jb + c * 64];                 \
        _Pragma("unroll")                                                   \
        for (int rr = 0; rr < 16; ++rr) {                                   \
            const float4 xv = *reinterpret_cast<const float4*>(             \
                &xs[r0 + rr][KOFF + k]);                                    \
            _Pragma("unroll")                                               \
            for (int c = 0; c < 4; ++c) {                                   \
                acc[rr][c] = fmaf(xv.x, w[0][c], acc[rr][c]);               \
                acc[rr][c] = fmaf(xv.y, w[1][c], acc[rr][c]);               \
                acc[rr][c] = fmaf(xv.z, w[2][c], acc[rr][c]);               \
                acc[rr][c] = fmaf(xv.w, w[3][c], acc[rr][c]);               \
            }                                                               \
        }                                                                   \
    }

    K_BLOCK(Wself, 0)
    K_BLOCK(Wneigh, IN_F)
#undef K_BLOCK

    float bj[4];
#pragma unroll
    for (int c = 0; c < 4; ++c) bj[c] = b1[jb + c * 64];

#pragma unroll
    for (int rr = 0; rr < 16; ++rr) {
        int g = row0 + r0 + rr;
        if (g - row0 >= nrow) continue;
#pragma unroll
        for (int c = 0; c < 4; ++c) {
            int j = jb + c * 64;
            float v = fmaxf(acc[rr][c] + bj[c], 0.f);
            uint32_t bits = jax_bits((uint32_t)(g * HID + j));
            v = (bits & 0x80000000u) ? 0.f : v * 2.0f;
            h1d[(size_t)g * HID + j] = v;
        }
    }
}

// ------------- build padded combined layer-2 weight [256 x 128] --------------
__global__ __launch_bounds__(256) void build_wcat(
    const float* __restrict__ Ws2, const float* __restrict__ Wn2,
    float* __restrict__ Wcat)
{
    int gid = blockIdx.x * 256 + threadIdx.x;
    if (gid >= HID * 128) return;
    int k = gid >> 7, j = gid & 127;
    float v = 0.f;
    if (j < NCLS)                 v = Ws2[k * NCLS + j];
    else if (j >= 48 && j < 95)   v = Wn2[k * NCLS + (j - 48)];
    Wcat[gid] = v;
}

// ------------- layer-2 GEMM: self -> d_out (with b2), z2 -> ws ---------------
__global__ __launch_bounds__(256) void gemm2(
    const float* __restrict__ h1d, const float* __restrict__ Wcat,
    const float* __restrict__ b2, float* __restrict__ out, float* __restrict__ z2)
{
    __shared__ float hs[64][HID];   // 64 KiB
    const int row0 = blockIdx.x * 64;
    const int tid  = threadIdx.x;
    const int nrow = min(64, N_NODES - row0);

    {
        const float4* hg = (const float4*)(h1d + (size_t)row0 * HID);
        for (int idx = tid; idx < 64 * (HID / 4); idx += 256) {
            int r = idx / (HID / 4);
            float4 v = make_float4(0.f,0.f,0.f,0.f);
            if (r < nrow) v = hg[idx];
            reinterpret_cast<float4*>(hs)[idx] = v;
        }
    }
    __syncthreads();

    const int jb = tid & 63;
    const int r0 = (tid >> 6) * 16;

    float acc[16][2];
#pragma unroll
    for (int r = 0; r < 16; ++r) { acc[r][0] = 0.f; acc[r][1] = 0.f; }

    for (int ks = 0; ks < HID / 4; ++ks) {
        const int k = ks * 4;
        float w[4][2];
#pragma unroll
        for (int kk = 0; kk < 4; ++kk) {
            w[kk][0] = Wcat[(k + kk) * 128 + jb];
            w[kk][1] = Wcat[(k + kk) * 128 + jb + 64];
        }
#pragma unroll
        for (int rr = 0; rr < 16; ++rr) {
            const float4 hv = *reinterpret_cast<const float4*>(&hs[r0 + rr][k]);
#pragma unroll
            for (int c = 0; c < 2; ++c) {
                acc[rr][c] = fmaf(hv.x, w[0][c], acc[rr][c]);
                acc[rr][c] = fmaf(hv.y, w[1][c], acc[rr][c]);
                acc[rr][c] = fmaf(hv.z, w[2][c], acc[rr][c]);
                acc[rr][c] = fmaf(hv.w, w[3][c], acc[rr][c]);
            }
        }
    }

#pragma unroll
    for (int rr = 0; rr < 16; ++rr) {
        int g = row0 + r0 + rr;
        if (g - row0 >= nrow) continue;
#pragma unroll
        for (int c = 0; c < 2; ++c) {
            int j = jb + c * 64;
            if (j < NCLS)               out[(size_t)g * NCLS + j] = acc[rr][c] + b2[j];
            else if (j >= 48 && j < 95) z2[(size_t)g * NCLS + (j - 48)] = acc[rr][c];
        }
    }
}

// ============ pull aggregation, layer 2 (sum z2, fuse mean + add) ============
__global__ __launch_bounds__(256) void agg2(
    const int* __restrict__ row_ptr, const int* __restrict__ csr_src,
    const float* __restrict__ z2, const float* __restrict__ invdeg,
    float* __restrict__ out)
{
    int node = blockIdx.x * 4 + (threadIdx.x >> 6);
    int j = threadIdx.x & 63;
    if (node >= N_NODES || j >= NCLS) return;
    int beg = row_ptr[node], end = row_ptr[node + 1];
    float s = 0.f;
    int e = beg;
    for (; e + 1 < end; e += 2) {
        int s0 = csr_src[e], s1 = csr_src[e + 1];
        float v0 = z2[s0 * NCLS + j];
        float v1 = z2[s1 * NCLS + j];
        s += v0 + v1;
    }
    if (e < end) s += z2[csr_src[e] * NCLS + j];
    out[node * NCLS + j] += s * invdeg[node];
}

extern "C" void kernel_launch(void* const* d_in, const int* in_sizes, int n_in,
                              void* d_out, int out_size, void* d_ws, size_t ws_size,
                              hipStream_t stream)
{
    const float* x   = (const float*)d_in[0];
    const int*   src = (const int*)  d_in[1];
    const int*   dst = (const int*)  d_in[2];
    const float* Ws1 = (const float*)d_in[3];
    const float* Wn1 = (const float*)d_in[4];
    const float* b1  = (const float*)d_in[5];
    const float* Ws2 = (const float*)d_in[6];
    const float* Wn2 = (const float*)d_in[7];
    const float* b2  = (const float*)d_in[8];
    float* out = (float*)d_out;

    // ---- workspace layout ----
    int*   wsi     = (int*)d_ws;
    int*   deg     = wsi;               //  50,000
    int*   row_ptr = wsi + 50000;       //  50,001
    int*   cursor  = wsi + 100008;      //  50,000
    int*   csr_src = wsi + 150016;      // 800,000  (ends 950,016)
    int*   bsum    = wsi + 950016;      //     196
    int*   boff    = wsi + 950512;      //     196
    float* wsf    = (float*)d_ws;
    float* invdeg = wsf + 1000000;      //     50,000
    float* accm   = wsf + 1050000;      //  5,000,000 (mean-aggregated x)
    float* z2     = accm;               //  aliases accm (dead after gemm1)
    float* h1d    = wsf + 6050000;      // 12,800,000
    float* wcat   = wsf + 18850000;     //     32,768  (total ~75.5 MB)

    hipMemsetAsync(deg, 0, (size_t)50000 * sizeof(int), stream);

    count_deg  <<<(N_EDGES + 255) / 256, 256, 0, stream>>>(dst, deg);
    scan_phaseA<<<SCAN_NB, 256, 0, stream>>>(deg, bsum);
    scan_phaseB<<<1, 256, 0, stream>>>(bsum, boff);
    scan_phaseC<<<SCAN_NB, 256, 0, stream>>>(deg, boff, row_ptr, cursor, invdeg);
    fill_csr   <<<(N_EDGES + 255) / 256, 256, 0, stream>>>(src, dst, cursor, csr_src);

    agg1<<<(N_NODES + 1) / 2, 256, 0, stream>>>(row_ptr, csr_src, x, invdeg, accm);
    build_wcat<<<(HID * 128 + 255) / 256, 256, 0, stream>>>(Ws2, Wn2, wcat);
    gemm1_fused<<<(N_NODES + 63) / 64, 256, 0, stream>>>(x, accm, Ws1, Wn1, b1, h1d);
    gemm2<<<(N_NODES + 63) / 64, 256, 0, stream>>>(h1d, wcat, b2, out, z2);
    agg2<<<(N_NODES + 3) / 4, 256, 0, stream>>>(row_ptr, csr_src, z2, invdeg, out);
}

// Round 6
// 350.526 us; speedup vs baseline: 2.3651x; 1.2439x over previous
//
#include <hip/hip_runtime.h>
#include <stdint.h>

#define N_NODES 50000
#define N_EDGES 800000
#define IN_F    100
#define HID     256
#define NCLS    47
#define K1      224   // 200 padded to 7*32
#define K1S     232   // LDS row stride (bank-spread)
#define K2      256
#define K2S     264
#define SCAN_NB ((N_NODES + 255) / 256)

typedef __bf16 bf16x8 __attribute__((ext_vector_type(8)));
typedef __bf16 bf16x4 __attribute__((ext_vector_type(4)));
typedef float  f32x4  __attribute__((ext_vector_type(4)));

__device__ __forceinline__ uint32_t rotl32(uint32_t v, uint32_t r) {
    return (v << r) | (v >> (32u - r));
}

// JAX threefry2x32, key=(0,42), partitionable: counter=(0,i), bits=x0^x1.
// bernoulli(0.5) keeps iff MSB==0.  (verified round 2)
__device__ __forceinline__ uint32_t jax_bits(uint32_t i) {
    const uint32_t ks0 = 0u, ks1 = 42u, ks2 = 0x1BD11BDAu ^ 42u;
    uint32_t x0 = 0u + ks0;
    uint32_t x1 = i + ks1;
    x0 += x1; x1 = rotl32(x1, 13); x1 ^= x0;
    x0 += x1; x1 = rotl32(x1, 15); x1 ^= x0;
    x0 += x1; x1 = rotl32(x1, 26); x1 ^= x0;
    x0 += x1; x1 = rotl32(x1,  6); x1 ^= x0;
    x0 += ks1; x1 += ks2 + 1u;
    x0 += x1; x1 = rotl32(x1, 17); x1 ^= x0;
    x0 += x1; x1 = rotl32(x1, 29); x1 ^= x0;
    x0 += x1; x1 = rotl32(x1, 16); x1 ^= x0;
    x0 += x1; x1 = rotl32(x1, 24); x1 ^= x0;
    x0 += ks2; x1 += ks0 + 2u;
    x0 += x1; x1 = rotl32(x1, 13); x1 ^= x0;
    x0 += x1; x1 = rotl32(x1, 15); x1 ^= x0;
    x0 += x1; x1 = rotl32(x1, 26); x1 ^= x0;
    x0 += x1; x1 = rotl32(x1,  6); x1 ^= x0;
    x0 += ks0; x1 += ks1 + 3u;
    x0 += x1; x1 = rotl32(x1, 17); x1 ^= x0;
    x0 += x1; x1 = rotl32(x1, 29); x1 ^= x0;
    x0 += x1; x1 = rotl32(x1, 16); x1 ^= x0;
    x0 += x1; x1 = rotl32(x1, 24); x1 ^= x0;
    x0 += ks1; x1 += ks2 + 4u;
    x0 += x1; x1 = rotl32(x1, 13); x1 ^= x0;
    x0 += x1; x1 = rotl32(x1, 15); x1 ^= x0;
    x0 += x1; x1 = rotl32(x1, 26); x1 ^= x0;
    x0 += x1; x1 = rotl32(x1,  6); x1 ^= x0;
    x0 += ks2; x1 += ks0 + 5u;
    return x0 ^ x1;
}

// ======================= CSR build (dst -> srcs) =============================
__global__ __launch_bounds__(256) void count_deg(
    const int* __restrict__ dst, int* __restrict__ deg)
{
    int e = blockIdx.x * 256 + threadIdx.x;
    if (e < N_EDGES) atomicAdd(&deg[dst[e]], 1);
}

__global__ __launch_bounds__(256) void scan_phaseA(
    const int* __restrict__ deg, int* __restrict__ bsum)
{
    __shared__ int red[256];
    int i = blockIdx.x * 256 + threadIdx.x;
    int v = (i < N_NODES) ? deg[i] : 0;
    red[threadIdx.x] = v;
    __syncthreads();
    for (int off = 128; off > 0; off >>= 1) {
        if (threadIdx.x < off) red[threadIdx.x] += red[threadIdx.x + off];
        __syncthreads();
    }
    if (threadIdx.x == 0) bsum[blockIdx.x] = red[0];
}

__global__ __launch_bounds__(256) void scan_phaseB(
    const int* __restrict__ bsum, int* __restrict__ boff)
{
    __shared__ int s[256];
    int tid = threadIdx.x;
    int v = (tid < SCAN_NB) ? bsum[tid] : 0;
    s[tid] = v;
    __syncthreads();
    for (int off = 1; off < 256; off <<= 1) {
        int t = (tid >= off) ? s[tid - off] : 0;
        __syncthreads();
        s[tid] += t;
        __syncthreads();
    }
    if (tid < SCAN_NB) boff[tid] = s[tid] - v;
}

__global__ __launch_bounds__(256) void scan_phaseC(
    const int* __restrict__ deg, const int* __restrict__ boff,
    int* __restrict__ row_ptr, int* __restrict__ cursor,
    float* __restrict__ invdeg)
{
    __shared__ int s[256];
    int tid = threadIdx.x;
    int i = blockIdx.x * 256 + tid;
    int d = (i < N_NODES) ? deg[i] : 0;
    s[tid] = d;
    __syncthreads();
    for (int off = 1; off < 256; off <<= 1) {
        int t = (tid >= off) ? s[tid - off] : 0;
        __syncthreads();
        s[tid] += t;
        __syncthreads();
    }
    int excl = boff[blockIdx.x] + s[tid] - d;
    if (i < N_NODES) {
        row_ptr[i] = excl;
        cursor[i]  = excl;
        invdeg[i]  = 1.0f / fmaxf((float)d, 1.0f);
        if (i == N_NODES - 1) row_ptr[N_NODES] = excl + d;
    }
}

__global__ __launch_bounds__(256) void fill_csr(
    const int* __restrict__ src, const int* __restrict__ dst,
    int* __restrict__ cursor, int* __restrict__ csr_src)
{
    int e = blockIdx.x * 256 + threadIdx.x;
    if (e >= N_EDGES) return;
    int pos = atomicAdd(&cursor[dst[e]], 1);
    csr_src[pos] = src[e];
}

// ======== pull aggregation, layer 1 (MEAN of x over in-edges, fused) ========
__global__ __launch_bounds__(256) void agg1(
    const int* __restrict__ row_ptr, const int* __restrict__ csr_src,
    const float* __restrict__ x, const float* __restrict__ invdeg,
    float* __restrict__ accm)
{
    int node = blockIdx.x * 2 + (threadIdx.x >> 7);
    int j = threadIdx.x & 127;
    if (node >= N_NODES || j >= IN_F) return;
    int beg = row_ptr[node], end = row_ptr[node + 1];
    float s = 0.f;
    int e = beg;
    for (; e + 1 < end; e += 2) {
        int s0 = csr_src[e], s1 = csr_src[e + 1];
        float v0 = x[s0 * IN_F + j];
        float v1 = x[s1 * IN_F + j];
        s += v0 + v1;
    }
    if (e < end) s += x[csr_src[e] * IN_F + j];
    accm[node * IN_F + j] = s * invdeg[node];
}

// ---------- weight prep: W1^T bf16 [256][224]  (k<100:self, <200:neigh) -----
__global__ __launch_bounds__(256) void build_w1t(
    const float* __restrict__ Ws1, const float* __restrict__ Wn1,
    __bf16* __restrict__ w1t)
{
    int gid = blockIdx.x * 256 + threadIdx.x;   // 256*224 = 57344
    if (gid >= HID * K1) return;
    int j = gid / K1, k = gid % K1;
    float v = 0.f;
    if (k < IN_F)            v = Ws1[k * HID + j];
    else if (k < 2 * IN_F)   v = Wn1[(k - IN_F) * HID + j];
    w1t[gid] = (__bf16)v;
}

// ---------- weight prep: W2^T bf16 [96][256] (j<47:self, 48..94:neigh) ------
__global__ __launch_bounds__(256) void build_w2t(
    const float* __restrict__ Ws2, const float* __restrict__ Wn2,
    __bf16* __restrict__ w2t)
{
    int gid = blockIdx.x * 256 + threadIdx.x;   // 96*256 = 24576
    if (gid >= 96 * K2) return;
    int j = gid / K2, k = gid % K2;
    float v = 0.f;
    if (j < NCLS)                 v = Ws2[k * NCLS + j];
    else if (j >= 48 && j < 95)   v = Wn2[k * NCLS + (j - 48)];
    w2t[gid] = (__bf16)v;
}

// ------------- layer-1 MFMA GEMM + bias + ReLU + dropout ---------------------
// block: 256 thr = 4 waves; 64 rows x 256 cols; wave = 16 rows x 256 cols
__global__ __launch_bounds__(256) void gemm1_mfma(
    const float* __restrict__ x, const float* __restrict__ accm,
    const __bf16* __restrict__ w1t, const float* __restrict__ b1,
    __bf16* __restrict__ h1d)
{
    __shared__ __bf16 xs[64][K1S];   // 29.7 KB
    const int row0 = blockIdx.x * 64;
    const int tid  = threadIdx.x;
    const int nrow = min(64, N_NODES - row0);

    // stage (x || mean) as bf16, zero-pad k in [200,224)
    for (int t = tid; t < 64 * (K1 / 4); t += 256) {
        int r = t / (K1 / 4), c4 = t % (K1 / 4);
        float4 v = make_float4(0.f, 0.f, 0.f, 0.f);
        if (r < nrow) {
            if (c4 < IN_F / 4)
                v = *reinterpret_cast<const float4*>(x + (size_t)(row0 + r) * IN_F + c4 * 4);
            else if (c4 < 2 * IN_F / 4)
                v = *reinterpret_cast<const float4*>(accm + (size_t)(row0 + r) * IN_F + (c4 - IN_F / 4) * 4);
        }
        bf16x4 bv;
        bv[0] = (__bf16)v.x; bv[1] = (__bf16)v.y;
        bv[2] = (__bf16)v.z; bv[3] = (__bf16)v.w;
        *reinterpret_cast<bf16x4*>(&xs[r][c4 * 4]) = bv;
    }
    __syncthreads();

    const int w    = tid >> 6;          // wave 0..3 -> rows w*16..w*16+15
    const int lane = tid & 63;
    const int lm   = lane & 15;
    const int lk   = (lane >> 4) * 8;

    f32x4 acc[16];
#pragma unroll
    for (int ct = 0; ct < 16; ++ct) acc[ct] = (f32x4){0.f, 0.f, 0.f, 0.f};

    for (int kk = 0; kk < K1 / 32; ++kk) {
        const bf16x8 a = *reinterpret_cast<const bf16x8*>(&xs[w * 16 + lm][kk * 32 + lk]);
#pragma unroll
        for (int ct = 0; ct < 16; ++ct) {
            const bf16x8 b = *reinterpret_cast<const bf16x8*>(
                &w1t[(size_t)(ct * 16 + lm) * K1 + kk * 32 + lk]);
            acc[ct] = __builtin_amdgcn_mfma_f32_16x16x32_bf16(a, b, acc[ct], 0, 0, 0);
        }
    }

    // epilogue: bias + ReLU + threefry dropout, write bf16
    const int rbase = w * 16 + (lane >> 4) * 4;   // + reg
#pragma unroll
    for (int ct = 0; ct < 16; ++ct) {
        const int col = ct * 16 + lm;
        const float bj = b1[col];
#pragma unroll
        for (int reg = 0; reg < 4; ++reg) {
            int r = rbase + reg;
            if (r >= nrow) continue;
            int g = row0 + r;
            float v = fmaxf(acc[ct][reg] + bj, 0.f);
            uint32_t bits = jax_bits((uint32_t)(g * HID + col));
            v = (bits & 0x80000000u) ? 0.f : v * 2.0f;
            h1d[(size_t)g * HID + col] = (__bf16)v;
        }
    }
}

// ------------- layer-2 MFMA GEMM: self -> d_out (+b2), z2 -> ws --------------
// block: 256 thr = 4 waves; 64 rows x 96 cols; wave = 16 rows x 96 cols
__global__ __launch_bounds__(256) void gemm2_mfma(
    const __bf16* __restrict__ h1d, const __bf16* __restrict__ w2t,
    const float* __restrict__ b2, float* __restrict__ out, float* __restrict__ z2)
{
    __shared__ __bf16 hs[64][K2S];   // 33.8 KB
    const int row0 = blockIdx.x * 64;
    const int tid  = threadIdx.x;
    const int nrow = min(64, N_NODES - row0);

    for (int t = tid; t < 64 * (K2 / 8); t += 256) {
        int r = t / (K2 / 8), c8 = t % (K2 / 8);
        bf16x8 v = {};
        if (r < nrow)
            v = *reinterpret_cast<const bf16x8*>(h1d + (size_t)(row0 + r) * K2 + c8 * 8);
        *reinterpret_cast<bf16x8*>(&hs[r][c8 * 8]) = v;
    }
    __syncthreads();

    const int w    = tid >> 6;
    const int lane = tid & 63;
    const int lm   = lane & 15;
    const int lk   = (lane >> 4) * 8;

    f32x4 acc[6];
#pragma unroll
    for (int ct = 0; ct < 6; ++ct) acc[ct] = (f32x4){0.f, 0.f, 0.f, 0.f};

    for (int kk = 0; kk < K2 / 32; ++kk) {
        const bf16x8 a = *reinterpret_cast<const bf16x8*>(&hs[w * 16 + lm][kk * 32 + lk]);
#pragma unroll
        for (int ct = 0; ct < 6; ++ct) {
            const bf16x8 b = *reinterpret_cast<const bf16x8*>(
                &w2t[(size_t)(ct * 16 + lm) * K2 + kk * 32 + lk]);
            acc[ct] = __builtin_amdgcn_mfma_f32_16x16x32_bf16(a, b, acc[ct], 0, 0, 0);
        }
    }

    const int rbase = w * 16 + (lane >> 4) * 4;
#pragma unroll
    for (int ct = 0; ct < 6; ++ct) {
        const int col = ct * 16 + lm;
#pragma unroll
        for (int reg = 0; reg < 4; ++reg) {
            int r = rbase + reg;
            if (r >= nrow) continue;
            int g = row0 + r;
            float v = acc[ct][reg];
            if (col < NCLS)               out[(size_t)g * NCLS + col] = v + b2[col];
            else if (col >= 48 && col < 95) z2[(size_t)g * NCLS + (col - 48)] = v;
        }
    }
}

// ============ pull aggregation, layer 2 (sum z2, fuse mean + add) ============
__global__ __launch_bounds__(256) void agg2(
    const int* __restrict__ row_ptr, const int* __restrict__ csr_src,
    const float* __restrict__ z2, const float* __restrict__ invdeg,
    float* __restrict__ out)
{
    int node = blockIdx.x * 4 + (threadIdx.x >> 6);
    int j = threadIdx.x & 63;
    if (node >= N_NODES || j >= NCLS) return;
    int beg = row_ptr[node], end = row_ptr[node + 1];
    float s = 0.f;
    int e = beg;
    for (; e + 1 < end; e += 2) {
        int s0 = csr_src[e], s1 = csr_src[e + 1];
        float v0 = z2[s0 * NCLS + j];
        float v1 = z2[s1 * NCLS + j];
        s += v0 + v1;
    }
    if (e < end) s += z2[csr_src[e] * NCLS + j];
    out[node * NCLS + j] += s * invdeg[node];
}

extern "C" void kernel_launch(void* const* d_in, const int* in_sizes, int n_in,
                              void* d_out, int out_size, void* d_ws, size_t ws_size,
                              hipStream_t stream)
{
    const float* x   = (const float*)d_in[0];
    const int*   src = (const int*)  d_in[1];
    const int*   dst = (const int*)  d_in[2];
    const float* Ws1 = (const float*)d_in[3];
    const float* Wn1 = (const float*)d_in[4];
    const float* b1  = (const float*)d_in[5];
    const float* Ws2 = (const float*)d_in[6];
    const float* Wn2 = (const float*)d_in[7];
    const float* b2  = (const float*)d_in[8];
    float* out = (float*)d_out;

    // ---- workspace layout ----
    int*   wsi     = (int*)d_ws;
    int*   deg     = wsi;               //  50,000
    int*   row_ptr = wsi + 50000;       //  50,001
    int*   cursor  = wsi + 100008;      //  50,000
    int*   csr_src = wsi + 150016;      // 800,000  (ends 950,016)
    int*   bsum    = wsi + 950016;      //     196
    int*   boff    = wsi + 950512;      //     196
    float*  wsf    = (float*)d_ws;
    float*  invdeg = wsf + 1000000;     //     50,000
    float*  accm   = wsf + 1050000;     //  5,000,000
    float*  z2     = accm;              //  aliases accm (dead after gemm1)
    __bf16* h1d    = (__bf16*)(wsf + 6050000);   // 12.8M bf16 (25.6MB)
    __bf16* w1t    = (__bf16*)(wsf + 12450000);  // 57,344 bf16
    __bf16* w2t    = (__bf16*)(wsf + 12480000);  // 24,576 bf16  (~50MB total)

    hipMemsetAsync(deg, 0, (size_t)50000 * sizeof(int), stream);

    count_deg  <<<(N_EDGES + 255) / 256, 256, 0, stream>>>(dst, deg);
    scan_phaseA<<<SCAN_NB, 256, 0, stream>>>(deg, bsum);
    scan_phaseB<<<1, 256, 0, stream>>>(bsum, boff);
    scan_phaseC<<<SCAN_NB, 256, 0, stream>>>(deg, boff, row_ptr, cursor, invdeg);
    fill_csr   <<<(N_EDGES + 255) / 256, 256, 0, stream>>>(src, dst, cursor, csr_src);

    build_w1t<<<(HID * K1 + 255) / 256, 256, 0, stream>>>(Ws1, Wn1, w1t);
    build_w2t<<<(96 * K2 + 255) / 256, 256, 0, stream>>>(Ws2, Wn2, w2t);

    agg1<<<(N_NODES + 1) / 2, 256, 0, stream>>>(row_ptr, csr_src, x, invdeg, accm);
    gemm1_mfma<<<(N_NODES + 63) / 64, 256, 0, stream>>>(x, accm, w1t, b1, h1d);
    gemm2_mfma<<<(N_NODES + 63) / 64, 256, 0, stream>>>(h1d, w2t, b2, out, z2);
    agg2<<<(N_NODES + 3) / 4, 256, 0, stream>>>(row_ptr, csr_src, z2, invdeg, out);
}

// Round 7
// 277.743 us; speedup vs baseline: 2.9849x; 1.2621x over previous
//
#include <hip/hip_runtime.h>
#include <stdint.h>

#define N_NODES 50000
#define N_EDGES 800000
#define IN_F    100
#define HID     256
#define NCLS    47
#define K1      224   // 200 padded to 7*32
#define K1S     232   // LDS row stride
#define K2      256
#define K2S     264
#define SCAN_NB ((N_NODES + 255) / 256)

typedef __bf16 bf16x8 __attribute__((ext_vector_type(8)));
typedef __bf16 bf16x4 __attribute__((ext_vector_type(4)));
typedef float  f32x4  __attribute__((ext_vector_type(4)));

__device__ __forceinline__ uint32_t rotl32(uint32_t v, uint32_t r) {
    return (v << r) | (v >> (32u - r));
}

// JAX threefry2x32, key=(0,42), partitionable: counter=(0,i), bits=x0^x1.
// bernoulli(0.5) keeps iff MSB==0.  (verified round 2)
__device__ __forceinline__ uint32_t jax_bits(uint32_t i) {
    const uint32_t ks0 = 0u, ks1 = 42u, ks2 = 0x1BD11BDAu ^ 42u;
    uint32_t x0 = 0u + ks0;
    uint32_t x1 = i + ks1;
    x0 += x1; x1 = rotl32(x1, 13); x1 ^= x0;
    x0 += x1; x1 = rotl32(x1, 15); x1 ^= x0;
    x0 += x1; x1 = rotl32(x1, 26); x1 ^= x0;
    x0 += x1; x1 = rotl32(x1,  6); x1 ^= x0;
    x0 += ks1; x1 += ks2 + 1u;
    x0 += x1; x1 = rotl32(x1, 17); x1 ^= x0;
    x0 += x1; x1 = rotl32(x1, 29); x1 ^= x0;
    x0 += x1; x1 = rotl32(x1, 16); x1 ^= x0;
    x0 += x1; x1 = rotl32(x1, 24); x1 ^= x0;
    x0 += ks2; x1 += ks0 + 2u;
    x0 += x1; x1 = rotl32(x1, 13); x1 ^= x0;
    x0 += x1; x1 = rotl32(x1, 15); x1 ^= x0;
    x0 += x1; x1 = rotl32(x1, 26); x1 ^= x0;
    x0 += x1; x1 = rotl32(x1,  6); x1 ^= x0;
    x0 += ks0; x1 += ks1 + 3u;
    x0 += x1; x1 = rotl32(x1, 17); x1 ^= x0;
    x0 += x1; x1 = rotl32(x1, 29); x1 ^= x0;
    x0 += x1; x1 = rotl32(x1, 16); x1 ^= x0;
    x0 += x1; x1 = rotl32(x1, 24); x1 ^= x0;
    x0 += ks1; x1 += ks2 + 4u;
    x0 += x1; x1 = rotl32(x1, 13); x1 ^= x0;
    x0 += x1; x1 = rotl32(x1, 15); x1 ^= x0;
    x0 += x1; x1 = rotl32(x1, 26); x1 ^= x0;
    x0 += x1; x1 = rotl32(x1,  6); x1 ^= x0;
    x0 += ks2; x1 += ks0 + 5u;
    return x0 ^ x1;
}

// ======================= CSR build (dst -> srcs) =============================
__global__ __launch_bounds__(256) void count_deg(
    const int* __restrict__ dst, int* __restrict__ deg)
{
    int e = blockIdx.x * 256 + threadIdx.x;
    if (e < N_EDGES) atomicAdd(&deg[dst[e]], 1);
}

__global__ __launch_bounds__(256) void scan_phaseA(
    const int* __restrict__ deg, int* __restrict__ bsum)
{
    __shared__ int red[256];
    int i = blockIdx.x * 256 + threadIdx.x;
    int v = (i < N_NODES) ? deg[i] : 0;
    red[threadIdx.x] = v;
    __syncthreads();
    for (int off = 128; off > 0; off >>= 1) {
        if (threadIdx.x < off) red[threadIdx.x] += red[threadIdx.x + off];
        __syncthreads();
    }
    if (threadIdx.x == 0) bsum[blockIdx.x] = red[0];
}

__global__ __launch_bounds__(256) void scan_phaseB(
    const int* __restrict__ bsum, int* __restrict__ boff)
{
    __shared__ int s[256];
    int tid = threadIdx.x;
    int v = (tid < SCAN_NB) ? bsum[tid] : 0;
    s[tid] = v;
    __syncthreads();
    for (int off = 1; off < 256; off <<= 1) {
        int t = (tid >= off) ? s[tid - off] : 0;
        __syncthreads();
        s[tid] += t;
        __syncthreads();
    }
    if (tid < SCAN_NB) boff[tid] = s[tid] - v;
}

__global__ __launch_bounds__(256) void scan_phaseC(
    const int* __restrict__ deg, const int* __restrict__ boff,
    int* __restrict__ row_ptr, int* __restrict__ cursor,
    float* __restrict__ invdeg)
{
    __shared__ int s[256];
    int tid = threadIdx.x;
    int i = blockIdx.x * 256 + tid;
    int d = (i < N_NODES) ? deg[i] : 0;
    s[tid] = d;
    __syncthreads();
    for (int off = 1; off < 256; off <<= 1) {
        int t = (tid >= off) ? s[tid - off] : 0;
        __syncthreads();
        s[tid] += t;
        __syncthreads();
    }
    int excl = boff[blockIdx.x] + s[tid] - d;
    if (i < N_NODES) {
        row_ptr[i] = excl;
        cursor[i]  = excl;
        invdeg[i]  = 1.0f / fmaxf((float)d, 1.0f);
        if (i == N_NODES - 1) row_ptr[N_NODES] = excl + d;
    }
}

__global__ __launch_bounds__(256) void fill_csr(
    const int* __restrict__ src, const int* __restrict__ dst,
    int* __restrict__ cursor, int* __restrict__ csr_src)
{
    int e = blockIdx.x * 256 + threadIdx.x;
    if (e >= N_EDGES) return;
    int pos = atomicAdd(&cursor[dst[e]], 1);
    csr_src[pos] = src[e];
}

// ---------------- convert x to bf16 (4 elems/thread) -------------------------
__global__ __launch_bounds__(256) void x_to_bf16(
    const float* __restrict__ x, __bf16* __restrict__ xb)
{
    int i = blockIdx.x * 256 + threadIdx.x;   // i indexes float4
    if (i * 4 >= N_NODES * IN_F) return;
    float4 v = reinterpret_cast<const float4*>(x)[i];
    bf16x4 b;
    b[0] = (__bf16)v.x; b[1] = (__bf16)v.y;
    b[2] = (__bf16)v.z; b[3] = (__bf16)v.w;
    *reinterpret_cast<bf16x4*>(xb + i * 4) = b;
}

// ====== pull aggregation, layer 1: bf16 gather, MEAN -> accm_bf16 ============
// 32 threads per node, lane j<25 handles bf16[4j..4j+3]
__global__ __launch_bounds__(256) void agg1_bf(
    const int* __restrict__ row_ptr, const int* __restrict__ csr_src,
    const __bf16* __restrict__ xb, const float* __restrict__ invdeg,
    __bf16* __restrict__ accm)
{
    int gid  = blockIdx.x * 256 + threadIdx.x;
    int node = gid >> 5;
    int j    = gid & 31;
    if (node >= N_NODES || j >= 25) return;
    int beg = row_ptr[node], end = row_ptr[node + 1];
    f32x4 acc = {0.f, 0.f, 0.f, 0.f};
    int e = beg;
    for (; e + 1 < end; e += 2) {
        int s0 = csr_src[e], s1 = csr_src[e + 1];
        bf16x4 v0 = *reinterpret_cast<const bf16x4*>(xb + (size_t)s0 * IN_F + j * 4);
        bf16x4 v1 = *reinterpret_cast<const bf16x4*>(xb + (size_t)s1 * IN_F + j * 4);
#pragma unroll
        for (int q = 0; q < 4; ++q) acc[q] += (float)v0[q] + (float)v1[q];
    }
    if (e < end) {
        bf16x4 v = *reinterpret_cast<const bf16x4*>(xb + (size_t)csr_src[e] * IN_F + j * 4);
#pragma unroll
        for (int q = 0; q < 4; ++q) acc[q] += (float)v[q];
    }
    float inv = invdeg[node];
    bf16x4 r;
#pragma unroll
    for (int q = 0; q < 4; ++q) r[q] = (__bf16)(acc[q] * inv);
    *reinterpret_cast<bf16x4*>(accm + (size_t)node * IN_F + j * 4) = r;
}

// ---------- weight prep: W1^T bf16 [256][224]  (k<100:self, <200:neigh) -----
__global__ __launch_bounds__(256) void build_w1t(
    const float* __restrict__ Ws1, const float* __restrict__ Wn1,
    __bf16* __restrict__ w1t)
{
    int gid = blockIdx.x * 256 + threadIdx.x;
    if (gid >= HID * K1) return;
    int j = gid / K1, k = gid % K1;
    float v = 0.f;
    if (k < IN_F)            v = Ws1[k * HID + j];
    else if (k < 2 * IN_F)   v = Wn1[(k - IN_F) * HID + j];
    w1t[gid] = (__bf16)v;
}

// ---------- weight prep: W2^T bf16 [96][256] (j<47:self, 48..94:neigh) ------
__global__ __launch_bounds__(256) void build_w2t(
    const float* __restrict__ Ws2, const float* __restrict__ Wn2,
    __bf16* __restrict__ w2t)
{
    int gid = blockIdx.x * 256 + threadIdx.x;
    if (gid >= 96 * K2) return;
    int j = gid / K2, k = gid % K2;
    float v = 0.f;
    if (j < NCLS)                 v = Ws2[k * NCLS + j];
    else if (j >= 48 && j < 95)   v = Wn2[k * NCLS + (j - 48)];
    w2t[gid] = (__bf16)v;
}

// ------------- layer-1 MFMA GEMM + bias + ReLU + dropout ---------------------
__global__ __launch_bounds__(256) void gemm1_mfma(
    const __bf16* __restrict__ xb, const __bf16* __restrict__ accm,
    const __bf16* __restrict__ w1t, const float* __restrict__ b1,
    __bf16* __restrict__ h1d)
{
    __shared__ __bf16 xs[64][K1S];   // 29.7 KB
    const int row0 = blockIdx.x * 64;
    const int tid  = threadIdx.x;
    const int nrow = min(64, N_NODES - row0);

    // stage (x || mean) bf16, zero-pad k in [200,224); 4 bf16 per chunk
    for (int t = tid; t < 64 * (K1 / 4); t += 256) {
        int r = t / (K1 / 4), c4 = t % (K1 / 4);
        bf16x4 v = {};
        if (r < nrow) {
            if (c4 < 25)
                v = *reinterpret_cast<const bf16x4*>(xb + (size_t)(row0 + r) * IN_F + c4 * 4);
            else if (c4 < 50)
                v = *reinterpret_cast<const bf16x4*>(accm + (size_t)(row0 + r) * IN_F + (c4 - 25) * 4);
        }
        *reinterpret_cast<bf16x4*>(&xs[r][c4 * 4]) = v;
    }
    __syncthreads();

    const int w    = tid >> 6;
    const int lane = tid & 63;
    const int lm   = lane & 15;
    const int lk   = (lane >> 4) * 8;

    f32x4 acc[16];
#pragma unroll
    for (int ct = 0; ct < 16; ++ct) acc[ct] = (f32x4){0.f, 0.f, 0.f, 0.f};

    for (int kk = 0; kk < K1 / 32; ++kk) {
        const bf16x8 a = *reinterpret_cast<const bf16x8*>(&xs[w * 16 + lm][kk * 32 + lk]);
#pragma unroll
        for (int ct = 0; ct < 16; ++ct) {
            const bf16x8 b = *reinterpret_cast<const bf16x8*>(
                &w1t[(size_t)(ct * 16 + lm) * K1 + kk * 32 + lk]);
            acc[ct] = __builtin_amdgcn_mfma_f32_16x16x32_bf16(a, b, acc[ct], 0, 0, 0);
        }
    }

    const int rbase = w * 16 + (lane >> 4) * 4;
#pragma unroll
    for (int ct = 0; ct < 16; ++ct) {
        const int col = ct * 16 + lm;
        const float bj = b1[col];
#pragma unroll
        for (int reg = 0; reg < 4; ++reg) {
            int r = rbase + reg;
            if (r >= nrow) continue;
            int g = row0 + r;
            float v = fmaxf(acc[ct][reg] + bj, 0.f);
            uint32_t bits = jax_bits((uint32_t)(g * HID + col));
            v = (bits & 0x80000000u) ? 0.f : v * 2.0f;
            h1d[(size_t)g * HID + col] = (__bf16)v;
        }
    }
}

// ------------- layer-2 MFMA GEMM: self -> d_out (+b2), z2b (bf16) -----------
__global__ __launch_bounds__(256) void gemm2_mfma(
    const __bf16* __restrict__ h1d, const __bf16* __restrict__ w2t,
    const float* __restrict__ b2, float* __restrict__ out, __bf16* __restrict__ z2b)
{
    __shared__ __bf16 hs[64][K2S];   // 33.8 KB
    const int row0 = blockIdx.x * 64;
    const int tid  = threadIdx.x;
    const int nrow = min(64, N_NODES - row0);

    for (int t = tid; t < 64 * (K2 / 8); t += 256) {
        int r = t / (K2 / 8), c8 = t % (K2 / 8);
        bf16x8 v = {};
        if (r < nrow)
            v = *reinterpret_cast<const bf16x8*>(h1d + (size_t)(row0 + r) * K2 + c8 * 8);
        *reinterpret_cast<bf16x8*>(&hs[r][c8 * 8]) = v;
    }
    __syncthreads();

    const int w    = tid >> 6;
    const int lane = tid & 63;
    const int lm   = lane & 15;
    const int lk   = (lane >> 4) * 8;

    f32x4 acc[6];
#pragma unroll
    for (int ct = 0; ct < 6; ++ct) acc[ct] = (f32x4){0.f, 0.f, 0.f, 0.f};

    for (int kk = 0; kk < K2 / 32; ++kk) {
        const bf16x8 a = *reinterpret_cast<const bf16x8*>(&hs[w * 16 + lm][kk * 32 + lk]);
#pragma unroll
        for (int ct = 0; ct < 6; ++ct) {
            const bf16x8 b = *reinterpret_cast<const bf16x8*>(
                &w2t[(size_t)(ct * 16 + lm) * K2 + kk * 32 + lk]);
            acc[ct] = __builtin_amdgcn_mfma_f32_16x16x32_bf16(a, b, acc[ct], 0, 0, 0);
        }
    }

    const int rbase = w * 16 + (lane >> 4) * 4;
#pragma unroll
    for (int ct = 0; ct < 6; ++ct) {
        const int col = ct * 16 + lm;
#pragma unroll
        for (int reg = 0; reg < 4; ++reg) {
            int r = rbase + reg;
            if (r >= nrow) continue;
            int g = row0 + r;
            float v = acc[ct][reg];
            if (col < NCLS)               out[(size_t)g * NCLS + col] = v + b2[col];
            else if (col >= 48 && col < 95) z2b[(size_t)g * 48 + (col - 48)] = (__bf16)v;
            else if (col == 95)             z2b[(size_t)g * 48 + 47] = (__bf16)0.f;
        }
    }
}

// ====== pull aggregation, layer 2: bf16 gather of z2b, mean + add ============
// 16 threads per node, lane j<12 handles cols 4j..4j+3 (col 47 = pad)
__global__ __launch_bounds__(256) void agg2_bf(
    const int* __restrict__ row_ptr, const int* __restrict__ csr_src,
    const __bf16* __restrict__ z2b, const float* __restrict__ invdeg,
    float* __restrict__ out)
{
    int gid  = blockIdx.x * 256 + threadIdx.x;
    int node = gid >> 4;
    int j    = gid & 15;
    if (node >= N_NODES || j >= 12) return;
    int beg = row_ptr[node], end = row_ptr[node + 1];
    f32x4 acc = {0.f, 0.f, 0.f, 0.f};
    int e = beg;
    for (; e + 1 < end; e += 2) {
        int s0 = csr_src[e], s1 = csr_src[e + 1];
        bf16x4 v0 = *reinterpret_cast<const bf16x4*>(z2b + (size_t)s0 * 48 + j * 4);
        bf16x4 v1 = *reinterpret_cast<const bf16x4*>(z2b + (size_t)s1 * 48 + j * 4);
#pragma unroll
        for (int q = 0; q < 4; ++q) acc[q] += (float)v0[q] + (float)v1[q];
    }
    if (e < end) {
        bf16x4 v = *reinterpret_cast<const bf16x4*>(z2b + (size_t)csr_src[e] * 48 + j * 4);
#pragma unroll
        for (int q = 0; q < 4; ++q) acc[q] += (float)v[q];
    }
    float inv = invdeg[node];
#pragma unroll
    for (int q = 0; q < 4; ++q) {
        int col = j * 4 + q;
        if (col < NCLS)
            out[(size_t)node * NCLS + col] += acc[q] * inv;
    }
}

extern "C" void kernel_launch(void* const* d_in, const int* in_sizes, int n_in,
                              void* d_out, int out_size, void* d_ws, size_t ws_size,
                              hipStream_t stream)
{
    const float* x   = (const float*)d_in[0];
    const int*   src = (const int*)  d_in[1];
    const int*   dst = (const int*)  d_in[2];
    const float* Ws1 = (const float*)d_in[3];
    const float* Wn1 = (const float*)d_in[4];
    const float* b1  = (const float*)d_in[5];
    const float* Ws2 = (const float*)d_in[6];
    const float* Wn2 = (const float*)d_in[7];
    const float* b2  = (const float*)d_in[8];
    float* out = (float*)d_out;

    // ---- workspace layout (float-index units) ----
    int*   wsi     = (int*)d_ws;
    int*   deg     = wsi;               //  50,000
    int*   row_ptr = wsi + 50000;       //  50,001
    int*   cursor  = wsi + 100008;      //  50,000
    int*   csr_src = wsi + 150016;      // 800,000  (ends 950,016)
    int*   bsum    = wsi + 950016;      //     196
    int*   boff    = wsi + 950512;      //     196
    float*  wsf    = (float*)d_ws;
    float*  invdeg = wsf + 1000000;                  //  50,000 f32
    __bf16* xb     = (__bf16*)(wsf + 1050000);       //  5.0M bf16 -> +2.5M
    __bf16* accm   = (__bf16*)(wsf + 3550000);       //  5.0M bf16 -> +2.5M
    __bf16* h1d    = (__bf16*)(wsf + 6050000);       // 12.8M bf16 -> +6.4M
    __bf16* w1t    = (__bf16*)(wsf + 12450000);      // 57,344 bf16
    __bf16* w2t    = (__bf16*)(wsf + 12480000);      // 24,576 bf16
    __bf16* z2b    = (__bf16*)(wsf + 12500000);      //  2.4M bf16 -> +1.2M (~54.8MB)

    hipMemsetAsync(deg, 0, (size_t)50000 * sizeof(int), stream);

    count_deg  <<<(N_EDGES + 255) / 256, 256, 0, stream>>>(dst, deg);
    scan_phaseA<<<SCAN_NB, 256, 0, stream>>>(deg, bsum);
    scan_phaseB<<<1, 256, 0, stream>>>(bsum, boff);
    scan_phaseC<<<SCAN_NB, 256, 0, stream>>>(deg, boff, row_ptr, cursor, invdeg);
    fill_csr   <<<(N_EDGES + 255) / 256, 256, 0, stream>>>(src, dst, cursor, csr_src);

    x_to_bf16<<<(N_NODES * IN_F / 4 + 255) / 256, 256, 0, stream>>>(x, xb);
    build_w1t<<<(HID * K1 + 255) / 256, 256, 0, stream>>>(Ws1, Wn1, w1t);
    build_w2t<<<(96 * K2 + 255) / 256, 256, 0, stream>>>(Ws2, Wn2, w2t);

    agg1_bf<<<(N_NODES * 32 + 255) / 256, 256, 0, stream>>>(row_ptr, csr_src, xb, invdeg, accm);
    gemm1_mfma<<<(N_NODES + 63) / 64, 256, 0, stream>>>(xb, accm, w1t, b1, h1d);
    gemm2_mfma<<<(N_NODES + 63) / 64, 256, 0, stream>>>(h1d, w2t, b2, out, z2b);
    agg2_bf<<<(N_NODES * 16 + 255) / 256, 256, 0, stream>>>(row_ptr, csr_src, z2b, invdeg, out);
}

// Round 8
// 260.700 us; speedup vs baseline: 3.1800x; 1.0654x over previous
//
#include <hip/hip_runtime.h>
#include <stdint.h>

#define N_NODES 50000
#define N_EDGES 800000
#define IN_F    100
#define HID     256
#define NCLS    47
#define K1      224   // 200 padded to 7*32
#define K1S     232   // LDS row stride
#define K2      256
#define K2S     264
#define SCAN_NB ((N_NODES + 255) / 256)

typedef __bf16 bf16x8 __attribute__((ext_vector_type(8)));
typedef __bf16 bf16x4 __attribute__((ext_vector_type(4)));
typedef float  f32x4  __attribute__((ext_vector_type(4)));

__device__ __forceinline__ uint32_t rotl32(uint32_t v, uint32_t r) {
    return (v << r) | (v >> (32u - r));
}

// JAX threefry2x32, key=(0,42), partitionable: counter=(0,i), bits=x0^x1.
// bernoulli(0.5) keeps iff MSB==0.  (verified round 2)
__device__ __forceinline__ uint32_t jax_bits(uint32_t i) {
    const uint32_t ks0 = 0u, ks1 = 42u, ks2 = 0x1BD11BDAu ^ 42u;
    uint32_t x0 = 0u + ks0;
    uint32_t x1 = i + ks1;
    x0 += x1; x1 = rotl32(x1, 13); x1 ^= x0;
    x0 += x1; x1 = rotl32(x1, 15); x1 ^= x0;
    x0 += x1; x1 = rotl32(x1, 26); x1 ^= x0;
    x0 += x1; x1 = rotl32(x1,  6); x1 ^= x0;
    x0 += ks1; x1 += ks2 + 1u;
    x0 += x1; x1 = rotl32(x1, 17); x1 ^= x0;
    x0 += x1; x1 = rotl32(x1, 29); x1 ^= x0;
    x0 += x1; x1 = rotl32(x1, 16); x1 ^= x0;
    x0 += x1; x1 = rotl32(x1, 24); x1 ^= x0;
    x0 += ks2; x1 += ks0 + 2u;
    x0 += x1; x1 = rotl32(x1, 13); x1 ^= x0;
    x0 += x1; x1 = rotl32(x1, 15); x1 ^= x0;
    x0 += x1; x1 = rotl32(x1, 26); x1 ^= x0;
    x0 += x1; x1 = rotl32(x1,  6); x1 ^= x0;
    x0 += ks0; x1 += ks1 + 3u;
    x0 += x1; x1 = rotl32(x1, 17); x1 ^= x0;
    x0 += x1; x1 = rotl32(x1, 29); x1 ^= x0;
    x0 += x1; x1 = rotl32(x1, 16); x1 ^= x0;
    x0 += x1; x1 = rotl32(x1, 24); x1 ^= x0;
    x0 += ks1; x1 += ks2 + 4u;
    x0 += x1; x1 = rotl32(x1, 13); x1 ^= x0;
    x0 += x1; x1 = rotl32(x1, 15); x1 ^= x0;
    x0 += x1; x1 = rotl32(x1, 26); x1 ^= x0;
    x0 += x1; x1 = rotl32(x1,  6); x1 ^= x0;
    x0 += ks2; x1 += ks0 + 5u;
    return x0 ^ x1;
}

// ======================= CSR build (dst -> srcs) =============================
__global__ __launch_bounds__(256) void count_deg(
    const int* __restrict__ dst, int* __restrict__ deg)
{
    int e = blockIdx.x * 256 + threadIdx.x;
    if (e < N_EDGES) atomicAdd(&deg[dst[e]], 1);
}

__global__ __launch_bounds__(256) void scan_phaseA(
    const int* __restrict__ deg, int* __restrict__ bsum)
{
    __shared__ int red[256];
    int i = blockIdx.x * 256 + threadIdx.x;
    int v = (i < N_NODES) ? deg[i] : 0;
    red[threadIdx.x] = v;
    __syncthreads();
    for (int off = 128; off > 0; off >>= 1) {
        if (threadIdx.x < off) red[threadIdx.x] += red[threadIdx.x + off];
        __syncthreads();
    }
    if (threadIdx.x == 0) bsum[blockIdx.x] = red[0];
}

__global__ __launch_bounds__(256) void scan_phaseB(
    const int* __restrict__ bsum, int* __restrict__ boff)
{
    __shared__ int s[256];
    int tid = threadIdx.x;
    int v = (tid < SCAN_NB) ? bsum[tid] : 0;
    s[tid] = v;
    __syncthreads();
    for (int off = 1; off < 256; off <<= 1) {
        int t = (tid >= off) ? s[tid - off] : 0;
        __syncthreads();
        s[tid] += t;
        __syncthreads();
    }
    if (tid < SCAN_NB) boff[tid] = s[tid] - v;
}

__global__ __launch_bounds__(256) void scan_phaseC(
    const int* __restrict__ deg, const int* __restrict__ boff,
    int* __restrict__ row_ptr, int* __restrict__ cursor,
    float* __restrict__ invdeg)
{
    __shared__ int s[256];
    int tid = threadIdx.x;
    int i = blockIdx.x * 256 + tid;
    int d = (i < N_NODES) ? deg[i] : 0;
    s[tid] = d;
    __syncthreads();
    for (int off = 1; off < 256; off <<= 1) {
        int t = (tid >= off) ? s[tid - off] : 0;
        __syncthreads();
        s[tid] += t;
        __syncthreads();
    }
    int excl = boff[blockIdx.x] + s[tid] - d;
    if (i < N_NODES) {
        row_ptr[i] = excl;
        cursor[i]  = excl;
        invdeg[i]  = 1.0f / fmaxf((float)d, 1.0f);
        if (i == N_NODES - 1) row_ptr[N_NODES] = excl + d;
    }
}

__global__ __launch_bounds__(256) void fill_csr(
    const int* __restrict__ src, const int* __restrict__ dst,
    int* __restrict__ cursor, int* __restrict__ csr_src)
{
    int e = blockIdx.x * 256 + threadIdx.x;
    if (e >= N_EDGES) return;
    int pos = atomicAdd(&cursor[dst[e]], 1);
    csr_src[pos] = src[e];
}

// ---------------- convert x to bf16 (4 elems/thread) -------------------------
__global__ __launch_bounds__(256) void x_to_bf16(
    const float* __restrict__ x, __bf16* __restrict__ xb)
{
    int i = blockIdx.x * 256 + threadIdx.x;
    if (i * 4 >= N_NODES * IN_F) return;
    float4 v = reinterpret_cast<const float4*>(x)[i];
    bf16x4 b;
    b[0] = (__bf16)v.x; b[1] = (__bf16)v.y;
    b[2] = (__bf16)v.z; b[3] = (__bf16)v.w;
    *reinterpret_cast<bf16x4*>(xb + i * 4) = b;
}

// ====== pull aggregation, layer 1: bf16 gather, MEAN -> accm_bf16 ============
__global__ __launch_bounds__(256) void agg1_bf(
    const int* __restrict__ row_ptr, const int* __restrict__ csr_src,
    const __bf16* __restrict__ xb, const float* __restrict__ invdeg,
    __bf16* __restrict__ accm)
{
    int gid  = blockIdx.x * 256 + threadIdx.x;
    int node = gid >> 5;
    int j    = gid & 31;
    if (node >= N_NODES || j >= 25) return;
    int beg = row_ptr[node], end = row_ptr[node + 1];
    f32x4 acc = {0.f, 0.f, 0.f, 0.f};
    int e = beg;
    for (; e + 1 < end; e += 2) {
        int s0 = csr_src[e], s1 = csr_src[e + 1];
        bf16x4 v0 = *reinterpret_cast<const bf16x4*>(xb + (size_t)s0 * IN_F + j * 4);
        bf16x4 v1 = *reinterpret_cast<const bf16x4*>(xb + (size_t)s1 * IN_F + j * 4);
#pragma unroll
        for (int q = 0; q < 4; ++q) acc[q] += (float)v0[q] + (float)v1[q];
    }
    if (e < end) {
        bf16x4 v = *reinterpret_cast<const bf16x4*>(xb + (size_t)csr_src[e] * IN_F + j * 4);
#pragma unroll
        for (int q = 0; q < 4; ++q) acc[q] += (float)v[q];
    }
    float inv = invdeg[node];
    bf16x4 r;
#pragma unroll
    for (int q = 0; q < 4; ++q) r[q] = (__bf16)(acc[q] * inv);
    *reinterpret_cast<bf16x4*>(accm + (size_t)node * IN_F + j * 4) = r;
}

// ---------- weight prep: W1^T bf16 [256][224]  (k<100:self, <200:neigh) -----
__global__ __launch_bounds__(256) void build_w1t(
    const float* __restrict__ Ws1, const float* __restrict__ Wn1,
    __bf16* __restrict__ w1t)
{
    int gid = blockIdx.x * 256 + threadIdx.x;
    if (gid >= HID * K1) return;
    int j = gid / K1, k = gid % K1;
    float v = 0.f;
    if (k < IN_F)            v = Ws1[k * HID + j];
    else if (k < 2 * IN_F)   v = Wn1[(k - IN_F) * HID + j];
    w1t[gid] = (__bf16)v;
}

// ---------- weight prep: W2^T bf16 [96][256] (j<47:self, 48..94:neigh) ------
__global__ __launch_bounds__(256) void build_w2t(
    const float* __restrict__ Ws2, const float* __restrict__ Wn2,
    __bf16* __restrict__ w2t)
{
    int gid = blockIdx.x * 256 + threadIdx.x;
    if (gid >= 96 * K2) return;
    int j = gid / K2, k = gid % K2;
    float v = 0.f;
    if (j < NCLS)                 v = Ws2[k * NCLS + j];
    else if (j >= 48 && j < 95)   v = Wn2[k * NCLS + (j - 48)];
    w2t[gid] = (__bf16)v;
}

// ------------- layer-1 MFMA GEMM + bias + ReLU + dropout ---------------------
// 32 rows/block; 4 waves; wave = 16 rows x 128 cols (8 ct)
__global__ __launch_bounds__(256) void gemm1_mfma(
    const __bf16* __restrict__ xb, const __bf16* __restrict__ accm,
    const __bf16* __restrict__ w1t, const float* __restrict__ b1,
    __bf16* __restrict__ h1d)
{
    __shared__ __bf16 xs[32][K1S];   // 14.8 KB
    const int row0 = blockIdx.x * 32;
    const int tid  = threadIdx.x;
    const int nrow = min(32, N_NODES - row0);

    for (int t = tid; t < 32 * (K1 / 4); t += 256) {
        int r = t / (K1 / 4), c4 = t % (K1 / 4);
        bf16x4 v = {};
        if (r < nrow) {
            if (c4 < 25)
                v = *reinterpret_cast<const bf16x4*>(xb + (size_t)(row0 + r) * IN_F + c4 * 4);
            else if (c4 < 50)
                v = *reinterpret_cast<const bf16x4*>(accm + (size_t)(row0 + r) * IN_F + (c4 - 25) * 4);
        }
        *reinterpret_cast<bf16x4*>(&xs[r][c4 * 4]) = v;
    }
    __syncthreads();

    const int w    = tid >> 6;
    const int lane = tid & 63;
    const int lm   = lane & 15;
    const int lk   = (lane >> 4) * 8;
    const int wr   = (w >> 1) * 16;        // wave row base (0 / 16)
    const int wc   = (w & 1) * 128;        // wave col base (0 / 128)

    f32x4 acc[8];
#pragma unroll
    for (int ct = 0; ct < 8; ++ct) acc[ct] = (f32x4){0.f, 0.f, 0.f, 0.f};

    for (int kk = 0; kk < K1 / 32; ++kk) {
        const bf16x8 a = *reinterpret_cast<const bf16x8*>(&xs[wr + lm][kk * 32 + lk]);
#pragma unroll
        for (int ct = 0; ct < 8; ++ct) {
            const bf16x8 b = *reinterpret_cast<const bf16x8*>(
                &w1t[(size_t)(wc + ct * 16 + lm) * K1 + kk * 32 + lk]);
            acc[ct] = __builtin_amdgcn_mfma_f32_16x16x32_bf16(a, b, acc[ct], 0, 0, 0);
        }
    }

    const int rbase = wr + (lane >> 4) * 4;
#pragma unroll
    for (int ct = 0; ct < 8; ++ct) {
        const int col = wc + ct * 16 + lm;
        const float bj = b1[col];
#pragma unroll
        for (int reg = 0; reg < 4; ++reg) {
            int r = rbase + reg;
            if (r >= nrow) continue;
            int g = row0 + r;
            float v = fmaxf(acc[ct][reg] + bj, 0.f);
            uint32_t bits = jax_bits((uint32_t)(g * HID + col));
            v = (bits & 0x80000000u) ? 0.f : v * 2.0f;
            h1d[(size_t)g * HID + col] = (__bf16)v;
        }
    }
}

// ------------- layer-2 MFMA GEMM: self -> d_out (+b2), z2b (bf16) -----------
// 32 rows/block; 4 waves; wave = 16 rows x 48 cols (3 ct)
__global__ __launch_bounds__(256) void gemm2_mfma(
    const __bf16* __restrict__ h1d, const __bf16* __restrict__ w2t,
    const float* __restrict__ b2, float* __restrict__ out, __bf16* __restrict__ z2b)
{
    __shared__ __bf16 hs[32][K2S];   // 16.9 KB
    const int row0 = blockIdx.x * 32;
    const int tid  = threadIdx.x;
    const int nrow = min(32, N_NODES - row0);

    for (int t = tid; t < 32 * (K2 / 8); t += 256) {
        int r = t / (K2 / 8), c8 = t % (K2 / 8);
        bf16x8 v = {};
        if (r < nrow)
            v = *reinterpret_cast<const bf16x8*>(h1d + (size_t)(row0 + r) * K2 + c8 * 8);
        *reinterpret_cast<bf16x8*>(&hs[r][c8 * 8]) = v;
    }
    __syncthreads();

    const int w    = tid >> 6;
    const int lane = tid & 63;
    const int lm   = lane & 15;
    const int lk   = (lane >> 4) * 8;
    const int wr   = (w >> 1) * 16;        // 0 / 16
    const int wcb  = (w & 1) * 3;          // ct base: 0 / 3 (cols 0-47 / 48-95)

    f32x4 acc[3];
#pragma unroll
    for (int ct = 0; ct < 3; ++ct) acc[ct] = (f32x4){0.f, 0.f, 0.f, 0.f};

    for (int kk = 0; kk < K2 / 32; ++kk) {
        const bf16x8 a = *reinterpret_cast<const bf16x8*>(&hs[wr + lm][kk * 32 + lk]);
#pragma unroll
        for (int ct = 0; ct < 3; ++ct) {
            const bf16x8 b = *reinterpret_cast<const bf16x8*>(
                &w2t[(size_t)((wcb + ct) * 16 + lm) * K2 + kk * 32 + lk]);
            acc[ct] = __builtin_amdgcn_mfma_f32_16x16x32_bf16(a, b, acc[ct], 0, 0, 0);
        }
    }

    const int rbase = wr + (lane >> 4) * 4;
#pragma unroll
    for (int ct = 0; ct < 3; ++ct) {
        const int col = (wcb + ct) * 16 + lm;
#pragma unroll
        for (int reg = 0; reg < 4; ++reg) {
            int r = rbase + reg;
            if (r >= nrow) continue;
            int g = row0 + r;
            float v = acc[ct][reg];
            if (col < NCLS)               out[(size_t)g * NCLS + col] = v + b2[col];
            else if (col >= 48 && col < 95) z2b[(size_t)g * 48 + (col - 48)] = (__bf16)v;
            else if (col == 95)             z2b[(size_t)g * 48 + 47] = (__bf16)0.f;
        }
    }
}

// ====== pull aggregation, layer 2: bf16 gather of z2b, mean + add ============
__global__ __launch_bounds__(256) void agg2_bf(
    const int* __restrict__ row_ptr, const int* __restrict__ csr_src,
    const __bf16* __restrict__ z2b, const float* __restrict__ invdeg,
    float* __restrict__ out)
{
    int gid  = blockIdx.x * 256 + threadIdx.x;
    int node = gid >> 4;
    int j    = gid & 15;
    if (node >= N_NODES || j >= 12) return;
    int beg = row_ptr[node], end = row_ptr[node + 1];
    f32x4 acc = {0.f, 0.f, 0.f, 0.f};
    int e = beg;
    for (; e + 1 < end; e += 2) {
        int s0 = csr_src[e], s1 = csr_src[e + 1];
        bf16x4 v0 = *reinterpret_cast<const bf16x4*>(z2b + (size_t)s0 * 48 + j * 4);
        bf16x4 v1 = *reinterpret_cast<const bf16x4*>(z2b + (size_t)s1 * 48 + j * 4);
#pragma unroll
        for (int q = 0; q < 4; ++q) acc[q] += (float)v0[q] + (float)v1[q];
    }
    if (e < end) {
        bf16x4 v = *reinterpret_cast<const bf16x4*>(z2b + (size_t)csr_src[e] * 48 + j * 4);
#pragma unroll
        for (int q = 0; q < 4; ++q) acc[q] += (float)v[q];
    }
    float inv = invdeg[node];
#pragma unroll
    for (int q = 0; q < 4; ++q) {
        int col = j * 4 + q;
        if (col < NCLS)
            out[(size_t)node * NCLS + col] += acc[q] * inv;
    }
}

extern "C" void kernel_launch(void* const* d_in, const int* in_sizes, int n_in,
                              void* d_out, int out_size, void* d_ws, size_t ws_size,
                              hipStream_t stream)
{
    const float* x   = (const float*)d_in[0];
    const int*   src = (const int*)  d_in[1];
    const int*   dst = (const int*)  d_in[2];
    const float* Ws1 = (const float*)d_in[3];
    const float* Wn1 = (const float*)d_in[4];
    const float* b1  = (const float*)d_in[5];
    const float* Ws2 = (const float*)d_in[6];
    const float* Wn2 = (const float*)d_in[7];
    const float* b2  = (const float*)d_in[8];
    float* out = (float*)d_out;

    // ---- workspace layout (float-index units) ----
    int*   wsi     = (int*)d_ws;
    int*   deg     = wsi;               //  50,000
    int*   row_ptr = wsi + 50000;       //  50,001
    int*   cursor  = wsi + 100008;      //  50,000
    int*   csr_src = wsi + 150016;      // 800,000  (ends 950,016)
    int*   bsum    = wsi + 950016;      //     196
    int*   boff    = wsi + 950512;      //     196
    float*  wsf    = (float*)d_ws;
    float*  invdeg = wsf + 1000000;                  //  50,000 f32
    __bf16* xb     = (__bf16*)(wsf + 1050000);       //  5.0M bf16
    __bf16* accm   = (__bf16*)(wsf + 3550000);       //  5.0M bf16
    __bf16* h1d    = (__bf16*)(wsf + 6050000);       // 12.8M bf16
    __bf16* w1t    = (__bf16*)(wsf + 12450000);      // 57,344 bf16
    __bf16* w2t    = (__bf16*)(wsf + 12480000);      // 24,576 bf16
    __bf16* z2b    = (__bf16*)(wsf + 12500000);      //  2.4M bf16 (~54.8MB)

    hipMemsetAsync(deg, 0, (size_t)50000 * sizeof(int), stream);

    count_deg  <<<(N_EDGES + 255) / 256, 256, 0, stream>>>(dst, deg);
    scan_phaseA<<<SCAN_NB, 256, 0, stream>>>(deg, bsum);
    scan_phaseB<<<1, 256, 0, stream>>>(bsum, boff);
    scan_phaseC<<<SCAN_NB, 256, 0, stream>>>(deg, boff, row_ptr, cursor, invdeg);
    fill_csr   <<<(N_EDGES + 255) / 256, 256, 0, stream>>>(src, dst, cursor, csr_src);

    x_to_bf16<<<(N_NODES * IN_F / 4 + 255) / 256, 256, 0, stream>>>(x, xb);
    build_w1t<<<(HID * K1 + 255) / 256, 256, 0, stream>>>(Ws1, Wn1, w1t);
    build_w2t<<<(96 * K2 + 255) / 256, 256, 0, stream>>>(Ws2, Wn2, w2t);

    agg1_bf<<<(N_NODES * 32 + 255) / 256, 256, 0, stream>>>(row_ptr, csr_src, xb, invdeg, accm);
    gemm1_mfma<<<(N_NODES + 31) / 32, 256, 0, stream>>>(xb, accm, w1t, b1, h1d);
    gemm2_mfma<<<(N_NODES + 31) / 32, 256, 0, stream>>>(h1d, w2t, b2, out, z2b);
    agg2_bf<<<(N_NODES * 16 + 255) / 256, 256, 0, stream>>>(row_ptr, csr_src, z2b, invdeg, out);
}

// Round 9
// 259.635 us; speedup vs baseline: 3.1931x; 1.0041x over previous
//
#include <hip/hip_runtime.h>
#include <stdint.h>

#define N_NODES 50000
#define N_EDGES 800000
#define IN_F    100
#define HID     256
#define NCLS    47
#define K1      224   // 200 padded to 7*32
#define K1S     232   // LDS row stride (bank-spread)
#define K2      256
#define K2S     264
#define SCAN_NB ((N_NODES + 255) / 256)
#define MASK_WORDS (N_NODES * (HID / 32))   // 400,000

typedef __bf16 bf16x8 __attribute__((ext_vector_type(8)));
typedef __bf16 bf16x4 __attribute__((ext_vector_type(4)));
typedef float  f32x4  __attribute__((ext_vector_type(4)));

__device__ __forceinline__ uint32_t rotl32(uint32_t v, uint32_t r) {
    return (v << r) | (v >> (32u - r));
}

// JAX threefry2x32, key=(0,42), partitionable: counter=(0,i), bits=x0^x1.
// bernoulli(0.5) keeps iff MSB==0.  (verified round 2)
__device__ __forceinline__ uint32_t jax_bits(uint32_t i) {
    const uint32_t ks0 = 0u, ks1 = 42u, ks2 = 0x1BD11BDAu ^ 42u;
    uint32_t x0 = 0u + ks0;
    uint32_t x1 = i + ks1;
    x0 += x1; x1 = rotl32(x1, 13); x1 ^= x0;
    x0 += x1; x1 = rotl32(x1, 15); x1 ^= x0;
    x0 += x1; x1 = rotl32(x1, 26); x1 ^= x0;
    x0 += x1; x1 = rotl32(x1,  6); x1 ^= x0;
    x0 += ks1; x1 += ks2 + 1u;
    x0 += x1; x1 = rotl32(x1, 17); x1 ^= x0;
    x0 += x1; x1 = rotl32(x1, 29); x1 ^= x0;
    x0 += x1; x1 = rotl32(x1, 16); x1 ^= x0;
    x0 += x1; x1 = rotl32(x1, 24); x1 ^= x0;
    x0 += ks2; x1 += ks0 + 2u;
    x0 += x1; x1 = rotl32(x1, 13); x1 ^= x0;
    x0 += x1; x1 = rotl32(x1, 15); x1 ^= x0;
    x0 += x1; x1 = rotl32(x1, 26); x1 ^= x0;
    x0 += x1; x1 = rotl32(x1,  6); x1 ^= x0;
    x0 += ks0; x1 += ks1 + 3u;
    x0 += x1; x1 = rotl32(x1, 17); x1 ^= x0;
    x0 += x1; x1 = rotl32(x1, 29); x1 ^= x0;
    x0 += x1; x1 = rotl32(x1, 16); x1 ^= x0;
    x0 += x1; x1 = rotl32(x1, 24); x1 ^= x0;
    x0 += ks1; x1 += ks2 + 4u;
    x0 += x1; x1 = rotl32(x1, 13); x1 ^= x0;
    x0 += x1; x1 = rotl32(x1, 15); x1 ^= x0;
    x0 += x1; x1 = rotl32(x1, 26); x1 ^= x0;
    x0 += x1; x1 = rotl32(x1,  6); x1 ^= x0;
    x0 += ks2; x1 += ks0 + 5u;
    return x0 ^ x1;
}

// ---------------- dropout mask: 1 bit per h1 element (keep=1) ----------------
__global__ __launch_bounds__(256) void make_mask(uint32_t* __restrict__ mask)
{
    int w = blockIdx.x * 256 + threadIdx.x;
    if (w >= MASK_WORDS) return;
    uint32_t base = (uint32_t)w * 32u;
    uint32_t m = 0u;
#pragma unroll
    for (int j = 0; j < 32; ++j) {
        uint32_t bits = jax_bits(base + (uint32_t)j);
        m |= ((~bits) >> 31) << j;   // keep iff MSB==0
    }
    mask[w] = m;
}

// ======================= CSR build (dst -> srcs) =============================
__global__ __launch_bounds__(256) void count_deg(
    const int* __restrict__ dst, int* __restrict__ deg)
{
    int e = blockIdx.x * 256 + threadIdx.x;
    if (e < N_EDGES) atomicAdd(&deg[dst[e]], 1);
}

__global__ __launch_bounds__(256) void scan_phaseA(
    const int* __restrict__ deg, int* __restrict__ bsum)
{
    __shared__ int red[256];
    int i = blockIdx.x * 256 + threadIdx.x;
    int v = (i < N_NODES) ? deg[i] : 0;
    red[threadIdx.x] = v;
    __syncthreads();
    for (int off = 128; off > 0; off >>= 1) {
        if (threadIdx.x < off) red[threadIdx.x] += red[threadIdx.x + off];
        __syncthreads();
    }
    if (threadIdx.x == 0) bsum[blockIdx.x] = red[0];
}

__global__ __launch_bounds__(256) void scan_phaseB(
    const int* __restrict__ bsum, int* __restrict__ boff)
{
    __shared__ int s[256];
    int tid = threadIdx.x;
    int v = (tid < SCAN_NB) ? bsum[tid] : 0;
    s[tid] = v;
    __syncthreads();
    for (int off = 1; off < 256; off <<= 1) {
        int t = (tid >= off) ? s[tid - off] : 0;
        __syncthreads();
        s[tid] += t;
        __syncthreads();
    }
    if (tid < SCAN_NB) boff[tid] = s[tid] - v;
}

__global__ __launch_bounds__(256) void scan_phaseC(
    const int* __restrict__ deg, const int* __restrict__ boff,
    int* __restrict__ row_ptr, int* __restrict__ cursor,
    float* __restrict__ invdeg)
{
    __shared__ int s[256];
    int tid = threadIdx.x;
    int i = blockIdx.x * 256 + tid;
    int d = (i < N_NODES) ? deg[i] : 0;
    s[tid] = d;
    __syncthreads();
    for (int off = 1; off < 256; off <<= 1) {
        int t = (tid >= off) ? s[tid - off] : 0;
        __syncthreads();
        s[tid] += t;
        __syncthreads();
    }
    int excl = boff[blockIdx.x] + s[tid] - d;
    if (i < N_NODES) {
        row_ptr[i] = excl;
        cursor[i]  = excl;
        invdeg[i]  = 1.0f / fmaxf((float)d, 1.0f);
        if (i == N_NODES - 1) row_ptr[N_NODES] = excl + d;
    }
}

__global__ __launch_bounds__(256) void fill_csr(
    const int* __restrict__ src, const int* __restrict__ dst,
    int* __restrict__ cursor, int* __restrict__ csr_src)
{
    int e = blockIdx.x * 256 + threadIdx.x;
    if (e >= N_EDGES) return;
    int pos = atomicAdd(&cursor[dst[e]], 1);
    csr_src[pos] = src[e];
}

// ---------------- convert x to bf16 (4 elems/thread) -------------------------
__global__ __launch_bounds__(256) void x_to_bf16(
    const float* __restrict__ x, __bf16* __restrict__ xb)
{
    int i = blockIdx.x * 256 + threadIdx.x;
    if (i * 4 >= N_NODES * IN_F) return;
    float4 v = reinterpret_cast<const float4*>(x)[i];
    bf16x4 b;
    b[0] = (__bf16)v.x; b[1] = (__bf16)v.y;
    b[2] = (__bf16)v.z; b[3] = (__bf16)v.w;
    *reinterpret_cast<bf16x4*>(xb + i * 4) = b;
}

// ====== pull aggregation, layer 1: bf16 gather, MEAN -> accm_bf16 ============
__global__ __launch_bounds__(256) void agg1_bf(
    const int* __restrict__ row_ptr, const int* __restrict__ csr_src,
    const __bf16* __restrict__ xb, const float* __restrict__ invdeg,
    __bf16* __restrict__ accm)
{
    int gid  = blockIdx.x * 256 + threadIdx.x;
    int node = gid >> 5;
    int j    = gid & 31;
    if (node >= N_NODES || j >= 25) return;
    int beg = row_ptr[node], end = row_ptr[node + 1];
    f32x4 acc = {0.f, 0.f, 0.f, 0.f};
    int e = beg;
    for (; e + 1 < end; e += 2) {
        int s0 = csr_src[e], s1 = csr_src[e + 1];
        bf16x4 v0 = *reinterpret_cast<const bf16x4*>(xb + (size_t)s0 * IN_F + j * 4);
        bf16x4 v1 = *reinterpret_cast<const bf16x4*>(xb + (size_t)s1 * IN_F + j * 4);
#pragma unroll
        for (int q = 0; q < 4; ++q) acc[q] += (float)v0[q] + (float)v1[q];
    }
    if (e < end) {
        bf16x4 v = *reinterpret_cast<const bf16x4*>(xb + (size_t)csr_src[e] * IN_F + j * 4);
#pragma unroll
        for (int q = 0; q < 4; ++q) acc[q] += (float)v[q];
    }
    float inv = invdeg[node];
    bf16x4 r;
#pragma unroll
    for (int q = 0; q < 4; ++q) r[q] = (__bf16)(acc[q] * inv);
    *reinterpret_cast<bf16x4*>(accm + (size_t)node * IN_F + j * 4) = r;
}

// ---------- weight prep: W1^T bf16 [256][224]  (k<100:self, <200:neigh) -----
__global__ __launch_bounds__(256) void build_w1t(
    const float* __restrict__ Ws1, const float* __restrict__ Wn1,
    __bf16* __restrict__ w1t)
{
    int gid = blockIdx.x * 256 + threadIdx.x;
    if (gid >= HID * K1) return;
    int j = gid / K1, k = gid % K1;
    float v = 0.f;
    if (k < IN_F)            v = Ws1[k * HID + j];
    else if (k < 2 * IN_F)   v = Wn1[(k - IN_F) * HID + j];
    w1t[gid] = (__bf16)v;
}

// ---------- weight prep: W2^T bf16 [96][256] (j<47:self, 48..94:neigh) ------
__global__ __launch_bounds__(256) void build_w2t(
    const float* __restrict__ Ws2, const float* __restrict__ Wn2,
    __bf16* __restrict__ w2t)
{
    int gid = blockIdx.x * 256 + threadIdx.x;
    if (gid >= 96 * K2) return;
    int j = gid / K2, k = gid % K2;
    float v = 0.f;
    if (j < NCLS)                 v = Ws2[k * NCLS + j];
    else if (j >= 48 && j < 95)   v = Wn2[k * NCLS + (j - 48)];
    w2t[gid] = (__bf16)v;
}

// ====== FUSED layer-1 + layer-2 MFMA: h1 tile lives in LDS only ==============
// 32 rows/block; 4 waves.
// phase1: wave = 16 rows x 128 cols (8 ct), epilogue(bias,relu,mask) -> hs LDS
// phase2: wave = 16 rows x 48 cols (3 ct): self -> out(+b2), neigh -> z2b
__global__ __launch_bounds__(256) void gemm12_fused(
    const __bf16* __restrict__ xb, const __bf16* __restrict__ accm,
    const __bf16* __restrict__ w1t, const float* __restrict__ b1,
    const uint32_t* __restrict__ mask,
    const __bf16* __restrict__ w2t, const float* __restrict__ b2,
    float* __restrict__ out, __bf16* __restrict__ z2b)
{
    __shared__ __bf16 xs[32][K1S];   // 14.8 KB
    __shared__ __bf16 hs[32][K2S];   // 16.9 KB
    const int row0 = blockIdx.x * 32;
    const int tid  = threadIdx.x;
    const int nrow = min(32, N_NODES - row0);

    // ---- stage (x || mean) bf16, zero-pad k in [200,224) ----
    for (int t = tid; t < 32 * (K1 / 4); t += 256) {
        int r = t / (K1 / 4), c4 = t % (K1 / 4);
        bf16x4 v = {};
        if (r < nrow) {
            if (c4 < 25)
                v = *reinterpret_cast<const bf16x4*>(xb + (size_t)(row0 + r) * IN_F + c4 * 4);
            else if (c4 < 50)
                v = *reinterpret_cast<const bf16x4*>(accm + (size_t)(row0 + r) * IN_F + (c4 - 25) * 4);
        }
        *reinterpret_cast<bf16x4*>(&xs[r][c4 * 4]) = v;
    }
    __syncthreads();

    const int w    = tid >> 6;
    const int lane = tid & 63;
    const int lm   = lane & 15;
    const int lk   = (lane >> 4) * 8;
    const int wr   = (w >> 1) * 16;        // wave row base (0 / 16)
    const int wc   = (w & 1) * 128;        // wave col base (0 / 128)
    const int rbase = wr + (lane >> 4) * 4;

    // ---- phase 1: h1 = (x||mean) @ W1^T ----
    f32x4 acc[8];
#pragma unroll
    for (int ct = 0; ct < 8; ++ct) acc[ct] = (f32x4){0.f, 0.f, 0.f, 0.f};

    for (int kk = 0; kk < K1 / 32; ++kk) {
        const bf16x8 a = *reinterpret_cast<const bf16x8*>(&xs[wr + lm][kk * 32 + lk]);
#pragma unroll
        for (int ct = 0; ct < 8; ++ct) {
            const bf16x8 b = *reinterpret_cast<const bf16x8*>(
                &w1t[(size_t)(wc + ct * 16 + lm) * K1 + kk * 32 + lk]);
            acc[ct] = __builtin_amdgcn_mfma_f32_16x16x32_bf16(a, b, acc[ct], 0, 0, 0);
        }
    }

    // preload mask words: 4 rows x 4 words (128 cols starting at wc)
    uint4 mw[4];
#pragma unroll
    for (int reg = 0; reg < 4; ++reg) {
        int r = rbase + reg;
        if (r < nrow)
            mw[reg] = *reinterpret_cast<const uint4*>(
                &mask[(size_t)(row0 + r) * (HID / 32) + (wc >> 5)]);
    }

    // epilogue 1: bias + ReLU + dropout -> hs (LDS)
#pragma unroll
    for (int ct = 0; ct < 8; ++ct) {
        const int col = wc + ct * 16 + lm;
        const float bj = b1[col];
#pragma unroll
        for (int reg = 0; reg < 4; ++reg) {
            int r = rbase + reg;
            float v = 0.f;
            if (r < nrow) {
                v = fmaxf(acc[ct][reg] + bj, 0.f);
                uint32_t word = ((const uint32_t*)&mw[reg])[ct >> 1];
                v = ((word >> ((ct & 1) * 16 + lm)) & 1u) ? v * 2.0f : 0.f;
            }
            hs[r][col] = (__bf16)v;
        }
    }
    __syncthreads();

    // ---- phase 2: [out_self | z2] = h1 @ W2^T ----
    const int wcb = (w & 1) * 3;          // ct base: cols 0-47 / 48-95
    f32x4 acc2[3];
#pragma unroll
    for (int ct = 0; ct < 3; ++ct) acc2[ct] = (f32x4){0.f, 0.f, 0.f, 0.f};

    for (int kk = 0; kk < K2 / 32; ++kk) {
        const bf16x8 a = *reinterpret_cast<const bf16x8*>(&hs[wr + lm][kk * 32 + lk]);
#pragma unroll
        for (int ct = 0; ct < 3; ++ct) {
            const bf16x8 b = *reinterpret_cast<const bf16x8*>(
                &w2t[(size_t)((wcb + ct) * 16 + lm) * K2 + kk * 32 + lk]);
            acc2[ct] = __builtin_amdgcn_mfma_f32_16x16x32_bf16(a, b, acc2[ct], 0, 0, 0);
        }
    }

#pragma unroll
    for (int ct = 0; ct < 3; ++ct) {
        const int col = (wcb + ct) * 16 + lm;
#pragma unroll
        for (int reg = 0; reg < 4; ++reg) {
            int r = rbase + reg;
            if (r >= nrow) continue;
            int g = row0 + r;
            float v = acc2[ct][reg];
            if (col < NCLS)                 out[(size_t)g * NCLS + col] = v + b2[col];
            else if (col >= 48 && col < 95) z2b[(size_t)g * 48 + (col - 48)] = (__bf16)v;
            else if (col == 95)             z2b[(size_t)g * 48 + 47] = (__bf16)0.f;
        }
    }
}

// ====== pull aggregation, layer 2: bf16 gather of z2b, mean + add ============
__global__ __launch_bounds__(256) void agg2_bf(
    const int* __restrict__ row_ptr, const int* __restrict__ csr_src,
    const __bf16* __restrict__ z2b, const float* __restrict__ invdeg,
    float* __restrict__ out)
{
    int gid  = blockIdx.x * 256 + threadIdx.x;
    int node = gid >> 4;
    int j    = gid & 15;
    if (node >= N_NODES || j >= 12) return;
    int beg = row_ptr[node], end = row_ptr[node + 1];
    f32x4 acc = {0.f, 0.f, 0.f, 0.f};
    int e = beg;
    for (; e + 1 < end; e += 2) {
        int s0 = csr_src[e], s1 = csr_src[e + 1];
        bf16x4 v0 = *reinterpret_cast<const bf16x4*>(z2b + (size_t)s0 * 48 + j * 4);
        bf16x4 v1 = *reinterpret_cast<const bf16x4*>(z2b + (size_t)s1 * 48 + j * 4);
#pragma unroll
        for (int q = 0; q < 4; ++q) acc[q] += (float)v0[q] + (float)v1[q];
    }
    if (e < end) {
        bf16x4 v = *reinterpret_cast<const bf16x4*>(z2b + (size_t)csr_src[e] * 48 + j * 4);
#pragma unroll
        for (int q = 0; q < 4; ++q) acc[q] += (float)v[q];
    }
    float inv = invdeg[node];
#pragma unroll
    for (int q = 0; q < 4; ++q) {
        int col = j * 4 + q;
        if (col < NCLS)
            out[(size_t)node * NCLS + col] += acc[q] * inv;
    }
}

extern "C" void kernel_launch(void* const* d_in, const int* in_sizes, int n_in,
                              void* d_out, int out_size, void* d_ws, size_t ws_size,
                              hipStream_t stream)
{
    const float* x   = (const float*)d_in[0];
    const int*   src = (const int*)  d_in[1];
    const int*   dst = (const int*)  d_in[2];
    const float* Ws1 = (const float*)d_in[3];
    const float* Wn1 = (const float*)d_in[4];
    const float* b1  = (const float*)d_in[5];
    const float* Ws2 = (const float*)d_in[6];
    const float* Wn2 = (const float*)d_in[7];
    const float* b2  = (const float*)d_in[8];
    float* out = (float*)d_out;

    // ---- workspace layout (float-index units) ----
    int*   wsi     = (int*)d_ws;
    int*   deg     = wsi;               //  50,000
    int*   row_ptr = wsi + 50000;       //  50,001
    int*   cursor  = wsi + 100008;      //  50,000
    int*   csr_src = wsi + 150016;      // 800,000  (ends 950,016)
    int*   bsum    = wsi + 950016;      //     196
    int*   boff    = wsi + 950512;      //     196
    float*  wsf    = (float*)d_ws;
    float*  invdeg = wsf + 1000000;                  //  50,000 f32
    __bf16* xb     = (__bf16*)(wsf + 1050000);       //  5.0M bf16
    __bf16* accm   = (__bf16*)(wsf + 3550000);       //  5.0M bf16
    uint32_t* mask = (uint32_t*)(wsf + 6050000);     //  400K u32 (1.6MB)
    __bf16* w1t    = (__bf16*)(wsf + 12450000);      // 57,344 bf16
    __bf16* w2t    = (__bf16*)(wsf + 12480000);      // 24,576 bf16
    __bf16* z2b    = (__bf16*)(wsf + 12500000);      //  2.4M bf16 (~54.8MB)

    hipMemsetAsync(deg, 0, (size_t)50000 * sizeof(int), stream);

    make_mask  <<<(MASK_WORDS + 255) / 256, 256, 0, stream>>>(mask);
    count_deg  <<<(N_EDGES + 255) / 256, 256, 0, stream>>>(dst, deg);
    scan_phaseA<<<SCAN_NB, 256, 0, stream>>>(deg, bsum);
    scan_phaseB<<<1, 256, 0, stream>>>(bsum, boff);
    scan_phaseC<<<SCAN_NB, 256, 0, stream>>>(deg, boff, row_ptr, cursor, invdeg);
    fill_csr   <<<(N_EDGES + 255) / 256, 256, 0, stream>>>(src, dst, cursor, csr_src);

    x_to_bf16<<<(N_NODES * IN_F / 4 + 255) / 256, 256, 0, stream>>>(x, xb);
    build_w1t<<<(HID * K1 + 255) / 256, 256, 0, stream>>>(Ws1, Wn1, w1t);
    build_w2t<<<(96 * K2 + 255) / 256, 256, 0, stream>>>(Ws2, Wn2, w2t);

    agg1_bf<<<(N_NODES * 32 + 255) / 256, 256, 0, stream>>>(row_ptr, csr_src, xb, invdeg, accm);
    gemm12_fused<<<(N_NODES + 31) / 32, 256, 0, stream>>>(
        xb, accm, w1t, b1, mask, w2t, b2, out, z2b);
    agg2_bf<<<(N_NODES * 16 + 255) / 256, 256, 0, stream>>>(row_ptr, csr_src, z2b, invdeg, out);
}

// Round 10
// 233.035 us; speedup vs baseline: 3.5575x; 1.1141x over previous
//
#include <hip/hip_runtime.h>
#include <stdint.h>

#define N_NODES 50000
#define N_EDGES 800000
#define IN_F    100
#define HID     256
#define NCLS    47
#define K1      224   // 200 padded to 7*32
#define K1S     232   // LDS row stride (bank-spread)
#define K2      256
#define K2S     264
#define SCAN_NB ((N_NODES + 255) / 256)
#define MASK_WORDS (N_NODES * (HID / 32))   // 400,000

typedef __bf16 bf16x8 __attribute__((ext_vector_type(8)));
typedef __bf16 bf16x4 __attribute__((ext_vector_type(4)));
typedef float  f32x4  __attribute__((ext_vector_type(4)));

__device__ __forceinline__ uint32_t rotl32(uint32_t v, uint32_t r) {
    return (v << r) | (v >> (32u - r));
}

// JAX threefry2x32, key=(0,42), partitionable: counter=(0,i), bits=x0^x1.
// bernoulli(0.5) keeps iff MSB==0.  (verified round 2)
__device__ __forceinline__ uint32_t jax_bits(uint32_t i) {
    const uint32_t ks0 = 0u, ks1 = 42u, ks2 = 0x1BD11BDAu ^ 42u;
    uint32_t x0 = 0u + ks0;
    uint32_t x1 = i + ks1;
    x0 += x1; x1 = rotl32(x1, 13); x1 ^= x0;
    x0 += x1; x1 = rotl32(x1, 15); x1 ^= x0;
    x0 += x1; x1 = rotl32(x1, 26); x1 ^= x0;
    x0 += x1; x1 = rotl32(x1,  6); x1 ^= x0;
    x0 += ks1; x1 += ks2 + 1u;
    x0 += x1; x1 = rotl32(x1, 17); x1 ^= x0;
    x0 += x1; x1 = rotl32(x1, 29); x1 ^= x0;
    x0 += x1; x1 = rotl32(x1, 16); x1 ^= x0;
    x0 += x1; x1 = rotl32(x1, 24); x1 ^= x0;
    x0 += ks2; x1 += ks0 + 2u;
    x0 += x1; x1 = rotl32(x1, 13); x1 ^= x0;
    x0 += x1; x1 = rotl32(x1, 15); x1 ^= x0;
    x0 += x1; x1 = rotl32(x1, 26); x1 ^= x0;
    x0 += x1; x1 = rotl32(x1,  6); x1 ^= x0;
    x0 += ks0; x1 += ks1 + 3u;
    x0 += x1; x1 = rotl32(x1, 17); x1 ^= x0;
    x0 += x1; x1 = rotl32(x1, 29); x1 ^= x0;
    x0 += x1; x1 = rotl32(x1, 16); x1 ^= x0;
    x0 += x1; x1 = rotl32(x1, 24); x1 ^= x0;
    x0 += ks1; x1 += ks2 + 4u;
    x0 += x1; x1 = rotl32(x1, 13); x1 ^= x0;
    x0 += x1; x1 = rotl32(x1, 15); x1 ^= x0;
    x0 += x1; x1 = rotl32(x1, 26); x1 ^= x0;
    x0 += x1; x1 = rotl32(x1,  6); x1 ^= x0;
    x0 += ks2; x1 += ks0 + 5u;
    return x0 ^ x1;
}

// ---------------- dropout mask: 1 bit per h1 element (keep=1) ----------------
__global__ __launch_bounds__(256) void make_mask(uint32_t* __restrict__ mask)
{
    int w = blockIdx.x * 256 + threadIdx.x;
    if (w >= MASK_WORDS) return;
    uint32_t base = (uint32_t)w * 32u;
    uint32_t m = 0u;
#pragma unroll
    for (int j = 0; j < 32; ++j) {
        uint32_t bits = jax_bits(base + (uint32_t)j);
        m |= ((~bits) >> 31) << j;   // keep iff MSB==0
    }
    mask[w] = m;
}

// ======================= CSR build (dst -> srcs) =============================
__global__ __launch_bounds__(256) void count_deg(
    const int* __restrict__ dst, int* __restrict__ deg)
{
    int e = blockIdx.x * 256 + threadIdx.x;
    if (e < N_EDGES) atomicAdd(&deg[dst[e]], 1);
}

__global__ __launch_bounds__(256) void scan_phaseA(
    const int* __restrict__ deg, int* __restrict__ bsum)
{
    __shared__ int red[256];
    int i = blockIdx.x * 256 + threadIdx.x;
    int v = (i < N_NODES) ? deg[i] : 0;
    red[threadIdx.x] = v;
    __syncthreads();
    for (int off = 128; off > 0; off >>= 1) {
        if (threadIdx.x < off) red[threadIdx.x] += red[threadIdx.x + off];
        __syncthreads();
    }
    if (threadIdx.x == 0) bsum[blockIdx.x] = red[0];
}

__global__ __launch_bounds__(256) void scan_phaseB(
    const int* __restrict__ bsum, int* __restrict__ boff)
{
    __shared__ int s[256];
    int tid = threadIdx.x;
    int v = (tid < SCAN_NB) ? bsum[tid] : 0;
    s[tid] = v;
    __syncthreads();
    for (int off = 1; off < 256; off <<= 1) {
        int t = (tid >= off) ? s[tid - off] : 0;
        __syncthreads();
        s[tid] += t;
        __syncthreads();
    }
    if (tid < SCAN_NB) boff[tid] = s[tid] - v;
}

__global__ __launch_bounds__(256) void scan_phaseC(
    const int* __restrict__ deg, const int* __restrict__ boff,
    int* __restrict__ row_ptr, int* __restrict__ cursor,
    float* __restrict__ invdeg)
{
    __shared__ int s[256];
    int tid = threadIdx.x;
    int i = blockIdx.x * 256 + tid;
    int d = (i < N_NODES) ? deg[i] : 0;
    s[tid] = d;
    __syncthreads();
    for (int off = 1; off < 256; off <<= 1) {
        int t = (tid >= off) ? s[tid - off] : 0;
        __syncthreads();
        s[tid] += t;
        __syncthreads();
    }
    int excl = boff[blockIdx.x] + s[tid] - d;
    if (i < N_NODES) {
        row_ptr[i] = excl;
        cursor[i]  = excl;
        invdeg[i]  = 1.0f / fmaxf((float)d, 1.0f);
        if (i == N_NODES - 1) row_ptr[N_NODES] = excl + d;
    }
}

__global__ __launch_bounds__(256) void fill_csr(
    const int* __restrict__ src, const int* __restrict__ dst,
    int* __restrict__ cursor, int* __restrict__ csr_src)
{
    int e = blockIdx.x * 256 + threadIdx.x;
    if (e >= N_EDGES) return;
    int pos = atomicAdd(&cursor[dst[e]], 1);
    csr_src[pos] = src[e];
}

// ---------------- convert x to bf16 (4 elems/thread) -------------------------
__global__ __launch_bounds__(256) void x_to_bf16(
    const float* __restrict__ x, __bf16* __restrict__ xb)
{
    int i = blockIdx.x * 256 + threadIdx.x;
    if (i * 4 >= N_NODES * IN_F) return;
    float4 v = reinterpret_cast<const float4*>(x)[i];
    bf16x4 b;
    b[0] = (__bf16)v.x; b[1] = (__bf16)v.y;
    b[2] = (__bf16)v.z; b[3] = (__bf16)v.w;
    *reinterpret_cast<bf16x4*>(xb + i * 4) = b;
}

// ====== pull aggregation, layer 1: bf16 gather, MEAN -> accm_bf16 ============
__global__ __launch_bounds__(256) void agg1_bf(
    const int* __restrict__ row_ptr, const int* __restrict__ csr_src,
    const __bf16* __restrict__ xb, const float* __restrict__ invdeg,
    __bf16* __restrict__ accm)
{
    int gid  = blockIdx.x * 256 + threadIdx.x;
    int node = gid >> 5;
    int j    = gid & 31;
    if (node >= N_NODES || j >= 25) return;
    int beg = row_ptr[node], end = row_ptr[node + 1];
    f32x4 acc = {0.f, 0.f, 0.f, 0.f};
    int e = beg;
    for (; e + 1 < end; e += 2) {
        int s0 = csr_src[e], s1 = csr_src[e + 1];
        bf16x4 v0 = *reinterpret_cast<const bf16x4*>(xb + (size_t)s0 * IN_F + j * 4);
        bf16x4 v1 = *reinterpret_cast<const bf16x4*>(xb + (size_t)s1 * IN_F + j * 4);
#pragma unroll
        for (int q = 0; q < 4; ++q) acc[q] += (float)v0[q] + (float)v1[q];
    }
    if (e < end) {
        bf16x4 v = *reinterpret_cast<const bf16x4*>(xb + (size_t)csr_src[e] * IN_F + j * 4);
#pragma unroll
        for (int q = 0; q < 4; ++q) acc[q] += (float)v[q];
    }
    float inv = invdeg[node];
    bf16x4 r;
#pragma unroll
    for (int q = 0; q < 4; ++q) r[q] = (__bf16)(acc[q] * inv);
    *reinterpret_cast<bf16x4*>(accm + (size_t)node * IN_F + j * 4) = r;
}

// ---------- weight prep: W1^T bf16 [256][224]  (k<100:self, <200:neigh) -----
__global__ __launch_bounds__(256) void build_w1t(
    const float* __restrict__ Ws1, const float* __restrict__ Wn1,
    __bf16* __restrict__ w1t)
{
    int gid = blockIdx.x * 256 + threadIdx.x;
    if (gid >= HID * K1) return;
    int j = gid / K1, k = gid % K1;
    float v = 0.f;
    if (k < IN_F)            v = Ws1[k * HID + j];
    else if (k < 2 * IN_F)   v = Wn1[(k - IN_F) * HID + j];
    w1t[gid] = (__bf16)v;
}

// ---------- weight prep: W2^T bf16 [96][256] (j<47:self, 48..94:neigh) ------
__global__ __launch_bounds__(256) void build_w2t(
    const float* __restrict__ Ws2, const float* __restrict__ Wn2,
    __bf16* __restrict__ w2t)
{
    int gid = blockIdx.x * 256 + threadIdx.x;
    if (gid >= 96 * K2) return;
    int j = gid / K2, k = gid % K2;
    float v = 0.f;
    if (j < NCLS)                 v = Ws2[k * NCLS + j];
    else if (j >= 48 && j < 95)   v = Wn2[k * NCLS + (j - 48)];
    w2t[gid] = (__bf16)v;
}

// ====== FUSED layer-1 + layer-2 MFMA: weight-amortized, 64 rows/block ========
// 512 threads = 8 waves.
// phase1: wave w = 64 rows x 32 cols (cols w*32..w*32+31), acc[2ct][4rg]
// phase2: waves 0..5 = 64 rows x 16 cols (cols w*16..w*16+15), acc2[4rg]
__global__ __launch_bounds__(512) void gemm12_fused(
    const __bf16* __restrict__ xb, const __bf16* __restrict__ accm,
    const __bf16* __restrict__ w1t, const float* __restrict__ b1,
    const uint32_t* __restrict__ mask,
    const __bf16* __restrict__ w2t, const float* __restrict__ b2,
    float* __restrict__ out, __bf16* __restrict__ z2b)
{
    __shared__ __bf16 xs[64][K1S];     // 29.0 KB
    __shared__ __bf16 hs[64][K2S];     // 33.0 KB
    __shared__ uint32_t msk[64][8];    //  2.0 KB   (total 64 KB -> 2 blocks/CU)
    const int row0 = blockIdx.x * 64;
    const int tid  = threadIdx.x;
    const int nrow = min(64, N_NODES - row0);

    // ---- stage (x || mean) bf16 (zero-pad k in [200,224)) + mask words ----
    for (int t = tid; t < 64 * (K1 / 4); t += 512) {
        int r = t / (K1 / 4), c4 = t % (K1 / 4);
        bf16x4 v = {};
        if (r < nrow) {
            if (c4 < 25)
                v = *reinterpret_cast<const bf16x4*>(xb + (size_t)(row0 + r) * IN_F + c4 * 4);
            else if (c4 < 50)
                v = *reinterpret_cast<const bf16x4*>(accm + (size_t)(row0 + r) * IN_F + (c4 - 25) * 4);
        }
        *reinterpret_cast<bf16x4*>(&xs[r][c4 * 4]) = v;
    }
    {
        int r = tid >> 3, w8 = tid & 7;
        msk[r][w8] = (r < nrow) ? mask[(size_t)(row0 + r) * 8 + w8] : 0u;
    }
    __syncthreads();

    const int w    = tid >> 6;          // wave 0..7
    const int lane = tid & 63;
    const int lm   = lane & 15;
    const int hi   = lane >> 4;         // 0..3
    const int lk   = hi * 8;

    // ---- phase 1: h1 = (x||mean) @ W1^T ; wave cols = w*32 + ct*16 + lm ----
    const int wc = w * 32;
    f32x4 acc[2][4];
#pragma unroll
    for (int ct = 0; ct < 2; ++ct)
#pragma unroll
        for (int rg = 0; rg < 4; ++rg) acc[ct][rg] = (f32x4){0.f, 0.f, 0.f, 0.f};

    for (int kk = 0; kk < K1 / 32; ++kk) {
        bf16x8 a[4];
#pragma unroll
        for (int rg = 0; rg < 4; ++rg)
            a[rg] = *reinterpret_cast<const bf16x8*>(&xs[rg * 16 + lm][kk * 32 + lk]);
#pragma unroll
        for (int ct = 0; ct < 2; ++ct) {
            const bf16x8 b = *reinterpret_cast<const bf16x8*>(
                &w1t[(size_t)(wc + ct * 16 + lm) * K1 + kk * 32 + lk]);
#pragma unroll
            for (int rg = 0; rg < 4; ++rg)
                acc[ct][rg] = __builtin_amdgcn_mfma_f32_16x16x32_bf16(a[rg], b, acc[ct][rg], 0, 0, 0);
        }
    }

    // epilogue 1: bias + ReLU + dropout -> hs (LDS); all rows/cols written
#pragma unroll
    for (int ct = 0; ct < 2; ++ct) {
        const int col = wc + ct * 16 + lm;
        const float bj = b1[col];
        const int bit = ct * 16 + lm;
#pragma unroll
        for (int rg = 0; rg < 4; ++rg) {
#pragma unroll
            for (int reg = 0; reg < 4; ++reg) {
                int r = rg * 16 + hi * 4 + reg;
                float v = 0.f;
                if (r < nrow) {
                    v = fmaxf(acc[ct][rg][reg] + bj, 0.f);
                    v = ((msk[r][w] >> bit) & 1u) ? v * 2.0f : 0.f;
                }
                hs[r][col] = (__bf16)v;
            }
        }
    }
    __syncthreads();

    // ---- phase 2: [out_self | z2] = h1 @ W2^T ; waves 0..5, 16 cols each ----
    if (w < 6) {
        const int wc2 = w * 16;
        f32x4 acc2[4];
#pragma unroll
        for (int rg = 0; rg < 4; ++rg) acc2[rg] = (f32x4){0.f, 0.f, 0.f, 0.f};

        for (int kk = 0; kk < K2 / 32; ++kk) {
            bf16x8 a[4];
#pragma unroll
            for (int rg = 0; rg < 4; ++rg)
                a[rg] = *reinterpret_cast<const bf16x8*>(&hs[rg * 16 + lm][kk * 32 + lk]);
            const bf16x8 b = *reinterpret_cast<const bf16x8*>(
                &w2t[(size_t)(wc2 + lm) * K2 + kk * 32 + lk]);
#pragma unroll
            for (int rg = 0; rg < 4; ++rg)
                acc2[rg] = __builtin_amdgcn_mfma_f32_16x16x32_bf16(a[rg], b, acc2[rg], 0, 0, 0);
        }

        const int col = wc2 + lm;
#pragma unroll
        for (int rg = 0; rg < 4; ++rg) {
#pragma unroll
            for (int reg = 0; reg < 4; ++reg) {
                int r = rg * 16 + hi * 4 + reg;
                if (r >= nrow) continue;
                int g = row0 + r;
                float v = acc2[rg][reg];
                if (col < NCLS)                 out[(size_t)g * NCLS + col] = v + b2[col];
                else if (col >= 48 && col < 95) z2b[(size_t)g * 48 + (col - 48)] = (__bf16)v;
                else if (col == 95)             z2b[(size_t)g * 48 + 47] = (__bf16)0.f;
            }
        }
    }
}

// ====== pull aggregation, layer 2: bf16 gather of z2b, mean + add ============
__global__ __launch_bounds__(256) void agg2_bf(
    const int* __restrict__ row_ptr, const int* __restrict__ csr_src,
    const __bf16* __restrict__ z2b, const float* __restrict__ invdeg,
    float* __restrict__ out)
{
    int gid  = blockIdx.x * 256 + threadIdx.x;
    int node = gid >> 4;
    int j    = gid & 15;
    if (node >= N_NODES || j >= 12) return;
    int beg = row_ptr[node], end = row_ptr[node + 1];
    f32x4 acc = {0.f, 0.f, 0.f, 0.f};
    int e = beg;
    for (; e + 1 < end; e += 2) {
        int s0 = csr_src[e], s1 = csr_src[e + 1];
        bf16x4 v0 = *reinterpret_cast<const bf16x4*>(z2b + (size_t)s0 * 48 + j * 4);
        bf16x4 v1 = *reinterpret_cast<const bf16x4*>(z2b + (size_t)s1 * 48 + j * 4);
#pragma unroll
        for (int q = 0; q < 4; ++q) acc[q] += (float)v0[q] + (float)v1[q];
    }
    if (e < end) {
        bf16x4 v = *reinterpret_cast<const bf16x4*>(z2b + (size_t)csr_src[e] * 48 + j * 4);
#pragma unroll
        for (int q = 0; q < 4; ++q) acc[q] += (float)v[q];
    }
    float inv = invdeg[node];
#pragma unroll
    for (int q = 0; q < 4; ++q) {
        int col = j * 4 + q;
        if (col < NCLS)
            out[(size_t)node * NCLS + col] += acc[q] * inv;
    }
}

extern "C" void kernel_launch(void* const* d_in, const int* in_sizes, int n_in,
                              void* d_out, int out_size, void* d_ws, size_t ws_size,
                              hipStream_t stream)
{
    const float* x   = (const float*)d_in[0];
    const int*   src = (const int*)  d_in[1];
    const int*   dst = (const int*)  d_in[2];
    const float* Ws1 = (const float*)d_in[3];
    const float* Wn1 = (const float*)d_in[4];
    const float* b1  = (const float*)d_in[5];
    const float* Ws2 = (const float*)d_in[6];
    const float* Wn2 = (const float*)d_in[7];
    const float* b2  = (const float*)d_in[8];
    float* out = (float*)d_out;

    // ---- workspace layout (float-index units) ----
    int*   wsi     = (int*)d_ws;
    int*   deg     = wsi;               //  50,000
    int*   row_ptr = wsi + 50000;       //  50,001
    int*   cursor  = wsi + 100008;      //  50,000
    int*   csr_src = wsi + 150016;      // 800,000  (ends 950,016)
    int*   bsum    = wsi + 950016;      //     196
    int*   boff    = wsi + 950512;      //     196
    float*  wsf    = (float*)d_ws;
    float*  invdeg = wsf + 1000000;                  //  50,000 f32
    __bf16* xb     = (__bf16*)(wsf + 1050000);       //  5.0M bf16
    __bf16* accm   = (__bf16*)(wsf + 3550000);       //  5.0M bf16
    uint32_t* mask = (uint32_t*)(wsf + 6050000);     //  400K u32 (1.6MB)
    __bf16* w1t    = (__bf16*)(wsf + 12450000);      // 57,344 bf16
    __bf16* w2t    = (__bf16*)(wsf + 12480000);      // 24,576 bf16
    __bf16* z2b    = (__bf16*)(wsf + 12500000);      //  2.4M bf16 (~54.8MB)

    hipMemsetAsync(deg, 0, (size_t)50000 * sizeof(int), stream);

    make_mask  <<<(MASK_WORDS + 255) / 256, 256, 0, stream>>>(mask);
    count_deg  <<<(N_EDGES + 255) / 256, 256, 0, stream>>>(dst, deg);
    scan_phaseA<<<SCAN_NB, 256, 0, stream>>>(deg, bsum);
    scan_phaseB<<<1, 256, 0, stream>>>(bsum, boff);
    scan_phaseC<<<SCAN_NB, 256, 0, stream>>>(deg, boff, row_ptr, cursor, invdeg);
    fill_csr   <<<(N_EDGES + 255) / 256, 256, 0, stream>>>(src, dst, cursor, csr_src);

    x_to_bf16<<<(N_NODES * IN_F / 4 + 255) / 256, 256, 0, stream>>>(x, xb);
    build_w1t<<<(HID * K1 + 255) / 256, 256, 0, stream>>>(Ws1, Wn1, w1t);
    build_w2t<<<(96 * K2 + 255) / 256, 256, 0, stream>>>(Ws2, Wn2, w2t);

    agg1_bf<<<(N_NODES * 32 + 255) / 256, 256, 0, stream>>>(row_ptr, csr_src, xb, invdeg, accm);
    gemm12_fused<<<(N_NODES + 63) / 64, 512, 0, stream>>>(
        xb, accm, w1t, b1, mask, w2t, b2, out, z2b);
    agg2_bf<<<(N_NODES * 16 + 255) / 256, 256, 0, stream>>>(row_ptr, csr_src, z2b, invdeg, out);
}

// Round 11
// 227.865 us; speedup vs baseline: 3.6383x; 1.0227x over previous
//
#include <hip/hip_runtime.h>
#include <stdint.h>

#define N_NODES 50000
#define N_EDGES 800000
#define IN_F    100
#define HID     256
#define NCLS    47
#define K1      224   // 200 padded to 7*32
#define K1S     232   // LDS row stride (bank-spread)
#define K2      256
#define K2S     264
#define SCAN_NB ((N_NODES + 255) / 256)
#define MASK_WORDS (N_NODES * (HID / 32))   // 400,000

typedef __bf16 bf16x8 __attribute__((ext_vector_type(8)));
typedef __bf16 bf16x4 __attribute__((ext_vector_type(4)));
typedef float  f32x4  __attribute__((ext_vector_type(4)));

__device__ __forceinline__ uint32_t rotl32(uint32_t v, uint32_t r) {
    return (v << r) | (v >> (32u - r));
}

// JAX threefry2x32, key=(0,42), partitionable: counter=(0,i), bits=x0^x1.
// bernoulli(0.5) keeps iff MSB==0.  (verified round 2)
__device__ __forceinline__ uint32_t jax_bits(uint32_t i) {
    const uint32_t ks0 = 0u, ks1 = 42u, ks2 = 0x1BD11BDAu ^ 42u;
    uint32_t x0 = 0u + ks0;
    uint32_t x1 = i + ks1;
    x0 += x1; x1 = rotl32(x1, 13); x1 ^= x0;
    x0 += x1; x1 = rotl32(x1, 15); x1 ^= x0;
    x0 += x1; x1 = rotl32(x1, 26); x1 ^= x0;
    x0 += x1; x1 = rotl32(x1,  6); x1 ^= x0;
    x0 += ks1; x1 += ks2 + 1u;
    x0 += x1; x1 = rotl32(x1, 17); x1 ^= x0;
    x0 += x1; x1 = rotl32(x1, 29); x1 ^= x0;
    x0 += x1; x1 = rotl32(x1, 16); x1 ^= x0;
    x0 += x1; x1 = rotl32(x1, 24); x1 ^= x0;
    x0 += ks2; x1 += ks0 + 2u;
    x0 += x1; x1 = rotl32(x1, 13); x1 ^= x0;
    x0 += x1; x1 = rotl32(x1, 15); x1 ^= x0;
    x0 += x1; x1 = rotl32(x1, 26); x1 ^= x0;
    x0 += x1; x1 = rotl32(x1,  6); x1 ^= x0;
    x0 += ks0; x1 += ks1 + 3u;
    x0 += x1; x1 = rotl32(x1, 17); x1 ^= x0;
    x0 += x1; x1 = rotl32(x1, 29); x1 ^= x0;
    x0 += x1; x1 = rotl32(x1, 16); x1 ^= x0;
    x0 += x1; x1 = rotl32(x1, 24); x1 ^= x0;
    x0 += ks1; x1 += ks2 + 4u;
    x0 += x1; x1 = rotl32(x1, 13); x1 ^= x0;
    x0 += x1; x1 = rotl32(x1, 15); x1 ^= x0;
    x0 += x1; x1 = rotl32(x1, 26); x1 ^= x0;
    x0 += x1; x1 = rotl32(x1,  6); x1 ^= x0;
    x0 += ks2; x1 += ks0 + 5u;
    return x0 ^ x1;
}

// ---------------- dropout mask: 1 bit per h1 element (keep=1) ----------------
__global__ __launch_bounds__(256) void make_mask(uint32_t* __restrict__ mask)
{
    int w = blockIdx.x * 256 + threadIdx.x;
    if (w >= MASK_WORDS) return;
    uint32_t base = (uint32_t)w * 32u;
    uint32_t m = 0u;
#pragma unroll
    for (int j = 0; j < 32; ++j) {
        uint32_t bits = jax_bits(base + (uint32_t)j);
        m |= ((~bits) >> 31) << j;   // keep iff MSB==0
    }
    mask[w] = m;
}

// ======================= CSR build (dst -> srcs) =============================
__global__ __launch_bounds__(256) void count_deg(
    const int* __restrict__ dst, int* __restrict__ deg)
{
    int e = blockIdx.x * 256 + threadIdx.x;
    if (e < N_EDGES) atomicAdd(&deg[dst[e]], 1);
}

__global__ __launch_bounds__(256) void scan_phaseA(
    const int* __restrict__ deg, int* __restrict__ bsum)
{
    __shared__ int red[256];
    int i = blockIdx.x * 256 + threadIdx.x;
    int v = (i < N_NODES) ? deg[i] : 0;
    red[threadIdx.x] = v;
    __syncthreads();
    for (int off = 128; off > 0; off >>= 1) {
        if (threadIdx.x < off) red[threadIdx.x] += red[threadIdx.x + off];
        __syncthreads();
    }
    if (threadIdx.x == 0) bsum[blockIdx.x] = red[0];
}

__global__ __launch_bounds__(256) void scan_phaseB(
    const int* __restrict__ bsum, int* __restrict__ boff)
{
    __shared__ int s[256];
    int tid = threadIdx.x;
    int v = (tid < SCAN_NB) ? bsum[tid] : 0;
    s[tid] = v;
    __syncthreads();
    for (int off = 1; off < 256; off <<= 1) {
        int t = (tid >= off) ? s[tid - off] : 0;
        __syncthreads();
        s[tid] += t;
        __syncthreads();
    }
    if (tid < SCAN_NB) boff[tid] = s[tid] - v;
}

__global__ __launch_bounds__(256) void scan_phaseC(
    const int* __restrict__ deg, const int* __restrict__ boff,
    int* __restrict__ row_ptr, int* __restrict__ cursor,
    float* __restrict__ invdeg)
{
    __shared__ int s[256];
    int tid = threadIdx.x;
    int i = blockIdx.x * 256 + tid;
    int d = (i < N_NODES) ? deg[i] : 0;
    s[tid] = d;
    __syncthreads();
    for (int off = 1; off < 256; off <<= 1) {
        int t = (tid >= off) ? s[tid - off] : 0;
        __syncthreads();
        s[tid] += t;
        __syncthreads();
    }
    int excl = boff[blockIdx.x] + s[tid] - d;
    if (i < N_NODES) {
        row_ptr[i] = excl;
        cursor[i]  = excl;
        invdeg[i]  = 1.0f / fmaxf((float)d, 1.0f);
        if (i == N_NODES - 1) row_ptr[N_NODES] = excl + d;
    }
}

// CSR adjacency stored as uint16 (src < 50000 < 65536): halves the
// random-scatter write amplification (round-10 counter: 51.6MB WRITE for 3.2MB)
__global__ __launch_bounds__(256) void fill_csr(
    const int* __restrict__ src, const int* __restrict__ dst,
    int* __restrict__ cursor, uint16_t* __restrict__ csr_src)
{
    int e = blockIdx.x * 256 + threadIdx.x;
    if (e >= N_EDGES) return;
    int pos = atomicAdd(&cursor[dst[e]], 1);
    csr_src[pos] = (uint16_t)src[e];
}

// ---------------- convert x to bf16 (4 elems/thread) -------------------------
__global__ __launch_bounds__(256) void x_to_bf16(
    const float* __restrict__ x, __bf16* __restrict__ xb)
{
    int i = blockIdx.x * 256 + threadIdx.x;
    if (i * 4 >= N_NODES * IN_F) return;
    float4 v = reinterpret_cast<const float4*>(x)[i];
    bf16x4 b;
    b[0] = (__bf16)v.x; b[1] = (__bf16)v.y;
    b[2] = (__bf16)v.z; b[3] = (__bf16)v.w;
    *reinterpret_cast<bf16x4*>(xb + i * 4) = b;
}

// ====== pull aggregation, layer 1: bf16 gather, MEAN -> accm_bf16 ============
__global__ __launch_bounds__(256) void agg1_bf(
    const int* __restrict__ row_ptr, const uint16_t* __restrict__ csr_src,
    const __bf16* __restrict__ xb, const float* __restrict__ invdeg,
    __bf16* __restrict__ accm)
{
    int gid  = blockIdx.x * 256 + threadIdx.x;
    int node = gid >> 5;
    int j    = gid & 31;
    if (node >= N_NODES || j >= 25) return;
    int beg = row_ptr[node], end = row_ptr[node + 1];
    f32x4 acc = {0.f, 0.f, 0.f, 0.f};
    int e = beg;
    for (; e + 1 < end; e += 2) {
        int s0 = csr_src[e], s1 = csr_src[e + 1];
        bf16x4 v0 = *reinterpret_cast<const bf16x4*>(xb + (size_t)s0 * IN_F + j * 4);
        bf16x4 v1 = *reinterpret_cast<const bf16x4*>(xb + (size_t)s1 * IN_F + j * 4);
#pragma unroll
        for (int q = 0; q < 4; ++q) acc[q] += (float)v0[q] + (float)v1[q];
    }
    if (e < end) {
        bf16x4 v = *reinterpret_cast<const bf16x4*>(xb + (size_t)csr_src[e] * IN_F + j * 4);
#pragma unroll
        for (int q = 0; q < 4; ++q) acc[q] += (float)v[q];
    }
    float inv = invdeg[node];
    bf16x4 r;
#pragma unroll
    for (int q = 0; q < 4; ++q) r[q] = (__bf16)(acc[q] * inv);
    *reinterpret_cast<bf16x4*>(accm + (size_t)node * IN_F + j * 4) = r;
}

// ---------- weight prep: W1^T bf16 [256][224]  (k<100:self, <200:neigh) -----
__global__ __launch_bounds__(256) void build_w1t(
    const float* __restrict__ Ws1, const float* __restrict__ Wn1,
    __bf16* __restrict__ w1t)
{
    int gid = blockIdx.x * 256 + threadIdx.x;
    if (gid >= HID * K1) return;
    int j = gid / K1, k = gid % K1;
    float v = 0.f;
    if (k < IN_F)            v = Ws1[k * HID + j];
    else if (k < 2 * IN_F)   v = Wn1[(k - IN_F) * HID + j];
    w1t[gid] = (__bf16)v;
}

// ---------- weight prep: W2^T bf16 [96][256] (j<47:self, 48..94:neigh) ------
__global__ __launch_bounds__(256) void build_w2t(
    const float* __restrict__ Ws2, const float* __restrict__ Wn2,
    __bf16* __restrict__ w2t)
{
    int gid = blockIdx.x * 256 + threadIdx.x;
    if (gid >= 96 * K2) return;
    int j = gid / K2, k = gid % K2;
    float v = 0.f;
    if (j < NCLS)                 v = Ws2[k * NCLS + j];
    else if (j >= 48 && j < 95)   v = Wn2[k * NCLS + (j - 48)];
    w2t[gid] = (__bf16)v;
}

// ====== FUSED layer-1 + layer-2 MFMA: weight-amortized, 64 rows/block ========
// 512 threads = 8 waves.
// phase1: wave w = 64 rows x 32 cols (cols w*32..w*32+31), acc[2ct][4rg]
// phase2: waves 0..5 = 64 rows x 16 cols (cols w*16..w*16+15), acc2[4rg]
__global__ __launch_bounds__(512) void gemm12_fused(
    const __bf16* __restrict__ xb, const __bf16* __restrict__ accm,
    const __bf16* __restrict__ w1t, const float* __restrict__ b1,
    const uint32_t* __restrict__ mask,
    const __bf16* __restrict__ w2t, const float* __restrict__ b2,
    float* __restrict__ out, __bf16* __restrict__ z2b)
{
    __shared__ __bf16 xs[64][K1S];     // 29.0 KB
    __shared__ __bf16 hs[64][K2S];     // 33.0 KB
    __shared__ uint32_t msk[64][8];    //  2.0 KB   (total 64 KB -> 2 blocks/CU)
    const int row0 = blockIdx.x * 64;
    const int tid  = threadIdx.x;
    const int nrow = min(64, N_NODES - row0);

    // ---- stage (x || mean) bf16 (zero-pad k in [200,224)) + mask words ----
    for (int t = tid; t < 64 * (K1 / 4); t += 512) {
        int r = t / (K1 / 4), c4 = t % (K1 / 4);
        bf16x4 v = {};
        if (r < nrow) {
            if (c4 < 25)
                v = *reinterpret_cast<const bf16x4*>(xb + (size_t)(row0 + r) * IN_F + c4 * 4);
            else if (c4 < 50)
                v = *reinterpret_cast<const bf16x4*>(accm + (size_t)(row0 + r) * IN_F + (c4 - 25) * 4);
        }
        *reinterpret_cast<bf16x4*>(&xs[r][c4 * 4]) = v;
    }
    {
        int r = tid >> 3, w8 = tid & 7;
        msk[r][w8] = (r < nrow) ? mask[(size_t)(row0 + r) * 8 + w8] : 0u;
    }
    __syncthreads();

    const int w    = tid >> 6;          // wave 0..7
    const int lane = tid & 63;
    const int lm   = lane & 15;
    const int hi   = lane >> 4;         // 0..3
    const int lk   = hi * 8;

    // ---- phase 1: h1 = (x||mean) @ W1^T ; wave cols = w*32 + ct*16 + lm ----
    const int wc = w * 32;
    f32x4 acc[2][4];
#pragma unroll
    for (int ct = 0; ct < 2; ++ct)
#pragma unroll
        for (int rg = 0; rg < 4; ++rg) acc[ct][rg] = (f32x4){0.f, 0.f, 0.f, 0.f};

    for (int kk = 0; kk < K1 / 32; ++kk) {
        bf16x8 a[4];
#pragma unroll
        for (int rg = 0; rg < 4; ++rg)
            a[rg] = *reinterpret_cast<const bf16x8*>(&xs[rg * 16 + lm][kk * 32 + lk]);
#pragma unroll
        for (int ct = 0; ct < 2; ++ct) {
            const bf16x8 b = *reinterpret_cast<const bf16x8*>(
                &w1t[(size_t)(wc + ct * 16 + lm) * K1 + kk * 32 + lk]);
#pragma unroll
            for (int rg = 0; rg < 4; ++rg)
                acc[ct][rg] = __builtin_amdgcn_mfma_f32_16x16x32_bf16(a[rg], b, acc[ct][rg], 0, 0, 0);
        }
    }

    // epilogue 1: bias + ReLU + dropout -> hs (LDS); all rows/cols written
#pragma unroll
    for (int ct = 0; ct < 2; ++ct) {
        const int col = wc + ct * 16 + lm;
        const float bj = b1[col];
        const int bit = ct * 16 + lm;
#pragma unroll
        for (int rg = 0; rg < 4; ++rg) {
#pragma unroll
            for (int reg = 0; reg < 4; ++reg) {
                int r = rg * 16 + hi * 4 + reg;
                float v = 0.f;
                if (r < nrow) {
                    v = fmaxf(acc[ct][rg][reg] + bj, 0.f);
                    v = ((msk[r][w] >> bit) & 1u) ? v * 2.0f : 0.f;
                }
                hs[r][col] = (__bf16)v;
            }
        }
    }
    __syncthreads();

    // ---- phase 2: [out_self | z2] = h1 @ W2^T ; waves 0..5, 16 cols each ----
    if (w < 6) {
        const int wc2 = w * 16;
        f32x4 acc2[4];
#pragma unroll
        for (int rg = 0; rg < 4; ++rg) acc2[rg] = (f32x4){0.f, 0.f, 0.f, 0.f};

        for (int kk = 0; kk < K2 / 32; ++kk) {
            bf16x8 a[4];
#pragma unroll
            for (int rg = 0; rg < 4; ++rg)
                a[rg] = *reinterpret_cast<const bf16x8*>(&hs[rg * 16 + lm][kk * 32 + lk]);
            const bf16x8 b = *reinterpret_cast<const bf16x8*>(
                &w2t[(size_t)(wc2 + lm) * K2 + kk * 32 + lk]);
#pragma unroll
            for (int rg = 0; rg < 4; ++rg)
                acc2[rg] = __builtin_amdgcn_mfma_f32_16x16x32_bf16(a[rg], b, acc2[rg], 0, 0, 0);
        }

        const int col = wc2 + lm;
#pragma unroll
        for (int rg = 0; rg < 4; ++rg) {
#pragma unroll
            for (int reg = 0; reg < 4; ++reg) {
                int r = rg * 16 + hi * 4 + reg;
                if (r >= nrow) continue;
                int g = row0 + r;
                float v = acc2[rg][reg];
                if (col < NCLS)                 out[(size_t)g * NCLS + col] = v + b2[col];
                else if (col >= 48 && col < 95) z2b[(size_t)g * 48 + (col - 48)] = (__bf16)v;
                else if (col == 95)             z2b[(size_t)g * 48 + 47] = (__bf16)0.f;
            }
        }
    }
}

// ====== pull aggregation, layer 2: bf16 gather of z2b, mean + add ============
__global__ __launch_bounds__(256) void agg2_bf(
    const int* __restrict__ row_ptr, const uint16_t* __restrict__ csr_src,
    const __bf16* __restrict__ z2b, const float* __restrict__ invdeg,
    float* __restrict__ out)
{
    int gid  = blockIdx.x * 256 + threadIdx.x;
    int node = gid >> 4;
    int j    = gid & 15;
    if (node >= N_NODES || j >= 12) return;
    int beg = row_ptr[node], end = row_ptr[node + 1];
    f32x4 acc = {0.f, 0.f, 0.f, 0.f};
    int e = beg;
    for (; e + 1 < end; e += 2) {
        int s0 = csr_src[e], s1 = csr_src[e + 1];
        bf16x4 v0 = *reinterpret_cast<const bf16x4*>(z2b + (size_t)s0 * 48 + j * 4);
        bf16x4 v1 = *reinterpret_cast<const bf16x4*>(z2b + (size_t)s1 * 48 + j * 4);
#pragma unroll
        for (int q = 0; q < 4; ++q) acc[q] += (float)v0[q] + (float)v1[q];
    }
    if (e < end) {
        bf16x4 v = *reinterpret_cast<const bf16x4*>(z2b + (size_t)csr_src[e] * 48 + j * 4);
#pragma unroll
        for (int q = 0; q < 4; ++q) acc[q] += (float)v[q];
    }
    float inv = invdeg[node];
#pragma unroll
    for (int q = 0; q < 4; ++q) {
        int col = j * 4 + q;
        if (col < NCLS)
            out[(size_t)node * NCLS + col] += acc[q] * inv;
    }
}

extern "C" void kernel_launch(void* const* d_in, const int* in_sizes, int n_in,
                              void* d_out, int out_size, void* d_ws, size_t ws_size,
                              hipStream_t stream)
{
    const float* x   = (const float*)d_in[0];
    const int*   src = (const int*)  d_in[1];
    const int*   dst = (const int*)  d_in[2];
    const float* Ws1 = (const float*)d_in[3];
    const float* Wn1 = (const float*)d_in[4];
    const float* b1  = (const float*)d_in[5];
    const float* Ws2 = (const float*)d_in[6];
    const float* Wn2 = (const float*)d_in[7];
    const float* b2  = (const float*)d_in[8];
    float* out = (float*)d_out;

    // ---- workspace layout (float-index units) ----
    int*      wsi     = (int*)d_ws;
    int*      deg     = wsi;               //  50,000
    int*      row_ptr = wsi + 50000;       //  50,001
    int*      cursor  = wsi + 100008;      //  50,000
    uint16_t* csr_src = (uint16_t*)(wsi + 150016);  // 800,000 u16 (= 400,000 int slots)
    int*      bsum    = wsi + 550016;      //     196
    int*      boff    = wsi + 550528;      //     196
    float*  wsf    = (float*)d_ws;
    float*  invdeg = wsf + 1000000;                  //  50,000 f32
    __bf16* xb     = (__bf16*)(wsf + 1050000);       //  5.0M bf16
    __bf16* accm   = (__bf16*)(wsf + 3550000);       //  5.0M bf16
    uint32_t* mask = (uint32_t*)(wsf + 6050000);     //  400K u32 (1.6MB)
    __bf16* w1t    = (__bf16*)(wsf + 12450000);      // 57,344 bf16
    __bf16* w2t    = (__bf16*)(wsf + 12480000);      // 24,576 bf16
    __bf16* z2b    = (__bf16*)(wsf + 12500000);      //  2.4M bf16 (~54.8MB)

    hipMemsetAsync(deg, 0, (size_t)50000 * sizeof(int), stream);

    make_mask  <<<(MASK_WORDS + 255) / 256, 256, 0, stream>>>(mask);
    count_deg  <<<(N_EDGES + 255) / 256, 256, 0, stream>>>(dst, deg);
    scan_phaseA<<<SCAN_NB, 256, 0, stream>>>(deg, bsum);
    scan_phaseB<<<1, 256, 0, stream>>>(bsum, boff);
    scan_phaseC<<<SCAN_NB, 256, 0, stream>>>(deg, boff, row_ptr, cursor, invdeg);
    fill_csr   <<<(N_EDGES + 255) / 256, 256, 0, stream>>>(src, dst, cursor, csr_src);

    x_to_bf16<<<(N_NODES * IN_F / 4 + 255) / 256, 256, 0, stream>>>(x, xb);
    build_w1t<<<(HID * K1 + 255) / 256, 256, 0, stream>>>(Ws1, Wn1, w1t);
    build_w2t<<<(96 * K2 + 255) / 256, 256, 0, stream>>>(Ws2, Wn2, w2t);

    agg1_bf<<<(N_NODES * 32 + 255) / 256, 256, 0, stream>>>(row_ptr, csr_src, xb, invdeg, accm);
    gemm12_fused<<<(N_NODES + 63) / 64, 512, 0, stream>>>(
        xb, accm, w1t, b1, mask, w2t, b2, out, z2b);
    agg2_bf<<<(N_NODES * 16 + 255) / 256, 256, 0, stream>>>(row_ptr, csr_src, z2b, invdeg, out);
}

// Round 12
// 225.434 us; speedup vs baseline: 3.6775x; 1.0108x over previous
//
#include <hip/hip_runtime.h>
#include <stdint.h>

#define N_NODES 50000
#define N_EDGES 800000
#define IN_F    100
#define HID     256
#define NCLS    47
#define K1      224   // 200 padded to 7*32
#define K1S     232   // LDS row stride (bank-spread)
#define K2      256
#define K2S     264
#define SCAN_NB ((N_NODES + 255) / 256)
#define MASK_WORDS (N_NODES * (HID / 32))   // 400,000

typedef __bf16 bf16x8 __attribute__((ext_vector_type(8)));
typedef __bf16 bf16x4 __attribute__((ext_vector_type(4)));
typedef float  f32x4  __attribute__((ext_vector_type(4)));

__device__ __forceinline__ uint32_t rotl32(uint32_t v, uint32_t r) {
    return (v << r) | (v >> (32u - r));
}

// JAX threefry2x32, key=(0,42), partitionable: counter=(0,i), bits=x0^x1.
// bernoulli(0.5) keeps iff MSB==0.  (verified round 2)
__device__ __forceinline__ uint32_t jax_bits(uint32_t i) {
    const uint32_t ks0 = 0u, ks1 = 42u, ks2 = 0x1BD11BDAu ^ 42u;
    uint32_t x0 = 0u + ks0;
    uint32_t x1 = i + ks1;
    x0 += x1; x1 = rotl32(x1, 13); x1 ^= x0;
    x0 += x1; x1 = rotl32(x1, 15); x1 ^= x0;
    x0 += x1; x1 = rotl32(x1, 26); x1 ^= x0;
    x0 += x1; x1 = rotl32(x1,  6); x1 ^= x0;
    x0 += ks1; x1 += ks2 + 1u;
    x0 += x1; x1 = rotl32(x1, 17); x1 ^= x0;
    x0 += x1; x1 = rotl32(x1, 29); x1 ^= x0;
    x0 += x1; x1 = rotl32(x1, 16); x1 ^= x0;
    x0 += x1; x1 = rotl32(x1, 24); x1 ^= x0;
    x0 += ks2; x1 += ks0 + 2u;
    x0 += x1; x1 = rotl32(x1, 13); x1 ^= x0;
    x0 += x1; x1 = rotl32(x1, 15); x1 ^= x0;
    x0 += x1; x1 = rotl32(x1, 26); x1 ^= x0;
    x0 += x1; x1 = rotl32(x1,  6); x1 ^= x0;
    x0 += ks0; x1 += ks1 + 3u;
    x0 += x1; x1 = rotl32(x1, 17); x1 ^= x0;
    x0 += x1; x1 = rotl32(x1, 29); x1 ^= x0;
    x0 += x1; x1 = rotl32(x1, 16); x1 ^= x0;
    x0 += x1; x1 = rotl32(x1, 24); x1 ^= x0;
    x0 += ks1; x1 += ks2 + 4u;
    x0 += x1; x1 = rotl32(x1, 13); x1 ^= x0;
    x0 += x1; x1 = rotl32(x1, 15); x1 ^= x0;
    x0 += x1; x1 = rotl32(x1, 26); x1 ^= x0;
    x0 += x1; x1 = rotl32(x1,  6); x1 ^= x0;
    x0 += ks2; x1 += ks0 + 5u;
    return x0 ^ x1;
}

// ---------------- zero deg (replaces pathological hipMemsetAsync) ------------
__global__ __launch_bounds__(256) void zero_deg(int* __restrict__ deg)
{
    int i = blockIdx.x * 256 + threadIdx.x;
    if (i < N_NODES) deg[i] = 0;
}

// ---------------- dropout mask: 1 bit per h1 element (keep=1) ----------------
__global__ __launch_bounds__(256) void make_mask(uint32_t* __restrict__ mask)
{
    int w = blockIdx.x * 256 + threadIdx.x;
    if (w >= MASK_WORDS) return;
    uint32_t base = (uint32_t)w * 32u;
    uint32_t m = 0u;
#pragma unroll
    for (int j = 0; j < 32; ++j) {
        uint32_t bits = jax_bits(base + (uint32_t)j);
        m |= ((~bits) >> 31) << j;   // keep iff MSB==0
    }
    mask[w] = m;
}

// ======================= CSR build (dst -> srcs) =============================
__global__ __launch_bounds__(256) void count_deg(
    const int* __restrict__ dst, int* __restrict__ deg)
{
    int e = blockIdx.x * 256 + threadIdx.x;
    if (e < N_EDGES) atomicAdd(&deg[dst[e]], 1);
}

__global__ __launch_bounds__(256) void scan_phaseA(
    const int* __restrict__ deg, int* __restrict__ bsum)
{
    __shared__ int red[256];
    int i = blockIdx.x * 256 + threadIdx.x;
    int v = (i < N_NODES) ? deg[i] : 0;
    red[threadIdx.x] = v;
    __syncthreads();
    for (int off = 128; off > 0; off >>= 1) {
        if (threadIdx.x < off) red[threadIdx.x] += red[threadIdx.x + off];
        __syncthreads();
    }
    if (threadIdx.x == 0) bsum[blockIdx.x] = red[0];
}

__global__ __launch_bounds__(256) void scan_phaseB(
    const int* __restrict__ bsum, int* __restrict__ boff)
{
    __shared__ int s[256];
    int tid = threadIdx.x;
    int v = (tid < SCAN_NB) ? bsum[tid] : 0;
    s[tid] = v;
    __syncthreads();
    for (int off = 1; off < 256; off <<= 1) {
        int t = (tid >= off) ? s[tid - off] : 0;
        __syncthreads();
        s[tid] += t;
        __syncthreads();
    }
    if (tid < SCAN_NB) boff[tid] = s[tid] - v;
}

__global__ __launch_bounds__(256) void scan_phaseC(
    const int* __restrict__ deg, const int* __restrict__ boff,
    int* __restrict__ row_ptr, int* __restrict__ cursor,
    float* __restrict__ invdeg)
{
    __shared__ int s[256];
    int tid = threadIdx.x;
    int i = blockIdx.x * 256 + tid;
    int d = (i < N_NODES) ? deg[i] : 0;
    s[tid] = d;
    __syncthreads();
    for (int off = 1; off < 256; off <<= 1) {
        int t = (tid >= off) ? s[tid - off] : 0;
        __syncthreads();
        s[tid] += t;
        __syncthreads();
    }
    int excl = boff[blockIdx.x] + s[tid] - d;
    if (i < N_NODES) {
        row_ptr[i] = excl;
        cursor[i]  = excl;
        invdeg[i]  = 1.0f / fmaxf((float)d, 1.0f);
        if (i == N_NODES - 1) row_ptr[N_NODES] = excl + d;
    }
}

// CSR adjacency stored as uint16 (src < 50000 < 65536)
__global__ __launch_bounds__(256) void fill_csr(
    const int* __restrict__ src, const int* __restrict__ dst,
    int* __restrict__ cursor, uint16_t* __restrict__ csr_src)
{
    int e = blockIdx.x * 256 + threadIdx.x;
    if (e >= N_EDGES) return;
    int pos = atomicAdd(&cursor[dst[e]], 1);
    csr_src[pos] = (uint16_t)src[e];
}

// ---------------- convert x to bf16 (4 elems/thread) -------------------------
__global__ __launch_bounds__(256) void x_to_bf16(
    const float* __restrict__ x, __bf16* __restrict__ xb)
{
    int i = blockIdx.x * 256 + threadIdx.x;
    if (i * 4 >= N_NODES * IN_F) return;
    float4 v = reinterpret_cast<const float4*>(x)[i];
    bf16x4 b;
    b[0] = (__bf16)v.x; b[1] = (__bf16)v.y;
    b[2] = (__bf16)v.z; b[3] = (__bf16)v.w;
    *reinterpret_cast<bf16x4*>(xb + i * 4) = b;
}

// ====== pull aggregation, layer 1: bf16 gather, MEAN -> accm_bf16 ============
__global__ __launch_bounds__(256) void agg1_bf(
    const int* __restrict__ row_ptr, const uint16_t* __restrict__ csr_src,
    const __bf16* __restrict__ xb, const float* __restrict__ invdeg,
    __bf16* __restrict__ accm)
{
    int gid  = blockIdx.x * 256 + threadIdx.x;
    int node = gid >> 5;
    int j    = gid & 31;
    if (node >= N_NODES || j >= 25) return;
    int beg = row_ptr[node], end = row_ptr[node + 1];
    f32x4 acc = {0.f, 0.f, 0.f, 0.f};
    int e = beg;
    for (; e + 1 < end; e += 2) {
        int s0 = csr_src[e], s1 = csr_src[e + 1];
        bf16x4 v0 = *reinterpret_cast<const bf16x4*>(xb + (size_t)s0 * IN_F + j * 4);
        bf16x4 v1 = *reinterpret_cast<const bf16x4*>(xb + (size_t)s1 * IN_F + j * 4);
#pragma unroll
        for (int q = 0; q < 4; ++q) acc[q] += (float)v0[q] + (float)v1[q];
    }
    if (e < end) {
        bf16x4 v = *reinterpret_cast<const bf16x4*>(xb + (size_t)csr_src[e] * IN_F + j * 4);
#pragma unroll
        for (int q = 0; q < 4; ++q) acc[q] += (float)v[q];
    }
    float inv = invdeg[node];
    bf16x4 r;
#pragma unroll
    for (int q = 0; q < 4; ++q) r[q] = (__bf16)(acc[q] * inv);
    *reinterpret_cast<bf16x4*>(accm + (size_t)node * IN_F + j * 4) = r;
}

// ---------- weight prep: W1^T bf16 [256][224]  (k<100:self, <200:neigh) -----
__global__ __launch_bounds__(256) void build_w1t(
    const float* __restrict__ Ws1, const float* __restrict__ Wn1,
    __bf16* __restrict__ w1t)
{
    int gid = blockIdx.x * 256 + threadIdx.x;
    if (gid >= HID * K1) return;
    int j = gid / K1, k = gid % K1;
    float v = 0.f;
    if (k < IN_F)            v = Ws1[k * HID + j];
    else if (k < 2 * IN_F)   v = Wn1[(k - IN_F) * HID + j];
    w1t[gid] = (__bf16)v;
}

// ---------- weight prep: W2^T bf16 [96][256] (j<47:self, 48..94:neigh) ------
__global__ __launch_bounds__(256) void build_w2t(
    const float* __restrict__ Ws2, const float* __restrict__ Wn2,
    __bf16* __restrict__ w2t)
{
    int gid = blockIdx.x * 256 + threadIdx.x;
    if (gid >= 96 * K2) return;
    int j = gid / K2, k = gid % K2;
    float v = 0.f;
    if (j < NCLS)                 v = Ws2[k * NCLS + j];
    else if (j >= 48 && j < 95)   v = Wn2[k * NCLS + (j - 48)];
    w2t[gid] = (__bf16)v;
}

// ====== FUSED layer-1 + layer-2 MFMA: weight-amortized, 64 rows/block ========
// 512 threads = 8 waves.
// phase1: wave w = 64 rows x 32 cols (cols w*32..w*32+31), acc[2ct][4rg]
// phase2: waves 0..5 = 64 rows x 16 cols (cols w*16..w*16+15), acc2[4rg]
__global__ __launch_bounds__(512) void gemm12_fused(
    const __bf16* __restrict__ xb, const __bf16* __restrict__ accm,
    const __bf16* __restrict__ w1t, const float* __restrict__ b1,
    const uint32_t* __restrict__ mask,
    const __bf16* __restrict__ w2t, const float* __restrict__ b2,
    float* __restrict__ out, __bf16* __restrict__ z2b)
{
    __shared__ __bf16 xs[64][K1S];     // 29.0 KB
    __shared__ __bf16 hs[64][K2S];     // 33.0 KB
    __shared__ uint32_t msk[64][8];    //  2.0 KB   (total 64 KB -> 2 blocks/CU)
    const int row0 = blockIdx.x * 64;
    const int tid  = threadIdx.x;
    const int nrow = min(64, N_NODES - row0);

    // ---- stage (x || mean) bf16 (zero-pad k in [200,224)) + mask words ----
    for (int t = tid; t < 64 * (K1 / 4); t += 512) {
        int r = t / (K1 / 4), c4 = t % (K1 / 4);
        bf16x4 v = {};
        if (r < nrow) {
            if (c4 < 25)
                v = *reinterpret_cast<const bf16x4*>(xb + (size_t)(row0 + r) * IN_F + c4 * 4);
            else if (c4 < 50)
                v = *reinterpret_cast<const bf16x4*>(accm + (size_t)(row0 + r) * IN_F + (c4 - 25) * 4);
        }
        *reinterpret_cast<bf16x4*>(&xs[r][c4 * 4]) = v;
    }
    {
        int r = tid >> 3, w8 = tid & 7;
        msk[r][w8] = (r < nrow) ? mask[(size_t)(row0 + r) * 8 + w8] : 0u;
    }
    __syncthreads();

    const int w    = tid >> 6;          // wave 0..7
    const int lane = tid & 63;
    const int lm   = lane & 15;
    const int hi   = lane >> 4;         // 0..3
    const int lk   = hi * 8;

    // ---- phase 1: h1 = (x||mean) @ W1^T ; wave cols = w*32 + ct*16 + lm ----
    const int wc = w * 32;
    f32x4 acc[2][4];
#pragma unroll
    for (int ct = 0; ct < 2; ++ct)
#pragma unroll
        for (int rg = 0; rg < 4; ++rg) acc[ct][rg] = (f32x4){0.f, 0.f, 0.f, 0.f};

    for (int kk = 0; kk < K1 / 32; ++kk) {
        bf16x8 a[4];
#pragma unroll
        for (int rg = 0; rg < 4; ++rg)
            a[rg] = *reinterpret_cast<const bf16x8*>(&xs[rg * 16 + lm][kk * 32 + lk]);
#pragma unroll
        for (int ct = 0; ct < 2; ++ct) {
            const bf16x8 b = *reinterpret_cast<const bf16x8*>(
                &w1t[(size_t)(wc + ct * 16 + lm) * K1 + kk * 32 + lk]);
#pragma unroll
            for (int rg = 0; rg < 4; ++rg)
                acc[ct][rg] = __builtin_amdgcn_mfma_f32_16x16x32_bf16(a[rg], b, acc[ct][rg], 0, 0, 0);
        }
    }

    // epilogue 1: bias + ReLU + dropout -> hs (LDS); all rows/cols written
#pragma unroll
    for (int ct = 0; ct < 2; ++ct) {
        const int col = wc + ct * 16 + lm;
        const float bj = b1[col];
        const int bit = ct * 16 + lm;
#pragma unroll
        for (int rg = 0; rg < 4; ++rg) {
#pragma unroll
            for (int reg = 0; reg < 4; ++reg) {
                int r = rg * 16 + hi * 4 + reg;
                float v = 0.f;
                if (r < nrow) {
                    v = fmaxf(acc[ct][rg][reg] + bj, 0.f);
                    v = ((msk[r][w] >> bit) & 1u) ? v * 2.0f : 0.f;
                }
                hs[r][col] = (__bf16)v;
            }
        }
    }
    __syncthreads();

    // ---- phase 2: [out_self | z2] = h1 @ W2^T ; waves 0..5, 16 cols each ----
    if (w < 6) {
        const int wc2 = w * 16;
        f32x4 acc2[4];
#pragma unroll
        for (int rg = 0; rg < 4; ++rg) acc2[rg] = (f32x4){0.f, 0.f, 0.f, 0.f};

        for (int kk = 0; kk < K2 / 32; ++kk) {
            bf16x8 a[4];
#pragma unroll
            for (int rg = 0; rg < 4; ++rg)
                a[rg] = *reinterpret_cast<const bf16x8*>(&hs[rg * 16 + lm][kk * 32 + lk]);
            const bf16x8 b = *reinterpret_cast<const bf16x8*>(
                &w2t[(size_t)(wc2 + lm) * K2 + kk * 32 + lk]);
#pragma unroll
            for (int rg = 0; rg < 4; ++rg)
                acc2[rg] = __builtin_amdgcn_mfma_f32_16x16x32_bf16(a[rg], b, acc2[rg], 0, 0, 0);
        }

        const int col = wc2 + lm;
#pragma unroll
        for (int rg = 0; rg < 4; ++rg) {
#pragma unroll
            for (int reg = 0; reg < 4; ++reg) {
                int r = rg * 16 + hi * 4 + reg;
                if (r >= nrow) continue;
                int g = row0 + r;
                float v = acc2[rg][reg];
                if (col < NCLS)                 out[(size_t)g * NCLS + col] = v + b2[col];
                else if (col >= 48 && col < 95) z2b[(size_t)g * 48 + (col - 48)] = (__bf16)v;
                else if (col == 95)             z2b[(size_t)g * 48 + 47] = (__bf16)0.f;
            }
        }
    }
}

// ====== pull aggregation, layer 2: bf16 gather of z2b, mean + add ============
__global__ __launch_bounds__(256) void agg2_bf(
    const int* __restrict__ row_ptr, const uint16_t* __restrict__ csr_src,
    const __bf16* __restrict__ z2b, const float* __restrict__ invdeg,
    float* __restrict__ out)
{
    int gid  = blockIdx.x * 256 + threadIdx.x;
    int node = gid >> 4;
    int j    = gid & 15;
    if (node >= N_NODES || j >= 12) return;
    int beg = row_ptr[node], end = row_ptr[node + 1];
    f32x4 acc = {0.f, 0.f, 0.f, 0.f};
    int e = beg;
    for (; e + 1 < end; e += 2) {
        int s0 = csr_src[e], s1 = csr_src[e + 1];
        bf16x4 v0 = *reinterpret_cast<const bf16x4*>(z2b + (size_t)s0 * 48 + j * 4);
        bf16x4 v1 = *reinterpret_cast<const bf16x4*>(z2b + (size_t)s1 * 48 + j * 4);
#pragma unroll
        for (int q = 0; q < 4; ++q) acc[q] += (float)v0[q] + (float)v1[q];
    }
    if (e < end) {
        bf16x4 v = *reinterpret_cast<const bf16x4*>(z2b + (size_t)csr_src[e] * 48 + j * 4);
#pragma unroll
        for (int q = 0; q < 4; ++q) acc[q] += (float)v[q];
    }
    float inv = invdeg[node];
#pragma unroll
    for (int q = 0; q < 4; ++q) {
        int col = j * 4 + q;
        if (col < NCLS)
            out[(size_t)node * NCLS + col] += acc[q] * inv;
    }
}

extern "C" void kernel_launch(void* const* d_in, const int* in_sizes, int n_in,
                              void* d_out, int out_size, void* d_ws, size_t ws_size,
                              hipStream_t stream)
{
    const float* x   = (const float*)d_in[0];
    const int*   src = (const int*)  d_in[1];
    const int*   dst = (const int*)  d_in[2];
    const float* Ws1 = (const float*)d_in[3];
    const float* Wn1 = (const float*)d_in[4];
    const float* b1  = (const float*)d_in[5];
    const float* Ws2 = (const float*)d_in[6];
    const float* Wn2 = (const float*)d_in[7];
    const float* b2  = (const float*)d_in[8];
    float* out = (float*)d_out;

    // ---- workspace layout (float-index units) ----
    int*      wsi     = (int*)d_ws;
    int*      deg     = wsi;               //  50,000
    int*      row_ptr = wsi + 50000;       //  50,001
    int*      cursor  = wsi + 100008;      //  50,000
    uint16_t* csr_src = (uint16_t*)(wsi + 150016);  // 800,000 u16
    int*      bsum    = wsi + 550016;      //     196
    int*      boff    = wsi + 550528;      //     196
    float*  wsf    = (float*)d_ws;
    float*  invdeg = wsf + 1000000;                  //  50,000 f32
    __bf16* xb     = (__bf16*)(wsf + 1050000);       //  5.0M bf16
    __bf16* accm   = (__bf16*)(wsf + 3550000);       //  5.0M bf16
    uint32_t* mask = (uint32_t*)(wsf + 6050000);     //  400K u32 (1.6MB)
    __bf16* w1t    = (__bf16*)(wsf + 12450000);      // 57,344 bf16
    __bf16* w2t    = (__bf16*)(wsf + 12480000);      // 24,576 bf16
    __bf16* z2b    = (__bf16*)(wsf + 12500000);      //  2.4M bf16 (~54.8MB)

    zero_deg   <<<SCAN_NB, 256, 0, stream>>>(deg);   // replaces 42us hipMemsetAsync
    count_deg  <<<(N_EDGES + 255) / 256, 256, 0, stream>>>(dst, deg);
    scan_phaseA<<<SCAN_NB, 256, 0, stream>>>(deg, bsum);
    scan_phaseB<<<1, 256, 0, stream>>>(bsum, boff);
    scan_phaseC<<<SCAN_NB, 256, 0, stream>>>(deg, boff, row_ptr, cursor, invdeg);
    fill_csr   <<<(N_EDGES + 255) / 256, 256, 0, stream>>>(src, dst, cursor, csr_src);

    make_mask<<<(MASK_WORDS + 255) / 256, 256, 0, stream>>>(mask);
    x_to_bf16<<<(N_NODES * IN_F / 4 + 255) / 256, 256, 0, stream>>>(x, xb);
    build_w1t<<<(HID * K1 + 255) / 256, 256, 0, stream>>>(Ws1, Wn1, w1t);
    build_w2t<<<(96 * K2 + 255) / 256, 256, 0, stream>>>(Ws2, Wn2, w2t);

    agg1_bf<<<(N_NODES * 32 + 255) / 256, 256, 0, stream>>>(row_ptr, csr_src, xb, invdeg, accm);
    gemm12_fused<<<(N_NODES + 63) / 64, 512, 0, stream>>>(
        xb, accm, w1t, b1, mask, w2t, b2, out, z2b);
    agg2_bf<<<(N_NODES * 16 + 255) / 256, 256, 0, stream>>>(row_ptr, csr_src, z2b, invdeg, out);
}

// Round 13
// 175.883 us; speedup vs baseline: 4.7136x; 1.2817x over previous
//
#include <hip/hip_runtime.h>
#include <stdint.h>

#define N_NODES 50000
#define N_EDGES 800000
#define IN_F    100
#define HID     256
#define NCLS    47
#define K1      224   // 200 padded to 7*32
#define K1S     232   // LDS row stride (bank-spread)
#define K2      256
#define K2S     264
#define NBKT    196   // ceil(50000/256) buckets of 256 dst nodes
#define MASK_WORDS (N_NODES * (HID / 32))   // 400,000

typedef __bf16 bf16x8 __attribute__((ext_vector_type(8)));
typedef __bf16 bf16x4 __attribute__((ext_vector_type(4)));
typedef float  f32x4  __attribute__((ext_vector_type(4)));

__device__ __forceinline__ uint32_t rotl32(uint32_t v, uint32_t r) {
    return (v << r) | (v >> (32u - r));
}

// JAX threefry2x32, key=(0,42), partitionable: counter=(0,i), bits=x0^x1.
// bernoulli(0.5) keeps iff MSB==0.  (verified round 2)
__device__ __forceinline__ uint32_t jax_bits(uint32_t i) {
    const uint32_t ks0 = 0u, ks1 = 42u, ks2 = 0x1BD11BDAu ^ 42u;
    uint32_t x0 = 0u + ks0;
    uint32_t x1 = i + ks1;
    x0 += x1; x1 = rotl32(x1, 13); x1 ^= x0;
    x0 += x1; x1 = rotl32(x1, 15); x1 ^= x0;
    x0 += x1; x1 = rotl32(x1, 26); x1 ^= x0;
    x0 += x1; x1 = rotl32(x1,  6); x1 ^= x0;
    x0 += ks1; x1 += ks2 + 1u;
    x0 += x1; x1 = rotl32(x1, 17); x1 ^= x0;
    x0 += x1; x1 = rotl32(x1, 29); x1 ^= x0;
    x0 += x1; x1 = rotl32(x1, 16); x1 ^= x0;
    x0 += x1; x1 = rotl32(x1, 24); x1 ^= x0;
    x0 += ks2; x1 += ks0 + 2u;
    x0 += x1; x1 = rotl32(x1, 13); x1 ^= x0;
    x0 += x1; x1 = rotl32(x1, 15); x1 ^= x0;
    x0 += x1; x1 = rotl32(x1, 26); x1 ^= x0;
    x0 += x1; x1 = rotl32(x1,  6); x1 ^= x0;
    x0 += ks0; x1 += ks1 + 3u;
    x0 += x1; x1 = rotl32(x1, 17); x1 ^= x0;
    x0 += x1; x1 = rotl32(x1, 29); x1 ^= x0;
    x0 += x1; x1 = rotl32(x1, 16); x1 ^= x0;
    x0 += x1; x1 = rotl32(x1, 24); x1 ^= x0;
    x0 += ks1; x1 += ks2 + 4u;
    x0 += x1; x1 = rotl32(x1, 13); x1 ^= x0;
    x0 += x1; x1 = rotl32(x1, 15); x1 ^= x0;
    x0 += x1; x1 = rotl32(x1, 26); x1 ^= x0;
    x0 += x1; x1 = rotl32(x1,  6); x1 ^= x0;
    x0 += ks2; x1 += ks0 + 5u;
    return x0 ^ x1;
}

// ---------------- dropout mask: 1 bit per h1 element (keep=1) ----------------
__global__ __launch_bounds__(256) void make_mask(uint32_t* __restrict__ mask)
{
    int w = blockIdx.x * 256 + threadIdx.x;
    if (w >= MASK_WORDS) return;
    uint32_t base = (uint32_t)w * 32u;
    uint32_t m = 0u;
#pragma unroll
    for (int j = 0; j < 32; ++j) {
        uint32_t bits = jax_bits(base + (uint32_t)j);
        m |= ((~bits) >> 31) << j;   // keep iff MSB==0
    }
    mask[w] = m;
}

// ============ locality-partitioned CSR build (dst -> srcs) ===================
__global__ __launch_bounds__(256) void zero_cnt(int* __restrict__ gcnt)
{
    if (threadIdx.x < NBKT) gcnt[threadIdx.x] = 0;
}

// pass A: 196-bucket histogram of dst (bucket = dst>>8), LDS-staged
__global__ __launch_bounds__(256) void bkt_hist(
    const int* __restrict__ dst, int* __restrict__ gcnt)
{
    __shared__ int lcnt[NBKT];
    for (int t = threadIdx.x; t < NBKT; t += 256) lcnt[t] = 0;
    __syncthreads();
    int base = blockIdx.x * 4096;
    for (int it = 0; it < 16; ++it) {
        int e = base + it * 256 + threadIdx.x;
        if (e < N_EDGES) atomicAdd(&lcnt[dst[e] >> 8], 1);
    }
    __syncthreads();
    for (int t = threadIdx.x; t < NBKT; t += 256)
        if (lcnt[t]) atomicAdd(&gcnt[t], lcnt[t]);
}

// pass B: exclusive scan of bucket counts -> gbase[NBKT+1]; gcur = gbase
__global__ __launch_bounds__(256) void bkt_scan(
    const int* __restrict__ gcnt, int* __restrict__ gbase, int* __restrict__ gcur)
{
    __shared__ int s[256];
    int tid = threadIdx.x;
    int v = (tid < NBKT) ? gcnt[tid] : 0;
    s[tid] = v;
    __syncthreads();
    for (int off = 1; off < 256; off <<= 1) {
        int t = (tid >= off) ? s[tid - off] : 0;
        __syncthreads();
        s[tid] += t;
        __syncthreads();
    }
    if (tid < NBKT) { int ex = s[tid] - v; gbase[tid] = ex; gcur[tid] = ex; }
    if (tid == NBKT - 1) gbase[NBKT] = s[tid];
}

// pass C: block-local multisplit of edges into bucket regions.
// packed u32 = (dst<<16)|src (both < 65536). LDS-partitioned then flushed as
// contiguous runs -> each output line written (mostly) by one block/XCD.
__global__ __launch_bounds__(256) void bkt_bin(
    const int* __restrict__ src, const int* __restrict__ dst,
    int* __restrict__ gcur, uint32_t* __restrict__ ebin)
{
    __shared__ uint32_t ldata[4096];
    __shared__ uint8_t  lbkt[4096];
    __shared__ int lcnt[NBKT], lofs[NBKT], lcur[NBKT], gb[NBKT];
    __shared__ int lscan[256];
    const int tid  = threadIdx.x;
    const int base = blockIdx.x * 4096;

    for (int t = tid; t < NBKT; t += 256) lcnt[t] = 0;
    __syncthreads();

    uint32_t pk[16];
    int bk[16];
    for (int it = 0; it < 16; ++it) {
        int e = base + it * 256 + tid;
        if (e < N_EDGES) {
            int d = dst[e];
            pk[it] = ((uint32_t)d << 16) | (uint32_t)src[e];
            bk[it] = d >> 8;
            atomicAdd(&lcnt[bk[it]], 1);
        } else bk[it] = -1;
    }
    __syncthreads();

    // scan the 196 counters (256-thread Hillis-Steele)
    int v = (tid < NBKT) ? lcnt[tid] : 0;
    lscan[tid] = v;
    __syncthreads();
    for (int off = 1; off < 256; off <<= 1) {
        int t = (tid >= off) ? lscan[tid - off] : 0;
        __syncthreads();
        lscan[tid] += t;
        __syncthreads();
    }
    if (tid < NBKT) {
        lofs[tid] = lscan[tid] - v;
        lcur[tid] = 0;
        gb[tid]   = (v > 0) ? atomicAdd(&gcur[tid], v) : 0;
    }
    __syncthreads();

    // place into LDS, partitioned by bucket
    for (int it = 0; it < 16; ++it) {
        if (bk[it] >= 0) {
            int p = lofs[bk[it]] + atomicAdd(&lcur[bk[it]], 1);
            ldata[p] = pk[it];
            lbkt[p]  = (uint8_t)bk[it];
        }
    }
    __syncthreads();

    // flush: consecutive LDS entries of a bucket -> consecutive global addrs
    const int n = min(4096, N_EDGES - base);
    for (int i = tid; i < n; i += 256) {
        int b = lbkt[i];
        ebin[gb[b] + (i - lofs[b])] = ldata[i];
    }
}

// pass D: one block per bucket: per-node degree+scan -> row_ptr/invdeg/cursor,
// then scatter u16 src within the bucket's own csr window (single-XCD writes)
__global__ __launch_bounds__(256) void bkt_build(
    const int* __restrict__ gbase, const uint32_t* __restrict__ ebin,
    int* __restrict__ row_ptr, float* __restrict__ invdeg,
    uint16_t* __restrict__ csr_src)
{
    __shared__ int ldeg[256], lscan[256], lcur[256];
    const int b = blockIdx.x, tid = threadIdx.x;
    const int beg = gbase[b], end = gbase[b + 1], n = end - beg;
    const int node0 = b << 8;
    const int nloc = min(256, N_NODES - node0);

    ldeg[tid] = 0;
    __syncthreads();
    for (int i = tid; i < n; i += 256)
        atomicAdd(&ldeg[(int)(ebin[beg + i] >> 16) - node0], 1);
    __syncthreads();

    int d = ldeg[tid];
    lscan[tid] = d;
    __syncthreads();
    for (int off = 1; off < 256; off <<= 1) {
        int t = (tid >= off) ? lscan[tid - off] : 0;
        __syncthreads();
        lscan[tid] += t;
        __syncthreads();
    }
    int excl = lscan[tid] - d;
    lcur[tid] = excl;
    if (tid < nloc) {
        row_ptr[node0 + tid] = beg + excl;
        invdeg[node0 + tid]  = 1.0f / fmaxf((float)d, 1.0f);
    }
    if (b == NBKT - 1 && tid == 0) row_ptr[N_NODES] = end;
    __syncthreads();

    for (int i = tid; i < n; i += 256) {
        uint32_t pk = ebin[beg + i];
        int ld = (int)(pk >> 16) - node0;
        int pos = atomicAdd(&lcur[ld], 1);
        csr_src[beg + pos] = (uint16_t)(pk & 0xFFFFu);
    }
}

// ---------------- convert x to bf16 (4 elems/thread) -------------------------
__global__ __launch_bounds__(256) void x_to_bf16(
    const float* __restrict__ x, __bf16* __restrict__ xb)
{
    int i = blockIdx.x * 256 + threadIdx.x;
    if (i * 4 >= N_NODES * IN_F) return;
    float4 v = reinterpret_cast<const float4*>(x)[i];
    bf16x4 b;
    b[0] = (__bf16)v.x; b[1] = (__bf16)v.y;
    b[2] = (__bf16)v.z; b[3] = (__bf16)v.w;
    *reinterpret_cast<bf16x4*>(xb + i * 4) = b;
}

// ====== pull aggregation, layer 1: bf16 gather, MEAN -> accm_bf16 ============
__global__ __launch_bounds__(256) void agg1_bf(
    const int* __restrict__ row_ptr, const uint16_t* __restrict__ csr_src,
    const __bf16* __restrict__ xb, const float* __restrict__ invdeg,
    __bf16* __restrict__ accm)
{
    int gid  = blockIdx.x * 256 + threadIdx.x;
    int node = gid >> 5;
    int j    = gid & 31;
    if (node >= N_NODES || j >= 25) return;
    int beg = row_ptr[node], end = row_ptr[node + 1];
    f32x4 acc = {0.f, 0.f, 0.f, 0.f};
    int e = beg;
    for (; e + 1 < end; e += 2) {
        int s0 = csr_src[e], s1 = csr_src[e + 1];
        bf16x4 v0 = *reinterpret_cast<const bf16x4*>(xb + (size_t)s0 * IN_F + j * 4);
        bf16x4 v1 = *reinterpret_cast<const bf16x4*>(xb + (size_t)s1 * IN_F + j * 4);
#pragma unroll
        for (int q = 0; q < 4; ++q) acc[q] += (float)v0[q] + (float)v1[q];
    }
    if (e < end) {
        bf16x4 v = *reinterpret_cast<const bf16x4*>(xb + (size_t)csr_src[e] * IN_F + j * 4);
#pragma unroll
        for (int q = 0; q < 4; ++q) acc[q] += (float)v[q];
    }
    float inv = invdeg[node];
    bf16x4 r;
#pragma unroll
    for (int q = 0; q < 4; ++q) r[q] = (__bf16)(acc[q] * inv);
    *reinterpret_cast<bf16x4*>(accm + (size_t)node * IN_F + j * 4) = r;
}

// ---------- weight prep: W1^T bf16 [256][224]  (k<100:self, <200:neigh) -----
__global__ __launch_bounds__(256) void build_w1t(
    const float* __restrict__ Ws1, const float* __restrict__ Wn1,
    __bf16* __restrict__ w1t)
{
    int gid = blockIdx.x * 256 + threadIdx.x;
    if (gid >= HID * K1) return;
    int j = gid / K1, k = gid % K1;
    float v = 0.f;
    if (k < IN_F)            v = Ws1[k * HID + j];
    else if (k < 2 * IN_F)   v = Wn1[(k - IN_F) * HID + j];
    w1t[gid] = (__bf16)v;
}

// ---------- weight prep: W2^T bf16 [96][256] (j<47:self, 48..94:neigh) ------
__global__ __launch_bounds__(256) void build_w2t(
    const float* __restrict__ Ws2, const float* __restrict__ Wn2,
    __bf16* __restrict__ w2t)
{
    int gid = blockIdx.x * 256 + threadIdx.x;
    if (gid >= 96 * K2) return;
    int j = gid / K2, k = gid % K2;
    float v = 0.f;
    if (j < NCLS)                 v = Ws2[k * NCLS + j];
    else if (j >= 48 && j < 95)   v = Wn2[k * NCLS + (j - 48)];
    w2t[gid] = (__bf16)v;
}

// ====== FUSED layer-1 + layer-2 MFMA: weight-amortized, 64 rows/block ========
// 512 threads = 8 waves.
// phase1: wave w = 64 rows x 32 cols (cols w*32..w*32+31), acc[2ct][4rg]
// phase2: waves 0..5 = 64 rows x 16 cols (cols w*16..w*16+15), acc2[4rg]
__global__ __launch_bounds__(512) void gemm12_fused(
    const __bf16* __restrict__ xb, const __bf16* __restrict__ accm,
    const __bf16* __restrict__ w1t, const float* __restrict__ b1,
    const uint32_t* __restrict__ mask,
    const __bf16* __restrict__ w2t, const float* __restrict__ b2,
    float* __restrict__ out, __bf16* __restrict__ z2b)
{
    __shared__ __bf16 xs[64][K1S];     // 29.0 KB
    __shared__ __bf16 hs[64][K2S];     // 33.0 KB
    __shared__ uint32_t msk[64][8];    //  2.0 KB   (total 64 KB -> 2 blocks/CU)
    const int row0 = blockIdx.x * 64;
    const int tid  = threadIdx.x;
    const int nrow = min(64, N_NODES - row0);

    // ---- stage (x || mean) bf16 (zero-pad k in [200,224)) + mask words ----
    for (int t = tid; t < 64 * (K1 / 4); t += 512) {
        int r = t / (K1 / 4), c4 = t % (K1 / 4);
        bf16x4 v = {};
        if (r < nrow) {
            if (c4 < 25)
                v = *reinterpret_cast<const bf16x4*>(xb + (size_t)(row0 + r) * IN_F + c4 * 4);
            else if (c4 < 50)
                v = *reinterpret_cast<const bf16x4*>(accm + (size_t)(row0 + r) * IN_F + (c4 - 25) * 4);
        }
        *reinterpret_cast<bf16x4*>(&xs[r][c4 * 4]) = v;
    }
    {
        int r = tid >> 3, w8 = tid & 7;
        msk[r][w8] = (r < nrow) ? mask[(size_t)(row0 + r) * 8 + w8] : 0u;
    }
    __syncthreads();

    const int w    = tid >> 6;          // wave 0..7
    const int lane = tid & 63;
    const int lm   = lane & 15;
    const int hi   = lane >> 4;         // 0..3
    const int lk   = hi * 8;

    // ---- phase 1: h1 = (x||mean) @ W1^T ; wave cols = w*32 + ct*16 + lm ----
    const int wc = w * 32;
    f32x4 acc[2][4];
#pragma unroll
    for (int ct = 0; ct < 2; ++ct)
#pragma unroll
        for (int rg = 0; rg < 4; ++rg) acc[ct][rg] = (f32x4){0.f, 0.f, 0.f, 0.f};

    for (int kk = 0; kk < K1 / 32; ++kk) {
        bf16x8 a[4];
#pragma unroll
        for (int rg = 0; rg < 4; ++rg)
            a[rg] = *reinterpret_cast<const bf16x8*>(&xs[rg * 16 + lm][kk * 32 + lk]);
#pragma unroll
        for (int ct = 0; ct < 2; ++ct) {
            const bf16x8 b = *reinterpret_cast<const bf16x8*>(
                &w1t[(size_t)(wc + ct * 16 + lm) * K1 + kk * 32 + lk]);
#pragma unroll
            for (int rg = 0; rg < 4; ++rg)
                acc[ct][rg] = __builtin_amdgcn_mfma_f32_16x16x32_bf16(a[rg], b, acc[ct][rg], 0, 0, 0);
        }
    }

    // epilogue 1: bias + ReLU + dropout -> hs (LDS); all rows/cols written
#pragma unroll
    for (int ct = 0; ct < 2; ++ct) {
        const int col = wc + ct * 16 + lm;
        const float bj = b1[col];
        const int bit = ct * 16 + lm;
#pragma unroll
        for (int rg = 0; rg < 4; ++rg) {
#pragma unroll
            for (int reg = 0; reg < 4; ++reg) {
                int r = rg * 16 + hi * 4 + reg;
                float v = 0.f;
                if (r < nrow) {
                    v = fmaxf(acc[ct][rg][reg] + bj, 0.f);
                    v = ((msk[r][w] >> bit) & 1u) ? v * 2.0f : 0.f;
                }
                hs[r][col] = (__bf16)v;
            }
        }
    }
    __syncthreads();

    // ---- phase 2: [out_self | z2] = h1 @ W2^T ; waves 0..5, 16 cols each ----
    if (w < 6) {
        const int wc2 = w * 16;
        f32x4 acc2[4];
#pragma unroll
        for (int rg = 0; rg < 4; ++rg) acc2[rg] = (f32x4){0.f, 0.f, 0.f, 0.f};

        for (int kk = 0; kk < K2 / 32; ++kk) {
            bf16x8 a[4];
#pragma unroll
            for (int rg = 0; rg < 4; ++rg)
                a[rg] = *reinterpret_cast<const bf16x8*>(&hs[rg * 16 + lm][kk * 32 + lk]);
            const bf16x8 b = *reinterpret_cast<const bf16x8*>(
                &w2t[(size_t)(wc2 + lm) * K2 + kk * 32 + lk]);
#pragma unroll
            for (int rg = 0; rg < 4; ++rg)
                acc2[rg] = __builtin_amdgcn_mfma_f32_16x16x32_bf16(a[rg], b, acc2[rg], 0, 0, 0);
        }

        const int col = wc2 + lm;
#pragma unroll
        for (int rg = 0; rg < 4; ++rg) {
#pragma unroll
            for (int reg = 0; reg < 4; ++reg) {
                int r = rg * 16 + hi * 4 + reg;
                if (r >= nrow) continue;
                int g = row0 + r;
                float v = acc2[rg][reg];
                if (col < NCLS)                 out[(size_t)g * NCLS + col] = v + b2[col];
                else if (col >= 48 && col < 95) z2b[(size_t)g * 48 + (col - 48)] = (__bf16)v;
                else if (col == 95)             z2b[(size_t)g * 48 + 47] = (__bf16)0.f;
            }
        }
    }
}

// ====== pull aggregation, layer 2: bf16 gather of z2b, mean + add ============
__global__ __launch_bounds__(256) void agg2_bf(
    const int* __restrict__ row_ptr, const uint16_t* __restrict__ csr_src,
    const __bf16* __restrict__ z2b, const float* __restrict__ invdeg,
    float* __restrict__ out)
{
    int gid  = blockIdx.x * 256 + threadIdx.x;
    int node = gid >> 4;
    int j    = gid & 15;
    if (node >= N_NODES || j >= 12) return;
    int beg = row_ptr[node], end = row_ptr[node + 1];
    f32x4 acc = {0.f, 0.f, 0.f, 0.f};
    int e = beg;
    for (; e + 1 < end; e += 2) {
        int s0 = csr_src[e], s1 = csr_src[e + 1];
        bf16x4 v0 = *reinterpret_cast<const bf16x4*>(z2b + (size_t)s0 * 48 + j * 4);
        bf16x4 v1 = *reinterpret_cast<const bf16x4*>(z2b + (size_t)s1 * 48 + j * 4);
#pragma unroll
        for (int q = 0; q < 4; ++q) acc[q] += (float)v0[q] + (float)v1[q];
    }
    if (e < end) {
        bf16x4 v = *reinterpret_cast<const bf16x4*>(z2b + (size_t)csr_src[e] * 48 + j * 4);
#pragma unroll
        for (int q = 0; q < 4; ++q) acc[q] += (float)v[q];
    }
    float inv = invdeg[node];
#pragma unroll
    for (int q = 0; q < 4; ++q) {
        int col = j * 4 + q;
        if (col < NCLS)
            out[(size_t)node * NCLS + col] += acc[q] * inv;
    }
}

extern "C" void kernel_launch(void* const* d_in, const int* in_sizes, int n_in,
                              void* d_out, int out_size, void* d_ws, size_t ws_size,
                              hipStream_t stream)
{
    const float* x   = (const float*)d_in[0];
    const int*   src = (const int*)  d_in[1];
    const int*   dst = (const int*)  d_in[2];
    const float* Ws1 = (const float*)d_in[3];
    const float* Wn1 = (const float*)d_in[4];
    const float* b1  = (const float*)d_in[5];
    const float* Ws2 = (const float*)d_in[6];
    const float* Wn2 = (const float*)d_in[7];
    const float* b2  = (const float*)d_in[8];
    float* out = (float*)d_out;

    // ---- workspace layout (int-slot / float-slot units) ----
    int*      wsi     = (int*)d_ws;
    int*      row_ptr = wsi;                 //  50,001
    int*      gcnt    = wsi + 50008;         //     196
    int*      gbase   = wsi + 50208;         //     197
    int*      gcur    = wsi + 50408;         //     196
    uint32_t* ebin    = (uint32_t*)(wsi + 50608);    // 800,000 u32
    uint16_t* csr_src = (uint16_t*)(wsi + 850608);   // 800,000 u16
    float*    wsf     = (float*)d_ws;
    float*    invdeg  = wsf + 1300000;               //  50,000 f32
    __bf16*   xb      = (__bf16*)(wsf + 1350000);    //  5.0M bf16
    __bf16*   accm    = (__bf16*)(wsf + 3850000);    //  5.0M bf16
    uint32_t* mask    = (uint32_t*)(wsf + 6350000);  //  400K u32
    __bf16*   w1t     = (__bf16*)(wsf + 6750000);    // 57,344 bf16
    __bf16*   w2t     = (__bf16*)(wsf + 6780000);    // 24,576 bf16
    __bf16*   z2b     = (__bf16*)(wsf + 6800000);    //  2.4M bf16  (~32 MB)

    // --- locality-partitioned CSR build ---
    zero_cnt <<<1, 256, 0, stream>>>(gcnt);
    bkt_hist <<<NBKT, 256, 0, stream>>>(dst, gcnt);
    bkt_scan <<<1, 256, 0, stream>>>(gcnt, gbase, gcur);
    bkt_bin  <<<NBKT, 256, 0, stream>>>(src, dst, gcur, ebin);
    bkt_build<<<NBKT, 256, 0, stream>>>(gbase, ebin, row_ptr, invdeg, csr_src);

    make_mask<<<(MASK_WORDS + 255) / 256, 256, 0, stream>>>(mask);
    x_to_bf16<<<(N_NODES * IN_F / 4 + 255) / 256, 256, 0, stream>>>(x, xb);
    build_w1t<<<(HID * K1 + 255) / 256, 256, 0, stream>>>(Ws1, Wn1, w1t);
    build_w2t<<<(96 * K2 + 255) / 256, 256, 0, stream>>>(Ws2, Wn2, w2t);

    agg1_bf<<<(N_NODES * 32 + 255) / 256, 256, 0, stream>>>(row_ptr, csr_src, xb, invdeg, accm);
    gemm12_fused<<<(N_NODES + 63) / 64, 512, 0, stream>>>(
        xb, accm, w1t, b1, mask, w2t, b2, out, z2b);
    agg2_bf<<<(N_NODES * 16 + 255) / 256, 256, 0, stream>>>(row_ptr, csr_src, z2b, invdeg, out);
}

// Round 14
// 162.074 us; speedup vs baseline: 5.1151x; 1.0852x over previous
//
#include <hip/hip_runtime.h>
#include <stdint.h>

#define N_NODES 50000
#define N_EDGES 800000
#define IN_F    100
#define HID     256
#define NCLS    47
#define K1      224   // 200 padded to 7*32
#define K1S     232   // LDS row stride (bank-spread)
#define K2      256
#define K2S     264
#define NBKT    196   // ceil(50000/256) buckets of 256 dst nodes
#define MASK_WORDS (N_NODES * (HID / 32))   // 400,000

#define MASK_NB ((MASK_WORDS + 255) / 256)            // 1563
#define XCVT_NB ((N_NODES * IN_F / 4 + 255) / 256)    // 4883
#define W1T_NB  ((HID * K1 + 255) / 256)              // 224
#define W2T_NB  ((96 * K2 + 255) / 256)               // 96
#define PREP_NB (MASK_NB + XCVT_NB + W1T_NB + W2T_NB + 1)

typedef __bf16 bf16x8 __attribute__((ext_vector_type(8)));
typedef __bf16 bf16x4 __attribute__((ext_vector_type(4)));
typedef float  f32x4  __attribute__((ext_vector_type(4)));

__device__ __forceinline__ uint32_t rotl32(uint32_t v, uint32_t r) {
    return (v << r) | (v >> (32u - r));
}

// JAX threefry2x32, key=(0,42), partitionable: counter=(0,i), bits=x0^x1.
// bernoulli(0.5) keeps iff MSB==0.  (verified round 2)
__device__ __forceinline__ uint32_t jax_bits(uint32_t i) {
    const uint32_t ks0 = 0u, ks1 = 42u, ks2 = 0x1BD11BDAu ^ 42u;
    uint32_t x0 = 0u + ks0;
    uint32_t x1 = i + ks1;
    x0 += x1; x1 = rotl32(x1, 13); x1 ^= x0;
    x0 += x1; x1 = rotl32(x1, 15); x1 ^= x0;
    x0 += x1; x1 = rotl32(x1, 26); x1 ^= x0;
    x0 += x1; x1 = rotl32(x1,  6); x1 ^= x0;
    x0 += ks1; x1 += ks2 + 1u;
    x0 += x1; x1 = rotl32(x1, 17); x1 ^= x0;
    x0 += x1; x1 = rotl32(x1, 29); x1 ^= x0;
    x0 += x1; x1 = rotl32(x1, 16); x1 ^= x0;
    x0 += x1; x1 = rotl32(x1, 24); x1 ^= x0;
    x0 += ks2; x1 += ks0 + 2u;
    x0 += x1; x1 = rotl32(x1, 13); x1 ^= x0;
    x0 += x1; x1 = rotl32(x1, 15); x1 ^= x0;
    x0 += x1; x1 = rotl32(x1, 26); x1 ^= x0;
    x0 += x1; x1 = rotl32(x1,  6); x1 ^= x0;
    x0 += ks0; x1 += ks1 + 3u;
    x0 += x1; x1 = rotl32(x1, 17); x1 ^= x0;
    x0 += x1; x1 = rotl32(x1, 29); x1 ^= x0;
    x0 += x1; x1 = rotl32(x1, 16); x1 ^= x0;
    x0 += x1; x1 = rotl32(x1, 24); x1 ^= x0;
    x0 += ks1; x1 += ks2 + 4u;
    x0 += x1; x1 = rotl32(x1, 13); x1 ^= x0;
    x0 += x1; x1 = rotl32(x1, 15); x1 ^= x0;
    x0 += x1; x1 = rotl32(x1, 26); x1 ^= x0;
    x0 += x1; x1 = rotl32(x1,  6); x1 ^= x0;
    x0 += ks2; x1 += ks0 + 5u;
    return x0 ^ x1;
}

// ===== merged prep: mask | x->bf16 | W1^T | W2^T | zero gcnt (independent) ===
__global__ __launch_bounds__(256) void prep(
    uint32_t* __restrict__ mask, const float* __restrict__ x,
    __bf16* __restrict__ xb,
    const float* __restrict__ Ws1, const float* __restrict__ Wn1,
    __bf16* __restrict__ w1t,
    const float* __restrict__ Ws2, const float* __restrict__ Wn2,
    __bf16* __restrict__ w2t, int* __restrict__ gcnt)
{
    const int b = blockIdx.x, tid = threadIdx.x;
    if (b < MASK_NB) {
        int w = b * 256 + tid;
        if (w >= MASK_WORDS) return;
        uint32_t base = (uint32_t)w * 32u;
        uint32_t m = 0u;
#pragma unroll
        for (int j = 0; j < 32; ++j) {
            uint32_t bits = jax_bits(base + (uint32_t)j);
            m |= ((~bits) >> 31) << j;
        }
        mask[w] = m;
    } else if (b < MASK_NB + XCVT_NB) {
        int i = (b - MASK_NB) * 256 + tid;
        if (i * 4 >= N_NODES * IN_F) return;
        float4 v = reinterpret_cast<const float4*>(x)[i];
        bf16x4 bb;
        bb[0] = (__bf16)v.x; bb[1] = (__bf16)v.y;
        bb[2] = (__bf16)v.z; bb[3] = (__bf16)v.w;
        *reinterpret_cast<bf16x4*>(xb + i * 4) = bb;
    } else if (b < MASK_NB + XCVT_NB + W1T_NB) {
        int gid = (b - MASK_NB - XCVT_NB) * 256 + tid;
        if (gid >= HID * K1) return;
        int j = gid / K1, k = gid % K1;
        float v = 0.f;
        if (k < IN_F)          v = Ws1[k * HID + j];
        else if (k < 2 * IN_F) v = Wn1[(k - IN_F) * HID + j];
        w1t[gid] = (__bf16)v;
    } else if (b < MASK_NB + XCVT_NB + W1T_NB + W2T_NB) {
        int gid = (b - MASK_NB - XCVT_NB - W1T_NB) * 256 + tid;
        if (gid >= 96 * K2) return;
        int j = gid / K2, k = gid % K2;
        float v = 0.f;
        if (j < NCLS)               v = Ws2[k * NCLS + j];
        else if (j >= 48 && j < 95) v = Wn2[k * NCLS + (j - 48)];
        w2t[gid] = (__bf16)v;
    } else {
        if (tid < NBKT) gcnt[tid] = 0;
    }
}

// ============ locality-partitioned CSR build (dst -> srcs) ===================
// pass A: 196-bucket histogram of dst (bucket = dst>>8), LDS-staged
__global__ __launch_bounds__(256) void bkt_hist(
    const int* __restrict__ dst, int* __restrict__ gcnt)
{
    __shared__ int lcnt[NBKT];
    for (int t = threadIdx.x; t < NBKT; t += 256) lcnt[t] = 0;
    __syncthreads();
    int base = blockIdx.x * 4096;
    for (int it = 0; it < 16; ++it) {
        int e = base + it * 256 + threadIdx.x;
        if (e < N_EDGES) atomicAdd(&lcnt[dst[e] >> 8], 1);
    }
    __syncthreads();
    for (int t = threadIdx.x; t < NBKT; t += 256)
        if (lcnt[t]) atomicAdd(&gcnt[t], lcnt[t]);
}

// pass B: exclusive scan of bucket counts -> gbase[NBKT+1]; gcur = gbase
__global__ __launch_bounds__(256) void bkt_scan(
    const int* __restrict__ gcnt, int* __restrict__ gbase, int* __restrict__ gcur)
{
    __shared__ int s[256];
    int tid = threadIdx.x;
    int v = (tid < NBKT) ? gcnt[tid] : 0;
    s[tid] = v;
    __syncthreads();
    for (int off = 1; off < 256; off <<= 1) {
        int t = (tid >= off) ? s[tid - off] : 0;
        __syncthreads();
        s[tid] += t;
        __syncthreads();
    }
    if (tid < NBKT) { int ex = s[tid] - v; gbase[tid] = ex; gcur[tid] = ex; }
    if (tid == NBKT - 1) gbase[NBKT] = s[tid];
}

// pass C: block-local multisplit of edges into bucket regions.
__global__ __launch_bounds__(256) void bkt_bin(
    const int* __restrict__ src, const int* __restrict__ dst,
    int* __restrict__ gcur, uint32_t* __restrict__ ebin)
{
    __shared__ uint32_t ldata[4096];
    __shared__ uint8_t  lbkt[4096];
    __shared__ int lcnt[NBKT], lofs[NBKT], lcur[NBKT], gb[NBKT];
    __shared__ int lscan[256];
    const int tid  = threadIdx.x;
    const int base = blockIdx.x * 4096;

    for (int t = tid; t < NBKT; t += 256) lcnt[t] = 0;
    __syncthreads();

    uint32_t pk[16];
    int bk[16];
    for (int it = 0; it < 16; ++it) {
        int e = base + it * 256 + tid;
        if (e < N_EDGES) {
            int d = dst[e];
            pk[it] = ((uint32_t)d << 16) | (uint32_t)src[e];
            bk[it] = d >> 8;
            atomicAdd(&lcnt[bk[it]], 1);
        } else bk[it] = -1;
    }
    __syncthreads();

    int v = (tid < NBKT) ? lcnt[tid] : 0;
    lscan[tid] = v;
    __syncthreads();
    for (int off = 1; off < 256; off <<= 1) {
        int t = (tid >= off) ? lscan[tid - off] : 0;
        __syncthreads();
        lscan[tid] += t;
        __syncthreads();
    }
    if (tid < NBKT) {
        lofs[tid] = lscan[tid] - v;
        lcur[tid] = 0;
        gb[tid]   = (v > 0) ? atomicAdd(&gcur[tid], v) : 0;
    }
    __syncthreads();

    for (int it = 0; it < 16; ++it) {
        if (bk[it] >= 0) {
            int p = lofs[bk[it]] + atomicAdd(&lcur[bk[it]], 1);
            ldata[p] = pk[it];
            lbkt[p]  = (uint8_t)bk[it];
        }
    }
    __syncthreads();

    const int n = min(4096, N_EDGES - base);
    for (int i = tid; i < n; i += 256) {
        int b = lbkt[i];
        ebin[gb[b] + (i - lofs[b])] = ldata[i];
    }
}

// pass D: one block per bucket -> row_ptr/invdeg + u16 scatter in own window
__global__ __launch_bounds__(256) void bkt_build(
    const int* __restrict__ gbase, const uint32_t* __restrict__ ebin,
    int* __restrict__ row_ptr, float* __restrict__ invdeg,
    uint16_t* __restrict__ csr_src)
{
    __shared__ int ldeg[256], lscan[256], lcur[256];
    const int b = blockIdx.x, tid = threadIdx.x;
    const int beg = gbase[b], end = gbase[b + 1], n = end - beg;
    const int node0 = b << 8;
    const int nloc = min(256, N_NODES - node0);

    ldeg[tid] = 0;
    __syncthreads();
    for (int i = tid; i < n; i += 256)
        atomicAdd(&ldeg[(int)(ebin[beg + i] >> 16) - node0], 1);
    __syncthreads();

    int d = ldeg[tid];
    lscan[tid] = d;
    __syncthreads();
    for (int off = 1; off < 256; off <<= 1) {
        int t = (tid >= off) ? lscan[tid - off] : 0;
        __syncthreads();
        lscan[tid] += t;
        __syncthreads();
    }
    int excl = lscan[tid] - d;
    lcur[tid] = excl;
    if (tid < nloc) {
        row_ptr[node0 + tid] = beg + excl;
        invdeg[node0 + tid]  = 1.0f / fmaxf((float)d, 1.0f);
    }
    if (b == NBKT - 1 && tid == 0) row_ptr[N_NODES] = end;
    __syncthreads();

    for (int i = tid; i < n; i += 256) {
        uint32_t pk = ebin[beg + i];
        int ld = (int)(pk >> 16) - node0;
        int pos = atomicAdd(&lcur[ld], 1);
        csr_src[beg + pos] = (uint16_t)(pk & 0xFFFFu);
    }
}

// ====== pull aggregation, layer 1: bf16 gather x4-unrolled -> accm_bf16 ======
__global__ __launch_bounds__(256) void agg1_bf(
    const int* __restrict__ row_ptr, const uint16_t* __restrict__ csr_src,
    const __bf16* __restrict__ xb, const float* __restrict__ invdeg,
    __bf16* __restrict__ accm)
{
    int gid  = blockIdx.x * 256 + threadIdx.x;
    int node = gid >> 5;
    int j    = gid & 31;
    if (node >= N_NODES || j >= 25) return;
    int beg = row_ptr[node], end = row_ptr[node + 1];
    f32x4 acc = {0.f, 0.f, 0.f, 0.f};
    int e = beg;
    for (; e + 3 < end; e += 4) {
        int s0 = csr_src[e],     s1 = csr_src[e + 1];
        int s2 = csr_src[e + 2], s3 = csr_src[e + 3];
        bf16x4 v0 = *reinterpret_cast<const bf16x4*>(xb + (size_t)s0 * IN_F + j * 4);
        bf16x4 v1 = *reinterpret_cast<const bf16x4*>(xb + (size_t)s1 * IN_F + j * 4);
        bf16x4 v2 = *reinterpret_cast<const bf16x4*>(xb + (size_t)s2 * IN_F + j * 4);
        bf16x4 v3 = *reinterpret_cast<const bf16x4*>(xb + (size_t)s3 * IN_F + j * 4);
#pragma unroll
        for (int q = 0; q < 4; ++q)
            acc[q] += ((float)v0[q] + (float)v1[q]) + ((float)v2[q] + (float)v3[q]);
    }
    for (; e < end; ++e) {
        bf16x4 v = *reinterpret_cast<const bf16x4*>(xb + (size_t)csr_src[e] * IN_F + j * 4);
#pragma unroll
        for (int q = 0; q < 4; ++q) acc[q] += (float)v[q];
    }
    float inv = invdeg[node];
    bf16x4 r;
#pragma unroll
    for (int q = 0; q < 4; ++q) r[q] = (__bf16)(acc[q] * inv);
    *reinterpret_cast<bf16x4*>(accm + (size_t)node * IN_F + j * 4) = r;
}

// ====== FUSED layer-1 + layer-2 MFMA: xs/hs LDS union -> 4 blocks/CU =========
// 512 threads = 8 waves.
// phase1: wave w = 64 rows x 32 cols; phase2: waves 0..5 = 64 rows x 16 cols
__global__ __launch_bounds__(512, 8) void gemm12_fused(
    const __bf16* __restrict__ xb, const __bf16* __restrict__ accm,
    const __bf16* __restrict__ w1t, const float* __restrict__ b1,
    const uint32_t* __restrict__ mask,
    const __bf16* __restrict__ w2t, const float* __restrict__ b2,
    float* __restrict__ out, __bf16* __restrict__ z2b)
{
    // union: xs [64][232] (29.7KB, dead after phase-1 MFMA) overlays
    //        hs [64][264] (33.8KB).  +2KB msk -> 35.8KB => 4 blocks/CU
    __shared__ __align__(16) unsigned char smem[64 * K2S * sizeof(__bf16)];
    __bf16 (*xs)[K1S] = reinterpret_cast<__bf16 (*)[K1S]>(smem);
    __bf16 (*hs)[K2S] = reinterpret_cast<__bf16 (*)[K2S]>(smem);
    __shared__ uint32_t msk[64][8];
    const int row0 = blockIdx.x * 64;
    const int tid  = threadIdx.x;
    const int nrow = min(64, N_NODES - row0);

    // ---- stage (x || mean) bf16 (zero-pad k in [200,224)) + mask words ----
    for (int t = tid; t < 64 * (K1 / 4); t += 512) {
        int r = t / (K1 / 4), c4 = t % (K1 / 4);
        bf16x4 v = {};
        if (r < nrow) {
            if (c4 < 25)
                v = *reinterpret_cast<const bf16x4*>(xb + (size_t)(row0 + r) * IN_F + c4 * 4);
            else if (c4 < 50)
                v = *reinterpret_cast<const bf16x4*>(accm + (size_t)(row0 + r) * IN_F + (c4 - 25) * 4);
        }
        *reinterpret_cast<bf16x4*>(&xs[r][c4 * 4]) = v;
    }
    {
        int r = tid >> 3, w8 = tid & 7;
        msk[r][w8] = (r < nrow) ? mask[(size_t)(row0 + r) * 8 + w8] : 0u;
    }
    __syncthreads();

    const int w    = tid >> 6;          // wave 0..7
    const int lane = tid & 63;
    const int lm   = lane & 15;
    const int hi   = lane >> 4;         // 0..3
    const int lk   = hi * 8;

    // ---- phase 1: h1 = (x||mean) @ W1^T ----
    const int wc = w * 32;
    f32x4 acc[2][4];
#pragma unroll
    for (int ct = 0; ct < 2; ++ct)
#pragma unroll
        for (int rg = 0; rg < 4; ++rg) acc[ct][rg] = (f32x4){0.f, 0.f, 0.f, 0.f};

    for (int kk = 0; kk < K1 / 32; ++kk) {
        bf16x8 a[4];
#pragma unroll
        for (int rg = 0; rg < 4; ++rg)
            a[rg] = *reinterpret_cast<const bf16x8*>(&xs[rg * 16 + lm][kk * 32 + lk]);
#pragma unroll
        for (int ct = 0; ct < 2; ++ct) {
            const bf16x8 b = *reinterpret_cast<const bf16x8*>(
                &w1t[(size_t)(wc + ct * 16 + lm) * K1 + kk * 32 + lk]);
#pragma unroll
            for (int rg = 0; rg < 4; ++rg)
                acc[ct][rg] = __builtin_amdgcn_mfma_f32_16x16x32_bf16(a[rg], b, acc[ct][rg], 0, 0, 0);
        }
    }
    __syncthreads();   // all waves done READING xs before hs overwrites it

    // epilogue 1: bias + ReLU + dropout -> hs (LDS)
#pragma unroll
    for (int ct = 0; ct < 2; ++ct) {
        const int col = wc + ct * 16 + lm;
        const float bj = b1[col];
        const int bit = ct * 16 + lm;
#pragma unroll
        for (int rg = 0; rg < 4; ++rg) {
#pragma unroll
            for (int reg = 0; reg < 4; ++reg) {
                int r = rg * 16 + hi * 4 + reg;
                float v = 0.f;
                if (r < nrow) {
                    v = fmaxf(acc[ct][rg][reg] + bj, 0.f);
                    v = ((msk[r][w] >> bit) & 1u) ? v * 2.0f : 0.f;
                }
                hs[r][col] = (__bf16)v;
            }
        }
    }
    __syncthreads();

    // ---- phase 2: [out_self | z2] = h1 @ W2^T ; waves 0..5, 16 cols each ----
    if (w < 6) {
        const int wc2 = w * 16;
        f32x4 acc2[4];
#pragma unroll
        for (int rg = 0; rg < 4; ++rg) acc2[rg] = (f32x4){0.f, 0.f, 0.f, 0.f};

        for (int kk = 0; kk < K2 / 32; ++kk) {
            bf16x8 a[4];
#pragma unroll
            for (int rg = 0; rg < 4; ++rg)
                a[rg] = *reinterpret_cast<const bf16x8*>(&hs[rg * 16 + lm][kk * 32 + lk]);
            const bf16x8 b = *reinterpret_cast<const bf16x8*>(
                &w2t[(size_t)(wc2 + lm) * K2 + kk * 32 + lk]);
#pragma unroll
            for (int rg = 0; rg < 4; ++rg)
                acc2[rg] = __builtin_amdgcn_mfma_f32_16x16x32_bf16(a[rg], b, acc2[rg], 0, 0, 0);
        }

        const int col = wc2 + lm;
#pragma unroll
        for (int rg = 0; rg < 4; ++rg) {
#pragma unroll
            for (int reg = 0; reg < 4; ++reg) {
                int r = rg * 16 + hi * 4 + reg;
                if (r >= nrow) continue;
                int g = row0 + r;
                float v = acc2[rg][reg];
                if (col < NCLS)                 out[(size_t)g * NCLS + col] = v + b2[col];
                else if (col >= 48 && col < 95) z2b[(size_t)g * 48 + (col - 48)] = (__bf16)v;
                else if (col == 95)             z2b[(size_t)g * 48 + 47] = (__bf16)0.f;
            }
        }
    }
}

// ====== pull aggregation, layer 2: bf16 gather x4-unrolled, mean + add =======
__global__ __launch_bounds__(256) void agg2_bf(
    const int* __restrict__ row_ptr, const uint16_t* __restrict__ csr_src,
    const __bf16* __restrict__ z2b, const float* __restrict__ invdeg,
    float* __restrict__ out)
{
    int gid  = blockIdx.x * 256 + threadIdx.x;
    int node = gid >> 4;
    int j    = gid & 15;
    if (node >= N_NODES || j >= 12) return;
    int beg = row_ptr[node], end = row_ptr[node + 1];
    f32x4 acc = {0.f, 0.f, 0.f, 0.f};
    int e = beg;
    for (; e + 3 < end; e += 4) {
        int s0 = csr_src[e],     s1 = csr_src[e + 1];
        int s2 = csr_src[e + 2], s3 = csr_src[e + 3];
        bf16x4 v0 = *reinterpret_cast<const bf16x4*>(z2b + (size_t)s0 * 48 + j * 4);
        bf16x4 v1 = *reinterpret_cast<const bf16x4*>(z2b + (size_t)s1 * 48 + j * 4);
        bf16x4 v2 = *reinterpret_cast<const bf16x4*>(z2b + (size_t)s2 * 48 + j * 4);
        bf16x4 v3 = *reinterpret_cast<const bf16x4*>(z2b + (size_t)s3 * 48 + j * 4);
#pragma unroll
        for (int q = 0; q < 4; ++q)
            acc[q] += ((float)v0[q] + (float)v1[q]) + ((float)v2[q] + (float)v3[q]);
    }
    for (; e < end; ++e) {
        bf16x4 v = *reinterpret_cast<const bf16x4*>(z2b + (size_t)csr_src[e] * 48 + j * 4);
#pragma unroll
        for (int q = 0; q < 4; ++q) acc[q] += (float)v[q];
    }
    float inv = invdeg[node];
#pragma unroll
    for (int q = 0; q < 4; ++q) {
        int col = j * 4 + q;
        if (col < NCLS)
            out[(size_t)node * NCLS + col] += acc[q] * inv;
    }
}

extern "C" void kernel_launch(void* const* d_in, const int* in_sizes, int n_in,
                              void* d_out, int out_size, void* d_ws, size_t ws_size,
                              hipStream_t stream)
{
    const float* x   = (const float*)d_in[0];
    const int*   src = (const int*)  d_in[1];
    const int*   dst = (const int*)  d_in[2];
    const float* Ws1 = (const float*)d_in[3];
    const float* Wn1 = (const float*)d_in[4];
    const float* b1  = (const float*)d_in[5];
    const float* Ws2 = (const float*)d_in[6];
    const float* Wn2 = (const float*)d_in[7];
    const float* b2  = (const float*)d_in[8];
    float* out = (float*)d_out;

    // ---- workspace layout (int-slot / float-slot units) ----
    int*      wsi     = (int*)d_ws;
    int*      row_ptr = wsi;                 //  50,001
    int*      gcnt    = wsi + 50008;         //     196
    int*      gbase   = wsi + 50208;         //     197
    int*      gcur    = wsi + 50408;         //     196
    uint32_t* ebin    = (uint32_t*)(wsi + 50608);    // 800,000 u32
    uint16_t* csr_src = (uint16_t*)(wsi + 850608);   // 800,000 u16
    float*    wsf     = (float*)d_ws;
    float*    invdeg  = wsf + 1300000;               //  50,000 f32
    __bf16*   xb      = (__bf16*)(wsf + 1350000);    //  5.0M bf16
    __bf16*   accm    = (__bf16*)(wsf + 3850000);    //  5.0M bf16
    uint32_t* mask    = (uint32_t*)(wsf + 6350000);  //  400K u32
    __bf16*   w1t     = (__bf16*)(wsf + 6750000);    // 57,344 bf16
    __bf16*   w2t     = (__bf16*)(wsf + 6780000);    // 24,576 bf16
    __bf16*   z2b     = (__bf16*)(wsf + 6800000);    //  2.4M bf16  (~32 MB)

    prep<<<PREP_NB, 256, 0, stream>>>(mask, x, xb, Ws1, Wn1, w1t, Ws2, Wn2, w2t, gcnt);

    bkt_hist <<<NBKT, 256, 0, stream>>>(dst, gcnt);
    bkt_scan <<<1, 256, 0, stream>>>(gcnt, gbase, gcur);
    bkt_bin  <<<NBKT, 256, 0, stream>>>(src, dst, gcur, ebin);
    bkt_build<<<NBKT, 256, 0, stream>>>(gbase, ebin, row_ptr, invdeg, csr_src);

    agg1_bf<<<(N_NODES * 32 + 255) / 256, 256, 0, stream>>>(row_ptr, csr_src, xb, invdeg, accm);
    gemm12_fused<<<(N_NODES + 63) / 64, 512, 0, stream>>>(
        xb, accm, w1t, b1, mask, w2t, b2, out, z2b);
    agg2_bf<<<(N_NODES * 16 + 255) / 256, 256, 0, stream>>>(row_ptr, csr_src, z2b, invdeg, out);
}

// Round 15
// 159.408 us; speedup vs baseline: 5.2007x; 1.0167x over previous
//
#include <hip/hip_runtime.h>
#include <stdint.h>

#define N_NODES 50000
#define N_EDGES 800000
#define IN_F    100
#define HID     256
#define NCLS    47
#define K1      224   // 200 padded to 7*32
#define K1S     232   // LDS row stride (bank-spread)
#define K2      256
#define K2S     264
#define NBKT    196   // ceil(50000/256) buckets of 256 dst nodes
#define MASK_WORDS (N_NODES * (HID / 32))   // 400,000

#define MASK_NB ((MASK_WORDS + 255) / 256)            // 1563
#define XCVT_NB ((N_NODES * IN_F / 4 + 255) / 256)    // 4883
#define W1T_NB  ((HID * K1 + 255) / 256)              // 224
#define W2T_NB  ((96 * K2 + 255) / 256)               // 96
#define PREP_NB (MASK_NB + XCVT_NB + W1T_NB + W2T_NB + 1)

typedef __bf16 bf16x8 __attribute__((ext_vector_type(8)));
typedef __bf16 bf16x4 __attribute__((ext_vector_type(4)));
typedef float  f32x4  __attribute__((ext_vector_type(4)));

__device__ __forceinline__ uint32_t rotl32(uint32_t v, uint32_t r) {
    return (v << r) | (v >> (32u - r));
}

// JAX threefry2x32, key=(0,42), partitionable: counter=(0,i), bits=x0^x1.
// bernoulli(0.5) keeps iff MSB==0.  (verified round 2)
__device__ __forceinline__ uint32_t jax_bits(uint32_t i) {
    const uint32_t ks0 = 0u, ks1 = 42u, ks2 = 0x1BD11BDAu ^ 42u;
    uint32_t x0 = 0u + ks0;
    uint32_t x1 = i + ks1;
    x0 += x1; x1 = rotl32(x1, 13); x1 ^= x0;
    x0 += x1; x1 = rotl32(x1, 15); x1 ^= x0;
    x0 += x1; x1 = rotl32(x1, 26); x1 ^= x0;
    x0 += x1; x1 = rotl32(x1,  6); x1 ^= x0;
    x0 += ks1; x1 += ks2 + 1u;
    x0 += x1; x1 = rotl32(x1, 17); x1 ^= x0;
    x0 += x1; x1 = rotl32(x1, 29); x1 ^= x0;
    x0 += x1; x1 = rotl32(x1, 16); x1 ^= x0;
    x0 += x1; x1 = rotl32(x1, 24); x1 ^= x0;
    x0 += ks2; x1 += ks0 + 2u;
    x0 += x1; x1 = rotl32(x1, 13); x1 ^= x0;
    x0 += x1; x1 = rotl32(x1, 15); x1 ^= x0;
    x0 += x1; x1 = rotl32(x1, 26); x1 ^= x0;
    x0 += x1; x1 = rotl32(x1,  6); x1 ^= x0;
    x0 += ks0; x1 += ks1 + 3u;
    x0 += x1; x1 = rotl32(x1, 17); x1 ^= x0;
    x0 += x1; x1 = rotl32(x1, 29); x1 ^= x0;
    x0 += x1; x1 = rotl32(x1, 16); x1 ^= x0;
    x0 += x1; x1 = rotl32(x1, 24); x1 ^= x0;
    x0 += ks1; x1 += ks2 + 4u;
    x0 += x1; x1 = rotl32(x1, 13); x1 ^= x0;
    x0 += x1; x1 = rotl32(x1, 15); x1 ^= x0;
    x0 += x1; x1 = rotl32(x1, 26); x1 ^= x0;
    x0 += x1; x1 = rotl32(x1,  6); x1 ^= x0;
    x0 += ks2; x1 += ks0 + 5u;
    return x0 ^ x1;
}

// ===== merged prep: mask | x->bf16 | W1^T | W2^T | zero gcnt (independent) ===
__global__ __launch_bounds__(256) void prep(
    uint32_t* __restrict__ mask, const float* __restrict__ x,
    __bf16* __restrict__ xb,
    const float* __restrict__ Ws1, const float* __restrict__ Wn1,
    __bf16* __restrict__ w1t,
    const float* __restrict__ Ws2, const float* __restrict__ Wn2,
    __bf16* __restrict__ w2t, int* __restrict__ gcnt)
{
    const int b = blockIdx.x, tid = threadIdx.x;
    if (b < MASK_NB) {
        int w = b * 256 + tid;
        if (w >= MASK_WORDS) return;
        uint32_t base = (uint32_t)w * 32u;
        uint32_t m = 0u;
#pragma unroll
        for (int j = 0; j < 32; ++j) {
            uint32_t bits = jax_bits(base + (uint32_t)j);
            m |= ((~bits) >> 31) << j;
        }
        mask[w] = m;
    } else if (b < MASK_NB + XCVT_NB) {
        int i = (b - MASK_NB) * 256 + tid;
        if (i * 4 >= N_NODES * IN_F) return;
        float4 v = reinterpret_cast<const float4*>(x)[i];
        bf16x4 bb;
        bb[0] = (__bf16)v.x; bb[1] = (__bf16)v.y;
        bb[2] = (__bf16)v.z; bb[3] = (__bf16)v.w;
        *reinterpret_cast<bf16x4*>(xb + i * 4) = bb;
    } else if (b < MASK_NB + XCVT_NB + W1T_NB) {
        int gid = (b - MASK_NB - XCVT_NB) * 256 + tid;
        if (gid >= HID * K1) return;
        int j = gid / K1, k = gid % K1;
        float v = 0.f;
        if (k < IN_F)          v = Ws1[k * HID + j];
        else if (k < 2 * IN_F) v = Wn1[(k - IN_F) * HID + j];
        w1t[gid] = (__bf16)v;
    } else if (b < MASK_NB + XCVT_NB + W1T_NB + W2T_NB) {
        int gid = (b - MASK_NB - XCVT_NB - W1T_NB) * 256 + tid;
        if (gid >= 96 * K2) return;
        int j = gid / K2, k = gid % K2;
        float v = 0.f;
        if (j < NCLS)               v = Ws2[k * NCLS + j];
        else if (j >= 48 && j < 95) v = Wn2[k * NCLS + (j - 48)];
        w2t[gid] = (__bf16)v;
    } else {
        if (tid < NBKT) gcnt[tid] = 0;
    }
}

// ============ locality-partitioned CSR build (dst -> srcs) ===================
__global__ __launch_bounds__(256) void bkt_hist(
    const int* __restrict__ dst, int* __restrict__ gcnt)
{
    __shared__ int lcnt[NBKT];
    for (int t = threadIdx.x; t < NBKT; t += 256) lcnt[t] = 0;
    __syncthreads();
    int base = blockIdx.x * 4096;
    for (int it = 0; it < 16; ++it) {
        int e = base + it * 256 + threadIdx.x;
        if (e < N_EDGES) atomicAdd(&lcnt[dst[e] >> 8], 1);
    }
    __syncthreads();
    for (int t = threadIdx.x; t < NBKT; t += 256)
        if (lcnt[t]) atomicAdd(&gcnt[t], lcnt[t]);
}

__global__ __launch_bounds__(256) void bkt_scan(
    const int* __restrict__ gcnt, int* __restrict__ gbase, int* __restrict__ gcur)
{
    __shared__ int s[256];
    int tid = threadIdx.x;
    int v = (tid < NBKT) ? gcnt[tid] : 0;
    s[tid] = v;
    __syncthreads();
    for (int off = 1; off < 256; off <<= 1) {
        int t = (tid >= off) ? s[tid - off] : 0;
        __syncthreads();
        s[tid] += t;
        __syncthreads();
    }
    if (tid < NBKT) { int ex = s[tid] - v; gbase[tid] = ex; gcur[tid] = ex; }
    if (tid == NBKT - 1) gbase[NBKT] = s[tid];
}

__global__ __launch_bounds__(256) void bkt_bin(
    const int* __restrict__ src, const int* __restrict__ dst,
    int* __restrict__ gcur, uint32_t* __restrict__ ebin)
{
    __shared__ uint32_t ldata[4096];
    __shared__ uint8_t  lbkt[4096];
    __shared__ int lcnt[NBKT], lofs[NBKT], lcur[NBKT], gb[NBKT];
    __shared__ int lscan[256];
    const int tid  = threadIdx.x;
    const int base = blockIdx.x * 4096;

    for (int t = tid; t < NBKT; t += 256) lcnt[t] = 0;
    __syncthreads();

    uint32_t pk[16];
    int bk[16];
    for (int it = 0; it < 16; ++it) {
        int e = base + it * 256 + tid;
        if (e < N_EDGES) {
            int d = dst[e];
            pk[it] = ((uint32_t)d << 16) | (uint32_t)src[e];
            bk[it] = d >> 8;
            atomicAdd(&lcnt[bk[it]], 1);
        } else bk[it] = -1;
    }
    __syncthreads();

    int v = (tid < NBKT) ? lcnt[tid] : 0;
    lscan[tid] = v;
    __syncthreads();
    for (int off = 1; off < 256; off <<= 1) {
        int t = (tid >= off) ? lscan[tid - off] : 0;
        __syncthreads();
        lscan[tid] += t;
        __syncthreads();
    }
    if (tid < NBKT) {
        lofs[tid] = lscan[tid] - v;
        lcur[tid] = 0;
        gb[tid]   = (v > 0) ? atomicAdd(&gcur[tid], v) : 0;
    }
    __syncthreads();

    for (int it = 0; it < 16; ++it) {
        if (bk[it] >= 0) {
            int p = lofs[bk[it]] + atomicAdd(&lcur[bk[it]], 1);
            ldata[p] = pk[it];
            lbkt[p]  = (uint8_t)bk[it];
        }
    }
    __syncthreads();

    const int n = min(4096, N_EDGES - base);
    for (int i = tid; i < n; i += 256) {
        int b = lbkt[i];
        ebin[gb[b] + (i - lofs[b])] = ldata[i];
    }
}

__global__ __launch_bounds__(256) void bkt_build(
    const int* __restrict__ gbase, const uint32_t* __restrict__ ebin,
    int* __restrict__ row_ptr, float* __restrict__ invdeg,
    uint16_t* __restrict__ csr_src)
{
    __shared__ int ldeg[256], lscan[256], lcur[256];
    const int b = blockIdx.x, tid = threadIdx.x;
    const int beg = gbase[b], end = gbase[b + 1], n = end - beg;
    const int node0 = b << 8;
    const int nloc = min(256, N_NODES - node0);

    ldeg[tid] = 0;
    __syncthreads();
    for (int i = tid; i < n; i += 256)
        atomicAdd(&ldeg[(int)(ebin[beg + i] >> 16) - node0], 1);
    __syncthreads();

    int d = ldeg[tid];
    lscan[tid] = d;
    __syncthreads();
    for (int off = 1; off < 256; off <<= 1) {
        int t = (tid >= off) ? lscan[tid - off] : 0;
        __syncthreads();
        lscan[tid] += t;
        __syncthreads();
    }
    int excl = lscan[tid] - d;
    lcur[tid] = excl;
    if (tid < nloc) {
        row_ptr[node0 + tid] = beg + excl;
        invdeg[node0 + tid]  = 1.0f / fmaxf((float)d, 1.0f);
    }
    if (b == NBKT - 1 && tid == 0) row_ptr[N_NODES] = end;
    __syncthreads();

    for (int i = tid; i < n; i += 256) {
        uint32_t pk = ebin[beg + i];
        int ld = (int)(pk >> 16) - node0;
        int pos = atomicAdd(&lcur[ld], 1);
        csr_src[beg + pos] = (uint16_t)(pk & 0xFFFFu);
    }
}

// ====== pull aggregation, layer 1: bf16 gather x4-unrolled -> accm_bf16 ======
__global__ __launch_bounds__(256) void agg1_bf(
    const int* __restrict__ row_ptr, const uint16_t* __restrict__ csr_src,
    const __bf16* __restrict__ xb, const float* __restrict__ invdeg,
    __bf16* __restrict__ accm)
{
    int gid  = blockIdx.x * 256 + threadIdx.x;
    int node = gid >> 5;
    int j    = gid & 31;
    if (node >= N_NODES || j >= 25) return;
    int beg = row_ptr[node], end = row_ptr[node + 1];
    f32x4 acc = {0.f, 0.f, 0.f, 0.f};
    int e = beg;
    for (; e + 3 < end; e += 4) {
        int s0 = csr_src[e],     s1 = csr_src[e + 1];
        int s2 = csr_src[e + 2], s3 = csr_src[e + 3];
        bf16x4 v0 = *reinterpret_cast<const bf16x4*>(xb + (size_t)s0 * IN_F + j * 4);
        bf16x4 v1 = *reinterpret_cast<const bf16x4*>(xb + (size_t)s1 * IN_F + j * 4);
        bf16x4 v2 = *reinterpret_cast<const bf16x4*>(xb + (size_t)s2 * IN_F + j * 4);
        bf16x4 v3 = *reinterpret_cast<const bf16x4*>(xb + (size_t)s3 * IN_F + j * 4);
#pragma unroll
        for (int q = 0; q < 4; ++q)
            acc[q] += ((float)v0[q] + (float)v1[q]) + ((float)v2[q] + (float)v3[q]);
    }
    for (; e < end; ++e) {
        bf16x4 v = *reinterpret_cast<const bf16x4*>(xb + (size_t)csr_src[e] * IN_F + j * 4);
#pragma unroll
        for (int q = 0; q < 4; ++q) acc[q] += (float)v[q];
    }
    float inv = invdeg[node];
    bf16x4 r;
#pragma unroll
    for (int q = 0; q < 4; ++q) r[q] = (__bf16)(acc[q] * inv);
    *reinterpret_cast<bf16x4*>(accm + (size_t)node * IN_F + j * 4) = r;
}

// ====== FUSED layer-1 + layer-2 MFMA: 32 rows/block, 256 thr, 6 blk/CU =======
// phase1: wave w (0..3) = 32 rows x 64 cols (ct=4, rg=2)
// phase2: waves 0..2    = 32 rows x 32 cols (ct=2, rg=2)
__global__ __launch_bounds__(256, 6) void gemm12_fused(
    const __bf16* __restrict__ xb, const __bf16* __restrict__ accm,
    const __bf16* __restrict__ w1t, const float* __restrict__ b1,
    const uint32_t* __restrict__ mask,
    const __bf16* __restrict__ w2t, const float* __restrict__ b2,
    float* __restrict__ out, __bf16* __restrict__ z2b)
{
    // union: xs [32][232] (14.5KB, dead after phase-1 MFMA) overlays
    //        hs [32][264] (16.5KB). +1KB msk => ~17.9KB, 6 blocks/CU (VGPR<=85)
    __shared__ __align__(16) unsigned char smem[32 * K2S * sizeof(__bf16)];
    __bf16 (*xs)[K1S] = reinterpret_cast<__bf16 (*)[K1S]>(smem);
    __bf16 (*hs)[K2S] = reinterpret_cast<__bf16 (*)[K2S]>(smem);
    __shared__ uint32_t msk[32][8];
    const int row0 = blockIdx.x * 32;
    const int tid  = threadIdx.x;
    const int nrow = min(32, N_NODES - row0);

    // ---- stage (x || mean) bf16 (zero-pad k in [200,224)) + mask words ----
    for (int t = tid; t < 32 * (K1 / 4); t += 256) {
        int r = t / (K1 / 4), c4 = t % (K1 / 4);
        bf16x4 v = {};
        if (r < nrow) {
            if (c4 < 25)
                v = *reinterpret_cast<const bf16x4*>(xb + (size_t)(row0 + r) * IN_F + c4 * 4);
            else if (c4 < 50)
                v = *reinterpret_cast<const bf16x4*>(accm + (size_t)(row0 + r) * IN_F + (c4 - 25) * 4);
        }
        *reinterpret_cast<bf16x4*>(&xs[r][c4 * 4]) = v;
    }
    {
        int r = tid >> 3, w8 = tid & 7;   // 32 rows x 8 words = 256 = blockDim
        msk[r][w8] = (r < nrow) ? mask[(size_t)(row0 + r) * 8 + w8] : 0u;
    }
    __syncthreads();

    const int w    = tid >> 6;          // wave 0..3
    const int lane = tid & 63;
    const int lm   = lane & 15;
    const int hi   = lane >> 4;         // 0..3
    const int lk   = hi * 8;

    // ---- phase 1: h1 = (x||mean) @ W1^T ; wave cols = w*64 + ct*16 + lm ----
    const int wc = w * 64;
    f32x4 acc[4][2];
#pragma unroll
    for (int ct = 0; ct < 4; ++ct)
#pragma unroll
        for (int rg = 0; rg < 2; ++rg) acc[ct][rg] = (f32x4){0.f, 0.f, 0.f, 0.f};

    for (int kk = 0; kk < K1 / 32; ++kk) {
        bf16x8 a[2];
#pragma unroll
        for (int rg = 0; rg < 2; ++rg)
            a[rg] = *reinterpret_cast<const bf16x8*>(&xs[rg * 16 + lm][kk * 32 + lk]);
#pragma unroll
        for (int ct = 0; ct < 4; ++ct) {
            const bf16x8 b = *reinterpret_cast<const bf16x8*>(
                &w1t[(size_t)(wc + ct * 16 + lm) * K1 + kk * 32 + lk]);
#pragma unroll
            for (int rg = 0; rg < 2; ++rg)
                acc[ct][rg] = __builtin_amdgcn_mfma_f32_16x16x32_bf16(a[rg], b, acc[ct][rg], 0, 0, 0);
        }
    }
    __syncthreads();   // all waves done READING xs before hs overwrites it

    // epilogue 1: bias + ReLU + dropout -> hs (LDS)
#pragma unroll
    for (int ct = 0; ct < 4; ++ct) {
        const int col = wc + ct * 16 + lm;
        const float bj = b1[col];
        const int word = (w << 1) + ((ct * 16 + lm) >> 5);
        const int bit  = (ct * 16 + lm) & 31;
#pragma unroll
        for (int rg = 0; rg < 2; ++rg) {
#pragma unroll
            for (int reg = 0; reg < 4; ++reg) {
                int r = rg * 16 + hi * 4 + reg;
                float v = 0.f;
                if (r < nrow) {
                    v = fmaxf(acc[ct][rg][reg] + bj, 0.f);
                    v = ((msk[r][word] >> bit) & 1u) ? v * 2.0f : 0.f;
                }
                hs[r][col] = (__bf16)v;
            }
        }
    }
    __syncthreads();

    // ---- phase 2: [out_self | z2] = h1 @ W2^T ; waves 0..2, 32 cols each ----
    if (w < 3) {
        const int wc2 = w * 32;
        f32x4 acc2[2][2];
#pragma unroll
        for (int ct = 0; ct < 2; ++ct)
#pragma unroll
            for (int rg = 0; rg < 2; ++rg) acc2[ct][rg] = (f32x4){0.f, 0.f, 0.f, 0.f};

        for (int kk = 0; kk < K2 / 32; ++kk) {
            bf16x8 a[2];
#pragma unroll
            for (int rg = 0; rg < 2; ++rg)
                a[rg] = *reinterpret_cast<const bf16x8*>(&hs[rg * 16 + lm][kk * 32 + lk]);
#pragma unroll
            for (int ct = 0; ct < 2; ++ct) {
                const bf16x8 b = *reinterpret_cast<const bf16x8*>(
                    &w2t[(size_t)(wc2 + ct * 16 + lm) * K2 + kk * 32 + lk]);
#pragma unroll
                for (int rg = 0; rg < 2; ++rg)
                    acc2[ct][rg] = __builtin_amdgcn_mfma_f32_16x16x32_bf16(a[rg], b, acc2[ct][rg], 0, 0, 0);
            }
        }

#pragma unroll
        for (int ct = 0; ct < 2; ++ct) {
            const int col = wc2 + ct * 16 + lm;
#pragma unroll
            for (int rg = 0; rg < 2; ++rg) {
#pragma unroll
                for (int reg = 0; reg < 4; ++reg) {
                    int r = rg * 16 + hi * 4 + reg;
                    if (r >= nrow) continue;
                    int g = row0 + r;
                    float v = acc2[ct][rg][reg];
                    if (col < NCLS)                 out[(size_t)g * NCLS + col] = v + b2[col];
                    else if (col >= 48 && col < 95) z2b[(size_t)g * 48 + (col - 48)] = (__bf16)v;
                    else if (col == 95)             z2b[(size_t)g * 48 + 47] = (__bf16)0.f;
                }
            }
        }
    }
}

// ====== pull aggregation, layer 2: bf16 gather x4-unrolled, mean + add =======
__global__ __launch_bounds__(256) void agg2_bf(
    const int* __restrict__ row_ptr, const uint16_t* __restrict__ csr_src,
    const __bf16* __restrict__ z2b, const float* __restrict__ invdeg,
    float* __restrict__ out)
{
    int gid  = blockIdx.x * 256 + threadIdx.x;
    int node = gid >> 4;
    int j    = gid & 15;
    if (node >= N_NODES || j >= 12) return;
    int beg = row_ptr[node], end = row_ptr[node + 1];
    f32x4 acc = {0.f, 0.f, 0.f, 0.f};
    int e = beg;
    for (; e + 3 < end; e += 4) {
        int s0 = csr_src[e],     s1 = csr_src[e + 1];
        int s2 = csr_src[e + 2], s3 = csr_src[e + 3];
        bf16x4 v0 = *reinterpret_cast<const bf16x4*>(z2b + (size_t)s0 * 48 + j * 4);
        bf16x4 v1 = *reinterpret_cast<const bf16x4*>(z2b + (size_t)s1 * 48 + j * 4);
        bf16x4 v2 = *reinterpret_cast<const bf16x4*>(z2b + (size_t)s2 * 48 + j * 4);
        bf16x4 v3 = *reinterpret_cast<const bf16x4*>(z2b + (size_t)s3 * 48 + j * 4);
#pragma unroll
        for (int q = 0; q < 4; ++q)
            acc[q] += ((float)v0[q] + (float)v1[q]) + ((float)v2[q] + (float)v3[q]);
    }
    for (; e < end; ++e) {
        bf16x4 v = *reinterpret_cast<const bf16x4*>(z2b + (size_t)csr_src[e] * 48 + j * 4);
#pragma unroll
        for (int q = 0; q < 4; ++q) acc[q] += (float)v[q];
    }
    float inv = invdeg[node];
#pragma unroll
    for (int q = 0; q < 4; ++q) {
        int col = j * 4 + q;
        if (col < NCLS)
            out[(size_t)node * NCLS + col] += acc[q] * inv;
    }
}

extern "C" void kernel_launch(void* const* d_in, const int* in_sizes, int n_in,
                              void* d_out, int out_size, void* d_ws, size_t ws_size,
                              hipStream_t stream)
{
    const float* x   = (const float*)d_in[0];
    const int*   src = (const int*)  d_in[1];
    const int*   dst = (const int*)  d_in[2];
    const float* Ws1 = (const float*)d_in[3];
    const float* Wn1 = (const float*)d_in[4];
    const float* b1  = (const float*)d_in[5];
    const float* Ws2 = (const float*)d_in[6];
    const float* Wn2 = (const float*)d_in[7];
    const float* b2  = (const float*)d_in[8];
    float* out = (float*)d_out;

    // ---- workspace layout (int-slot / float-slot units) ----
    int*      wsi     = (int*)d_ws;
    int*      row_ptr = wsi;                 //  50,001
    int*      gcnt    = wsi + 50008;         //     196
    int*      gbase   = wsi + 50208;         //     197
    int*      gcur    = wsi + 50408;         //     196
    uint32_t* ebin    = (uint32_t*)(wsi + 50608);    // 800,000 u32
    uint16_t* csr_src = (uint16_t*)(wsi + 850608);   // 800,000 u16
    float*    wsf     = (float*)d_ws;
    float*    invdeg  = wsf + 1300000;               //  50,000 f32
    __bf16*   xb      = (__bf16*)(wsf + 1350000);    //  5.0M bf16
    __bf16*   accm    = (__bf16*)(wsf + 3850000);    //  5.0M bf16
    uint32_t* mask    = (uint32_t*)(wsf + 6350000);  //  400K u32
    __bf16*   w1t     = (__bf16*)(wsf + 6750000);    // 57,344 bf16
    __bf16*   w2t     = (__bf16*)(wsf + 6780000);    // 24,576 bf16
    __bf16*   z2b     = (__bf16*)(wsf + 6800000);    //  2.4M bf16  (~32 MB)

    prep<<<PREP_NB, 256, 0, stream>>>(mask, x, xb, Ws1, Wn1, w1t, Ws2, Wn2, w2t, gcnt);

    bkt_hist <<<NBKT, 256, 0, stream>>>(dst, gcnt);
    bkt_scan <<<1, 256, 0, stream>>>(gcnt, gbase, gcur);
    bkt_bin  <<<NBKT, 256, 0, stream>>>(src, dst, gcur, ebin);
    bkt_build<<<NBKT, 256, 0, stream>>>(gbase, ebin, row_ptr, invdeg, csr_src);

    agg1_bf<<<(N_NODES * 32 + 255) / 256, 256, 0, stream>>>(row_ptr, csr_src, xb, invdeg, accm);
    gemm12_fused<<<(N_NODES + 31) / 32, 256, 0, stream>>>(
        xb, accm, w1t, b1, mask, w2t, b2, out, z2b);
    agg2_bf<<<(N_NODES * 16 + 255) / 256, 256, 0, stream>>>(row_ptr, csr_src, z2b, invdeg, out);
}

// Round 16
// 158.616 us; speedup vs baseline: 5.2267x; 1.0050x over previous
//
#include <hip/hip_runtime.h>
#include <stdint.h>

#define N_NODES 50000
#define N_EDGES 800000
#define IN_F    100
#define HID     256
#define NCLS    47
#define K1      224   // 200 padded to 7*32
#define K1S     232   // LDS row stride (bank-spread)
#define K2      256
#define K2S     264
#define NBKT    196   // ceil(50000/256) buckets of 256 dst nodes
#define MASK_WORDS (N_NODES * (HID / 32))   // 400,000

#define MASK_NB ((MASK_WORDS + 255) / 256)            // 1563
#define XCVT_NB ((N_NODES * IN_F / 4 + 255) / 256)    // 4883
#define W1T_NB  ((HID * K1 + 255) / 256)              // 224
#define W2T_NB  ((96 * K2 + 255) / 256)               // 96
#define PREP_NB (MASK_NB + XCVT_NB + W1T_NB + W2T_NB + 1)

typedef __bf16 bf16x8 __attribute__((ext_vector_type(8)));
typedef __bf16 bf16x4 __attribute__((ext_vector_type(4)));
typedef float  f32x4  __attribute__((ext_vector_type(4)));

__device__ __forceinline__ uint32_t rotl32(uint32_t v, uint32_t r) {
    return (v << r) | (v >> (32u - r));
}

// JAX threefry2x32, key=(0,42), partitionable: counter=(0,i), bits=x0^x1.
// bernoulli(0.5) keeps iff MSB==0.  (verified round 2)
__device__ __forceinline__ uint32_t jax_bits(uint32_t i) {
    const uint32_t ks0 = 0u, ks1 = 42u, ks2 = 0x1BD11BDAu ^ 42u;
    uint32_t x0 = 0u + ks0;
    uint32_t x1 = i + ks1;
    x0 += x1; x1 = rotl32(x1, 13); x1 ^= x0;
    x0 += x1; x1 = rotl32(x1, 15); x1 ^= x0;
    x0 += x1; x1 = rotl32(x1, 26); x1 ^= x0;
    x0 += x1; x1 = rotl32(x1,  6); x1 ^= x0;
    x0 += ks1; x1 += ks2 + 1u;
    x0 += x1; x1 = rotl32(x1, 17); x1 ^= x0;
    x0 += x1; x1 = rotl32(x1, 29); x1 ^= x0;
    x0 += x1; x1 = rotl32(x1, 16); x1 ^= x0;
    x0 += x1; x1 = rotl32(x1, 24); x1 ^= x0;
    x0 += ks2; x1 += ks0 + 2u;
    x0 += x1; x1 = rotl32(x1, 13); x1 ^= x0;
    x0 += x1; x1 = rotl32(x1, 15); x1 ^= x0;
    x0 += x1; x1 = rotl32(x1, 26); x1 ^= x0;
    x0 += x1; x1 = rotl32(x1,  6); x1 ^= x0;
    x0 += ks0; x1 += ks1 + 3u;
    x0 += x1; x1 = rotl32(x1, 17); x1 ^= x0;
    x0 += x1; x1 = rotl32(x1, 29); x1 ^= x0;
    x0 += x1; x1 = rotl32(x1, 16); x1 ^= x0;
    x0 += x1; x1 = rotl32(x1, 24); x1 ^= x0;
    x0 += ks1; x1 += ks2 + 4u;
    x0 += x1; x1 = rotl32(x1, 13); x1 ^= x0;
    x0 += x1; x1 = rotl32(x1, 15); x1 ^= x0;
    x0 += x1; x1 = rotl32(x1, 26); x1 ^= x0;
    x0 += x1; x1 = rotl32(x1,  6); x1 ^= x0;
    x0 += ks2; x1 += ks0 + 5u;
    return x0 ^ x1;
}

// ===== merged prep: mask | x->bf16 | W1^T | W2^T | zero gcnt (independent) ===
__global__ __launch_bounds__(256) void prep(
    uint32_t* __restrict__ mask, const float* __restrict__ x,
    __bf16* __restrict__ xb,
    const float* __restrict__ Ws1, const float* __restrict__ Wn1,
    __bf16* __restrict__ w1t,
    const float* __restrict__ Ws2, const float* __restrict__ Wn2,
    __bf16* __restrict__ w2t, int* __restrict__ gcnt)
{
    const int b = blockIdx.x, tid = threadIdx.x;
    if (b < MASK_NB) {
        int w = b * 256 + tid;
        if (w >= MASK_WORDS) return;
        uint32_t base = (uint32_t)w * 32u;
        uint32_t m = 0u;
#pragma unroll
        for (int j = 0; j < 32; ++j) {
            uint32_t bits = jax_bits(base + (uint32_t)j);
            m |= ((~bits) >> 31) << j;
        }
        mask[w] = m;
    } else if (b < MASK_NB + XCVT_NB) {
        int i = (b - MASK_NB) * 256 + tid;
        if (i * 4 >= N_NODES * IN_F) return;
        float4 v = reinterpret_cast<const float4*>(x)[i];
        bf16x4 bb;
        bb[0] = (__bf16)v.x; bb[1] = (__bf16)v.y;
        bb[2] = (__bf16)v.z; bb[3] = (__bf16)v.w;
        *reinterpret_cast<bf16x4*>(xb + i * 4) = bb;
    } else if (b < MASK_NB + XCVT_NB + W1T_NB) {
        int gid = (b - MASK_NB - XCVT_NB) * 256 + tid;
        if (gid >= HID * K1) return;
        int j = gid / K1, k = gid % K1;
        float v = 0.f;
        if (k < IN_F)          v = Ws1[k * HID + j];
        else if (k < 2 * IN_F) v = Wn1[(k - IN_F) * HID + j];
        w1t[gid] = (__bf16)v;
    } else if (b < MASK_NB + XCVT_NB + W1T_NB + W2T_NB) {
        int gid = (b - MASK_NB - XCVT_NB - W1T_NB) * 256 + tid;
        if (gid >= 96 * K2) return;
        int j = gid / K2, k = gid % K2;
        float v = 0.f;
        if (j < NCLS)               v = Ws2[k * NCLS + j];
        else if (j >= 48 && j < 95) v = Wn2[k * NCLS + (j - 48)];
        w2t[gid] = (__bf16)v;
    } else {
        if (tid < NBKT) gcnt[tid] = 0;
    }
}

// ============ locality-partitioned CSR build (dst -> srcs) ===================
__global__ __launch_bounds__(256) void bkt_hist(
    const int* __restrict__ dst, int* __restrict__ gcnt)
{
    __shared__ int lcnt[NBKT];
    for (int t = threadIdx.x; t < NBKT; t += 256) lcnt[t] = 0;
    __syncthreads();
    int base = blockIdx.x * 4096;
    for (int it = 0; it < 16; ++it) {
        int e = base + it * 256 + threadIdx.x;
        if (e < N_EDGES) atomicAdd(&lcnt[dst[e] >> 8], 1);
    }
    __syncthreads();
    for (int t = threadIdx.x; t < NBKT; t += 256)
        if (lcnt[t]) atomicAdd(&gcnt[t], lcnt[t]);
}

__global__ __launch_bounds__(256) void bkt_scan(
    const int* __restrict__ gcnt, int* __restrict__ gbase, int* __restrict__ gcur)
{
    __shared__ int s[256];
    int tid = threadIdx.x;
    int v = (tid < NBKT) ? gcnt[tid] : 0;
    s[tid] = v;
    __syncthreads();
    for (int off = 1; off < 256; off <<= 1) {
        int t = (tid >= off) ? s[tid - off] : 0;
        __syncthreads();
        s[tid] += t;
        __syncthreads();
    }
    if (tid < NBKT) { int ex = s[tid] - v; gbase[tid] = ex; gcur[tid] = ex; }
    if (tid == NBKT - 1) gbase[NBKT] = s[tid];
}

__global__ __launch_bounds__(256) void bkt_bin(
    const int* __restrict__ src, const int* __restrict__ dst,
    int* __restrict__ gcur, uint32_t* __restrict__ ebin)
{
    __shared__ uint32_t ldata[4096];
    __shared__ uint8_t  lbkt[4096];
    __shared__ int lcnt[NBKT], lofs[NBKT], lcur[NBKT], gb[NBKT];
    __shared__ int lscan[256];
    const int tid  = threadIdx.x;
    const int base = blockIdx.x * 4096;

    for (int t = tid; t < NBKT; t += 256) lcnt[t] = 0;
    __syncthreads();

    uint32_t pk[16];
    int bk[16];
    for (int it = 0; it < 16; ++it) {
        int e = base + it * 256 + tid;
        if (e < N_EDGES) {
            int d = dst[e];
            pk[it] = ((uint32_t)d << 16) | (uint32_t)src[e];
            bk[it] = d >> 8;
            atomicAdd(&lcnt[bk[it]], 1);
        } else bk[it] = -1;
    }
    __syncthreads();

    int v = (tid < NBKT) ? lcnt[tid] : 0;
    lscan[tid] = v;
    __syncthreads();
    for (int off = 1; off < 256; off <<= 1) {
        int t = (tid >= off) ? lscan[tid - off] : 0;
        __syncthreads();
        lscan[tid] += t;
        __syncthreads();
    }
    if (tid < NBKT) {
        lofs[tid] = lscan[tid] - v;
        lcur[tid] = 0;
        gb[tid]   = (v > 0) ? atomicAdd(&gcur[tid], v) : 0;
    }
    __syncthreads();

    for (int it = 0; it < 16; ++it) {
        if (bk[it] >= 0) {
            int p = lofs[bk[it]] + atomicAdd(&lcur[bk[it]], 1);
            ldata[p] = pk[it];
            lbkt[p]  = (uint8_t)bk[it];
        }
    }
    __syncthreads();

    const int n = min(4096, N_EDGES - base);
    for (int i = tid; i < n; i += 256) {
        int b = lbkt[i];
        ebin[gb[b] + (i - lofs[b])] = ldata[i];
    }
}

__global__ __launch_bounds__(256) void bkt_build(
    const int* __restrict__ gbase, const uint32_t* __restrict__ ebin,
    int* __restrict__ row_ptr, float* __restrict__ invdeg,
    uint16_t* __restrict__ csr_src)
{
    __shared__ int ldeg[256], lscan[256], lcur[256];
    const int b = blockIdx.x, tid = threadIdx.x;
    const int beg = gbase[b], end = gbase[b + 1], n = end - beg;
    const int node0 = b << 8;
    const int nloc = min(256, N_NODES - node0);

    ldeg[tid] = 0;
    __syncthreads();
    for (int i = tid; i < n; i += 256)
        atomicAdd(&ldeg[(int)(ebin[beg + i] >> 16) - node0], 1);
    __syncthreads();

    int d = ldeg[tid];
    lscan[tid] = d;
    __syncthreads();
    for (int off = 1; off < 256; off <<= 1) {
        int t = (tid >= off) ? lscan[tid - off] : 0;
        __syncthreads();
        lscan[tid] += t;
        __syncthreads();
    }
    int excl = lscan[tid] - d;
    lcur[tid] = excl;
    if (tid < nloc) {
        row_ptr[node0 + tid] = beg + excl;
        invdeg[node0 + tid]  = 1.0f / fmaxf((float)d, 1.0f);
    }
    if (b == NBKT - 1 && tid == 0) row_ptr[N_NODES] = end;
    __syncthreads();

    for (int i = tid; i < n; i += 256) {
        uint32_t pk = ebin[beg + i];
        int ld = (int)(pk >> 16) - node0;
        int pos = atomicAdd(&lcur[ld], 1);
        csr_src[beg + pos] = (uint16_t)(pk & 0xFFFFu);
    }
}

// ====== FUSED agg1 + layer-1 + layer-2: gather-mean -> LDS -> MFMA ===========
// 32 rows/block, 256 thr, 6 blk/CU.
// step A: stage own x rows -> xs[.][0..99], zero pad [200..224)
// step B: gather-mean neighbors -> xs[.][100..199]  (8 thr/node, x2-unrolled)
// phase1: wave w (0..3) = 32 rows x 64 cols (ct=4, rg=2) -> hs (LDS union)
// phase2: waves 0..2    = 32 rows x 32 cols -> out(+b2) | z2b
__global__ __launch_bounds__(256, 6) void sage_fused(
    const int* __restrict__ row_ptr, const uint16_t* __restrict__ csr_src,
    const __bf16* __restrict__ xb, const float* __restrict__ invdeg,
    const __bf16* __restrict__ w1t, const float* __restrict__ b1,
    const uint32_t* __restrict__ mask,
    const __bf16* __restrict__ w2t, const float* __restrict__ b2,
    float* __restrict__ out, __bf16* __restrict__ z2b)
{
    __shared__ __align__(16) unsigned char smem[32 * K2S * sizeof(__bf16)];
    __bf16 (*xs)[K1S] = reinterpret_cast<__bf16 (*)[K1S]>(smem);
    __bf16 (*hs)[K2S] = reinterpret_cast<__bf16 (*)[K2S]>(smem);
    __shared__ uint32_t msk[32][8];
    const int row0 = blockIdx.x * 32;
    const int tid  = threadIdx.x;
    const int nrow = min(32, N_NODES - row0);

    // ---- step A: own x rows (chunks 0..24) + zero pad (chunks 50..55) ----
    for (int t = tid; t < 32 * 56; t += 256) {
        int r = t / 56, c4 = t % 56;
        if (c4 >= 25 && c4 < 50) continue;   // mean region: written by step B
        bf16x4 v = {};
        if (r < nrow && c4 < 25)
            v = *reinterpret_cast<const bf16x4*>(xb + (size_t)(row0 + r) * IN_F + c4 * 4);
        *reinterpret_cast<bf16x4*>(&xs[r][c4 * 4]) = v;
    }
    {
        int r = tid >> 3, w8 = tid & 7;
        msk[r][w8] = (r < nrow) ? mask[(size_t)(row0 + r) * 8 + w8] : 0u;
    }

    // ---- step B: gather-mean -> xs[r][100..199]; 8 threads per node ----
    {
        const int r  = tid >> 3;     // node slot 0..31
        const int j8 = tid & 7;      // chunk lane: chunks {j8, j8+8, j8+16} (+24 if j8==0)
        const int node = row0 + r;
        if (node < N_NODES) {
            f32x4 a0 = {0.f,0.f,0.f,0.f}, a1 = a0, a2 = a0, a3 = a0;
            int beg = row_ptr[node], end = row_ptr[node + 1];
            int e = beg;
            for (; e + 1 < end; e += 2) {
                const __bf16* xp = xb + (size_t)csr_src[e]     * IN_F;
                const __bf16* xq = xb + (size_t)csr_src[e + 1] * IN_F;
                bf16x4 p0 = *reinterpret_cast<const bf16x4*>(xp + j8 * 4);
                bf16x4 p1 = *reinterpret_cast<const bf16x4*>(xp + (j8 + 8) * 4);
                bf16x4 p2 = *reinterpret_cast<const bf16x4*>(xp + (j8 + 16) * 4);
                bf16x4 q0 = *reinterpret_cast<const bf16x4*>(xq + j8 * 4);
                bf16x4 q1 = *reinterpret_cast<const bf16x4*>(xq + (j8 + 8) * 4);
                bf16x4 q2 = *reinterpret_cast<const bf16x4*>(xq + (j8 + 16) * 4);
#pragma unroll
                for (int q = 0; q < 4; ++q) {
                    a0[q] += (float)p0[q] + (float)q0[q];
                    a1[q] += (float)p1[q] + (float)q1[q];
                    a2[q] += (float)p2[q] + (float)q2[q];
                }
                if (j8 == 0) {
                    bf16x4 p3 = *reinterpret_cast<const bf16x4*>(xp + 96);
                    bf16x4 q3 = *reinterpret_cast<const bf16x4*>(xq + 96);
#pragma unroll
                    for (int q = 0; q < 4; ++q) a3[q] += (float)p3[q] + (float)q3[q];
                }
            }
            if (e < end) {
                const __bf16* xp = xb + (size_t)csr_src[e] * IN_F;
                bf16x4 p0 = *reinterpret_cast<const bf16x4*>(xp + j8 * 4);
                bf16x4 p1 = *reinterpret_cast<const bf16x4*>(xp + (j8 + 8) * 4);
                bf16x4 p2 = *reinterpret_cast<const bf16x4*>(xp + (j8 + 16) * 4);
#pragma unroll
                for (int q = 0; q < 4; ++q) {
                    a0[q] += (float)p0[q];
                    a1[q] += (float)p1[q];
                    a2[q] += (float)p2[q];
                }
                if (j8 == 0) {
                    bf16x4 p3 = *reinterpret_cast<const bf16x4*>(xp + 96);
#pragma unroll
                    for (int q = 0; q < 4; ++q) a3[q] += (float)p3[q];
                }
            }
            const float inv = invdeg[node];
            bf16x4 r0, r1, r2;
#pragma unroll
            for (int q = 0; q < 4; ++q) {
                r0[q] = (__bf16)(a0[q] * inv);
                r1[q] = (__bf16)(a1[q] * inv);
                r2[q] = (__bf16)(a2[q] * inv);
            }
            *reinterpret_cast<bf16x4*>(&xs[r][IN_F + j8 * 4])        = r0;
            *reinterpret_cast<bf16x4*>(&xs[r][IN_F + (j8 + 8) * 4])  = r1;
            *reinterpret_cast<bf16x4*>(&xs[r][IN_F + (j8 + 16) * 4]) = r2;
            if (j8 == 0) {
                bf16x4 r3;
#pragma unroll
                for (int q = 0; q < 4; ++q) r3[q] = (__bf16)(a3[q] * inv);
                *reinterpret_cast<bf16x4*>(&xs[r][IN_F + 96]) = r3;
            }
        } else {
            bf16x4 z = {};
            *reinterpret_cast<bf16x4*>(&xs[r][IN_F + j8 * 4])        = z;
            *reinterpret_cast<bf16x4*>(&xs[r][IN_F + (j8 + 8) * 4])  = z;
            *reinterpret_cast<bf16x4*>(&xs[r][IN_F + (j8 + 16) * 4]) = z;
            if (j8 == 0) *reinterpret_cast<bf16x4*>(&xs[r][IN_F + 96]) = z;
        }
    }
    __syncthreads();

    const int w    = tid >> 6;          // wave 0..3
    const int lane = tid & 63;
    const int lm   = lane & 15;
    const int hi   = lane >> 4;         // 0..3
    const int lk   = hi * 8;

    // ---- phase 1: h1 = (x||mean) @ W1^T ; wave cols = w*64 + ct*16 + lm ----
    const int wc = w * 64;
    f32x4 acc[4][2];
#pragma unroll
    for (int ct = 0; ct < 4; ++ct)
#pragma unroll
        for (int rg = 0; rg < 2; ++rg) acc[ct][rg] = (f32x4){0.f, 0.f, 0.f, 0.f};

    for (int kk = 0; kk < K1 / 32; ++kk) {
        bf16x8 a[2];
#pragma unroll
        for (int rg = 0; rg < 2; ++rg)
            a[rg] = *reinterpret_cast<const bf16x8*>(&xs[rg * 16 + lm][kk * 32 + lk]);
#pragma unroll
        for (int ct = 0; ct < 4; ++ct) {
            const bf16x8 b = *reinterpret_cast<const bf16x8*>(
                &w1t[(size_t)(wc + ct * 16 + lm) * K1 + kk * 32 + lk]);
#pragma unroll
            for (int rg = 0; rg < 2; ++rg)
                acc[ct][rg] = __builtin_amdgcn_mfma_f32_16x16x32_bf16(a[rg], b, acc[ct][rg], 0, 0, 0);
        }
    }
    __syncthreads();   // all waves done READING xs before hs overwrites it

    // epilogue 1: bias + ReLU + dropout -> hs (LDS)
#pragma unroll
    for (int ct = 0; ct < 4; ++ct) {
        const int col = wc + ct * 16 + lm;
        const float bj = b1[col];
        const int word = (w << 1) + ((ct * 16 + lm) >> 5);
        const int bit  = (ct * 16 + lm) & 31;
#pragma unroll
        for (int rg = 0; rg < 2; ++rg) {
#pragma unroll
            for (int reg = 0; reg < 4; ++reg) {
                int r = rg * 16 + hi * 4 + reg;
                float v = 0.f;
                if (r < nrow) {
                    v = fmaxf(acc[ct][rg][reg] + bj, 0.f);
                    v = ((msk[r][word] >> bit) & 1u) ? v * 2.0f : 0.f;
                }
                hs[r][col] = (__bf16)v;
            }
        }
    }
    __syncthreads();

    // ---- phase 2: [out_self | z2] = h1 @ W2^T ; waves 0..2, 32 cols each ----
    if (w < 3) {
        const int wc2 = w * 32;
        f32x4 acc2[2][2];
#pragma unroll
        for (int ct = 0; ct < 2; ++ct)
#pragma unroll
            for (int rg = 0; rg < 2; ++rg) acc2[ct][rg] = (f32x4){0.f, 0.f, 0.f, 0.f};

        for (int kk = 0; kk < K2 / 32; ++kk) {
            bf16x8 a[2];
#pragma unroll
            for (int rg = 0; rg < 2; ++rg)
                a[rg] = *reinterpret_cast<const bf16x8*>(&hs[rg * 16 + lm][kk * 32 + lk]);
#pragma unroll
            for (int ct = 0; ct < 2; ++ct) {
                const bf16x8 b = *reinterpret_cast<const bf16x8*>(
                    &w2t[(size_t)(wc2 + ct * 16 + lm) * K2 + kk * 32 + lk]);
#pragma unroll
                for (int rg = 0; rg < 2; ++rg)
                    acc2[ct][rg] = __builtin_amdgcn_mfma_f32_16x16x32_bf16(a[rg], b, acc2[ct][rg], 0, 0, 0);
            }
        }

#pragma unroll
        for (int ct = 0; ct < 2; ++ct) {
            const int col = wc2 + ct * 16 + lm;
#pragma unroll
            for (int rg = 0; rg < 2; ++rg) {
#pragma unroll
                for (int reg = 0; reg < 4; ++reg) {
                    int r = rg * 16 + hi * 4 + reg;
                    if (r >= nrow) continue;
                    int g = row0 + r;
                    float v = acc2[ct][rg][reg];
                    if (col < NCLS)                 out[(size_t)g * NCLS + col] = v + b2[col];
                    else if (col >= 48 && col < 95) z2b[(size_t)g * 48 + (col - 48)] = (__bf16)v;
                    else if (col == 95)             z2b[(size_t)g * 48 + 47] = (__bf16)0.f;
                }
            }
        }
    }
}

// ====== pull aggregation, layer 2: bf16 gather x4-unrolled, mean + add =======
__global__ __launch_bounds__(256) void agg2_bf(
    const int* __restrict__ row_ptr, const uint16_t* __restrict__ csr_src,
    const __bf16* __restrict__ z2b, const float* __restrict__ invdeg,
    float* __restrict__ out)
{
    int gid  = blockIdx.x * 256 + threadIdx.x;
    int node = gid >> 4;
    int j    = gid & 15;
    if (node >= N_NODES || j >= 12) return;
    int beg = row_ptr[node], end = row_ptr[node + 1];
    f32x4 acc = {0.f, 0.f, 0.f, 0.f};
    int e = beg;
    for (; e + 3 < end; e += 4) {
        int s0 = csr_src[e],     s1 = csr_src[e + 1];
        int s2 = csr_src[e + 2], s3 = csr_src[e + 3];
        bf16x4 v0 = *reinterpret_cast<const bf16x4*>(z2b + (size_t)s0 * 48 + j * 4);
        bf16x4 v1 = *reinterpret_cast<const bf16x4*>(z2b + (size_t)s1 * 48 + j * 4);
        bf16x4 v2 = *reinterpret_cast<const bf16x4*>(z2b + (size_t)s2 * 48 + j * 4);
        bf16x4 v3 = *reinterpret_cast<const bf16x4*>(z2b + (size_t)s3 * 48 + j * 4);
#pragma unroll
        for (int q = 0; q < 4; ++q)
            acc[q] += ((float)v0[q] + (float)v1[q]) + ((float)v2[q] + (float)v3[q]);
    }
    for (; e < end; ++e) {
        bf16x4 v = *reinterpret_cast<const bf16x4*>(z2b + (size_t)csr_src[e] * 48 + j * 4);
#pragma unroll
        for (int q = 0; q < 4; ++q) acc[q] += (float)v[q];
    }
    float inv = invdeg[node];
#pragma unroll
    for (int q = 0; q < 4; ++q) {
        int col = j * 4 + q;
        if (col < NCLS)
            out[(size_t)node * NCLS + col] += acc[q] * inv;
    }
}

extern "C" void kernel_launch(void* const* d_in, const int* in_sizes, int n_in,
                              void* d_out, int out_size, void* d_ws, size_t ws_size,
                              hipStream_t stream)
{
    const float* x   = (const float*)d_in[0];
    const int*   src = (const int*)  d_in[1];
    const int*   dst = (const int*)  d_in[2];
    const float* Ws1 = (const float*)d_in[3];
    const float* Wn1 = (const float*)d_in[4];
    const float* b1  = (const float*)d_in[5];
    const float* Ws2 = (const float*)d_in[6];
    const float* Wn2 = (const float*)d_in[7];
    const float* b2  = (const float*)d_in[8];
    float* out = (float*)d_out;

    // ---- workspace layout (int-slot / float-slot units) ----
    int*      wsi     = (int*)d_ws;
    int*      row_ptr = wsi;                 //  50,001
    int*      gcnt    = wsi + 50008;         //     196
    int*      gbase   = wsi + 50208;         //     197
    int*      gcur    = wsi + 50408;         //     196
    uint32_t* ebin    = (uint32_t*)(wsi + 50608);    // 800,000 u32
    uint16_t* csr_src = (uint16_t*)(wsi + 850608);   // 800,000 u16
    float*    wsf     = (float*)d_ws;
    float*    invdeg  = wsf + 1300000;               //  50,000 f32
    __bf16*   xb      = (__bf16*)(wsf + 1350000);    //  5.0M bf16
    uint32_t* mask    = (uint32_t*)(wsf + 6350000);  //  400K u32
    __bf16*   w1t     = (__bf16*)(wsf + 6750000);    // 57,344 bf16
    __bf16*   w2t     = (__bf16*)(wsf + 6780000);    // 24,576 bf16
    __bf16*   z2b     = (__bf16*)(wsf + 6800000);    //  2.4M bf16  (~32 MB)

    prep<<<PREP_NB, 256, 0, stream>>>(mask, x, xb, Ws1, Wn1, w1t, Ws2, Wn2, w2t, gcnt);

    bkt_hist <<<NBKT, 256, 0, stream>>>(dst, gcnt);
    bkt_scan <<<1, 256, 0, stream>>>(gcnt, gbase, gcur);
    bkt_bin  <<<NBKT, 256, 0, stream>>>(src, dst, gcur, ebin);
    bkt_build<<<NBKT, 256, 0, stream>>>(gbase, ebin, row_ptr, invdeg, csr_src);

    sage_fused<<<(N_NODES + 31) / 32, 256, 0, stream>>>(
        row_ptr, csr_src, xb, invdeg, w1t, b1, mask, w2t, b2, out, z2b);
    agg2_bf<<<(N_NODES * 16 + 255) / 256, 256, 0, stream>>>(row_ptr, csr_src, z2b, invdeg, out);
}